// Round 8
// baseline (3168.137 us; speedup 1.0000x reference)
//
#include <hip/hip_runtime.h>
#include <math.h>

typedef unsigned int u32;
typedef unsigned short u16;
typedef short bf16x8 __attribute__((ext_vector_type(8)));
typedef float f32x4 __attribute__((ext_vector_type(4)));

#define B_ROWS 131072
#define R_TILE 64
#define NTH 512

// ---------------- packed-weight layout in d_ws (16B frag units) ----------------
#define L0H 0        // bW1 K=32(pad) N=512: ct=32, ks=1
#define L0N 2048
#define L1H 4096     // bW2 K=512 N=256: ct=16, ks=16
#define L1N 16384
#define L2H 36864    // cW1 K=256 N=128: ct=8, ks=8
#define L2N 4096
#define L3H 45056    // cW2 K=128 N=128: ct=8, ks=4
#define L3N 2048
#define L4H 49152    // rW1 concat K=256 N=512: ct=32, ks=8
#define L4N 16384
#define L5H 81920    // rW2 concat K=128 N=512: ct=32, ks=4
#define L5N 8192
#define L6H 98304    // chW K=128 N=16(pad): ct=1, ks=4 (unused by main kernel now)
#define L6N 256
#define L7H 98816    // rhW per-expert K=128 N=16(cols 0..2 valid): ct=expert(4), ks=4
#define L7N 1024
#define WS_FRAGS 100864
#define WS_NEEDED ((size_t)WS_FRAGS * 16 + 128)

// ---------------- LDS arena ----------------
// u16 offsets (activation planes; each buffer = [hi plane][lo plane])
#define U_S      0       // s [64][264] x2 planes = 33792 u16 (never overwritten)
#define S_STR    264
#define S_PLANE  16896
#define U_B1     33792   // chunk h -> c2 [64][136] x2 = 17408 u16
#define U_B2     51200   // c1 [64][136] x2 = 17408 u16
#define B_STR    136
#define B_PLANE  8704
#define U_X      68608   // x [64][40] x2 = 5120 u16
#define X_STR    40
#define X_PLANE  2560
// reg-phase e1/e2 ping-pong buffer: [4 experts][32 rows][136] x2 planes = 34816 u16
// occupies exactly B1+B2 ([33792, 68608)), both dead after the class head.
#define E_OFF    33792
#define E_STR2   136
#define E_PLANE  17408
// dword (f32) offsets
#define WP_DW    36864   // wave stats partials [8][64][2] = 1024 dw (shared layers only)
#define RS_DW    37888   // row stats [64][2] (+ spare) = 512 dw
#define LG_DW    38400   // class logits [64][4] = 256 dw
#define IDX_DW   38656   // argmax [64]
#define RH_DW    38720   // chW staged (512 f32) -> later reg head out [4][64][4] = 1024 dw
#define SMEM_DW  39744   // 158,976 B

__device__ __forceinline__ u16 bf16_rne(float f) {
  u32 u = __float_as_uint(f);
  u32 r = u + 0x7fffu + ((u >> 16) & 1u);
  return (u16)(r >> 16);
}
__device__ __forceinline__ f32x4 mfma16(bf16x8 a, bf16x8 b, f32x4 c) {
  return __builtin_amdgcn_mfma_f32_16x16x32_bf16(a, b, c, 0, 0, 0);
}

// ---------------- weight pre-pack kernel (RNE hi/lo planes, frag layout) ----------------
__global__ void __launch_bounds__(256) pack_weights(
    const float* __restrict__ bW1, const float* __restrict__ bW2,
    const float* __restrict__ cW1, const float* __restrict__ cW2,
    const float* __restrict__ rW1, const float* __restrict__ rW2,
    const float* __restrict__ chW, const float* __restrict__ rhW,
    uint4* __restrict__ ws) {
  int t = blockIdx.x * 256 + threadIdx.x;  // 0..50431
  int base, nlanes, layer;
  if (t < 2048)       { layer = 0; base = L0H; nlanes = L0N; }
  else if (t < 18432) { layer = 1; base = L1H; nlanes = L1N; t -= 2048; }
  else if (t < 22528) { layer = 2; base = L2H; nlanes = L2N; t -= 18432; }
  else if (t < 24576) { layer = 3; base = L3H; nlanes = L3N; t -= 22528; }
  else if (t < 40960) { layer = 4; base = L4H; nlanes = L4N; t -= 24576; }
  else if (t < 49152) { layer = 5; base = L5H; nlanes = L5N; t -= 40960; }
  else if (t < 49408) { layer = 6; base = L6H; nlanes = L6N; t -= 49152; }
  else                { layer = 7; base = L7H; nlanes = L7N; t -= 49408; }
  const int ksteps = (layer == 0) ? 1 : (layer == 1) ? 16 : (layer == 2) ? 8 :
                     (layer == 3) ? 4 : (layer == 4) ? 8 : (layer == 5) ? 4 : 4;
  const int li = t;
  const int lane = li & 63;
  const int fi = li >> 6;
  const int ct = fi / ksteps;
  const int ks = fi - ct * ksteps;
  const int g = lane >> 4;
  const int col = ct * 16 + (lane & 15);
  const int kb = ks * 32 + 8 * g;
  float w[8];
#pragma unroll
  for (int e = 0; e < 8; ++e) {
    const int k = kb + e;
    float v;
    if (layer == 0)      v = (k < 5) ? bW1[k * 512 + col] : 0.f;
    else if (layer == 1) v = bW2[k * 256 + col];
    else if (layer == 2) v = cW1[k * 128 + col];
    else if (layer == 3) v = cW2[k * 128 + col];
    else if (layer == 4) v = rW1[((col >> 7) * 256 + k) * 128 + (col & 127)];
    else if (layer == 5) v = rW2[((col >> 7) * 128 + k) * 128 + (col & 127)];
    else if (layer == 6) v = (col < 4) ? chW[k * 4 + col] : 0.f;
    else {
      const int ex = col >> 4, cl = col & 15;
      v = (cl < 3) ? rhW[(ex * 128 + k) * 3 + cl] : 0.f;
    }
    w[e] = v;
  }
  u16 hi[8], lo[8];
#pragma unroll
  for (int e = 0; e < 8; ++e) {
    hi[e] = bf16_rne(w[e]);
    lo[e] = bf16_rne(w[e] - __uint_as_float((u32)hi[e] << 16));
  }
  uint4 H, L;
  H.x = (u32)hi[0] | ((u32)hi[1] << 16); H.y = (u32)hi[2] | ((u32)hi[3] << 16);
  H.z = (u32)hi[4] | ((u32)hi[5] << 16); H.w = (u32)hi[6] | ((u32)hi[7] << 16);
  L.x = (u32)lo[0] | ((u32)lo[1] << 16); L.y = (u32)lo[2] | ((u32)lo[3] << 16);
  L.z = (u32)lo[4] | ((u32)lo[5] << 16); L.w = (u32)lo[6] | ((u32)lo[7] << 16);
  ws[base + li] = H;
  ws[base + nlanes + li] = L;
}

// ---------------- LN(h) closed-form constants (quadratic form in x) ----------------
__global__ void __launch_bounds__(256) pack_stats(const float* __restrict__ bW1,
                                                  const float* __restrict__ bb1,
                                                  float* __restrict__ wsf) {
  __shared__ float red[27 * 256];
  const int t = threadIdx.x;
  float part[27];
#pragma unroll
  for (int j = 0; j < 27; ++j) part[j] = 0.f;
  for (int c = t; c < 512; c += 256) {
    float wv[5];
#pragma unroll
    for (int k = 0; k < 5; ++k) wv[k] = bW1[k * 512 + c];
    const float bc = bb1[c];
#pragma unroll
    for (int k = 0; k < 5; ++k) part[k] += wv[k];
    part[5] += bc;
    int p = 0;
#pragma unroll
    for (int k = 0; k < 5; ++k)
#pragma unroll
      for (int k2 = 0; k2 <= k; ++k2) part[6 + p++] += wv[k] * wv[k2];
#pragma unroll
    for (int k = 0; k < 5; ++k) part[21 + k] += wv[k] * bc;
    part[26] += bc * bc;
  }
#pragma unroll
  for (int j = 0; j < 27; ++j) red[j * 256 + t] = part[j];
  __syncthreads();
  if (t < 27) {
    float s = 0.f;
    for (int i = 0; i < 256; ++i) s += red[t * 256 + i];
    s *= (1.f / 512.f);
    if (t >= 6 && t < 21) {
      const int p = t - 6;
      const bool diag = (p == 0 || p == 2 || p == 5 || p == 9 || p == 14);
      if (!diag) s *= 2.f;
    }
    if (t >= 21 && t < 26) s *= 2.f;
    wsf[t] = s;
  }
}

// ---------------- main kernel building blocks ----------------
// GEMM on u16 bf16 planes in LDS: acc += Ahi*Whi [+ Alo*Whi] [+ Ahi*Wlo]
template<int KSTEPS, int CTS, int RGS, int LKS, bool ALO, bool WLO>
__device__ __forceinline__ void gemm16(const u16* smu, int a_off, int a_str, int a_plane,
                                       const uint4* __restrict__ wh,
                                       const uint4* __restrict__ wl,
                                       f32x4 (&acc)[RGS][CTS]) {
  const int lane = threadIdx.x & 63;
  const int l15 = lane & 15, g = lane >> 4;
#pragma unroll
  for (int ks = 0; ks < KSTEPS; ++ks) {
    bf16x8 ah[RGS], al[RGS];
#pragma unroll
    for (int rg = 0; rg < RGS; ++rg) {
      const int ao = a_off + (rg * 16 + l15) * a_str + ks * 32 + 8 * g;
      ah[rg] = *(const bf16x8*)(smu + ao);
      if (ALO) al[rg] = *(const bf16x8*)(smu + ao + a_plane);
    }
#pragma unroll
    for (int c = 0; c < CTS; ++c) {
      bf16x8 bh = __builtin_bit_cast(bf16x8, wh[(c * LKS + ks) * 64]);
#pragma unroll
      for (int rg = 0; rg < RGS; ++rg) acc[rg][c] = mfma16(ah[rg], bh, acc[rg][c]);
      if (ALO) {
#pragma unroll
        for (int rg = 0; rg < RGS; ++rg) acc[rg][c] = mfma16(al[rg], bh, acc[rg][c]);
      }
      if (WLO) {
        bf16x8 bl = __builtin_bit_cast(bf16x8, wl[(c * LKS + ks) * 64]);
#pragma unroll
        for (int rg = 0; rg < RGS; ++rg) acc[rg][c] = mfma16(ah[rg], bl, acc[rg][c]);
      }
    }
  }
}

template<int RGS, int CTS>
__device__ __forceinline__ void zero_acc(f32x4 (&acc)[RGS][CTS]) {
#pragma unroll
  for (int rg = 0; rg < RGS; ++rg)
#pragma unroll
    for (int c = 0; c < CTS; ++c) acc[rg][c] = (f32x4){0.f, 0.f, 0.f, 0.f};
}

// bias added AFTER the GEMM (R3 rounding order — class path depends on this)
template<int RGS, int CTS>
__device__ __forceinline__ void add_bias(f32x4 (&acc)[RGS][CTS],
                                         const float* __restrict__ bias, int col0) {
  const int l15 = threadIdx.x & 15;
#pragma unroll
  for (int c = 0; c < CTS; ++c) {
    const float bv = bias[col0 + c * 16 + l15];
#pragma unroll
    for (int rg = 0; rg < RGS; ++rg)
#pragma unroll
      for (int i = 0; i < 4; ++i) acc[rg][c][i] += bv;
  }
}

template<int RGS, int CTS>
__device__ __forceinline__ void init_bias(f32x4 (&acc)[RGS][CTS],
                                          const float* __restrict__ bias, int col0) {
  const int l15 = threadIdx.x & 15;
#pragma unroll
  for (int c = 0; c < CTS; ++c) {
    const float bv = bias[col0 + c * 16 + l15];
#pragma unroll
    for (int rg = 0; rg < RGS; ++rg)
#pragma unroll
      for (int i = 0; i < 4; ++i) acc[rg][c][i] = bv;
  }
}

// per-wave LN stats partials -> WP[w][row][2]  (shared layers)
template<int RGS, int CTS>
__device__ __forceinline__ void stats_partial(const f32x4 (&acc)[RGS][CTS], float* smf, int w) {
  const int lane = threadIdx.x & 63;
  const int l15 = lane & 15, g = lane >> 4;
  float s1[RGS][4], s2[RGS][4];
#pragma unroll
  for (int rg = 0; rg < RGS; ++rg)
#pragma unroll
    for (int i = 0; i < 4; ++i) {
      float a = 0.f, b = 0.f;
#pragma unroll
      for (int c = 0; c < CTS; ++c) { const float v = acc[rg][c][i]; a += v; b += v * v; }
      s1[rg][i] = a; s2[rg][i] = b;
    }
#pragma unroll
  for (int m = 1; m <= 8; m <<= 1)
#pragma unroll
    for (int rg = 0; rg < RGS; ++rg)
#pragma unroll
      for (int i = 0; i < 4; ++i) {
        s1[rg][i] += __shfl_xor(s1[rg][i], m);
        s2[rg][i] += __shfl_xor(s2[rg][i], m);
      }
  if (l15 == 0) {
#pragma unroll
    for (int rg = 0; rg < RGS; ++rg)
#pragma unroll
      for (int i = 0; i < 4; ++i) {
        const int row = rg * 16 + 4 * g + i;
        smf[WP_DW + (w * 64 + row) * 2]     = s1[rg][i];
        smf[WP_DW + (w * 64 + row) * 2 + 1] = s2[rg][i];
      }
  }
}

template<int N>
__device__ __forceinline__ void combine_shared(float* smf, int t) {
  if (t < 64) {
    float a = 0.f, b = 0.f;
#pragma unroll
    for (int w = 0; w < 8; ++w) {
      a += smf[WP_DW + (w * 64 + t) * 2];
      b += smf[WP_DW + (w * 64 + t) * 2 + 1];
    }
    const float mean = a * (1.f / N);
    const float var = b * (1.f / N) - mean * mean;
    smf[RS_DW + t * 2]     = mean;
    smf[RS_DW + t * 2 + 1] = rsqrtf(fmaxf(var, 0.f) + 1e-5f);
  }
}

// in-register LN stats over 128 cols (RGS=1, CTS=8)
template<int CTS>
__device__ __forceinline__ void stats_reg(const f32x4 (&acc)[1][CTS],
                                          float (&mean)[4], float (&inv)[4]) {
#pragma unroll
  for (int i = 0; i < 4; ++i) {
    float a = 0.f, b = 0.f;
#pragma unroll
    for (int c = 0; c < CTS; ++c) { const float v = acc[0][c][i]; a += v; b += v * v; }
#pragma unroll
    for (int m = 1; m <= 8; m <<= 1) { a += __shfl_xor(a, m); b += __shfl_xor(b, m); }
    const float mn = a * (1.f / 128.f);
    const float var = b * (1.f / 128.f) - mn * mn;
    mean[i] = mn;
    inv[i] = rsqrtf(fmaxf(var, 0.f) + 1e-5f);
  }
}

// normalize + ReLU + RNE double-split PAIR store (stats from registers)
template<int CTS>
__device__ __forceinline__ void nps_reg(const f32x4 (&acc)[1][CTS],
    const float (&mean)[4], const float (&inv)[4],
    const float* __restrict__ gamma, const float* __restrict__ beta, int col0,
    u16* smu, int dst, int dstr, int dplane) {
  const int lane = threadIdx.x & 63;
  const int l15 = lane & 15, g = lane >> 4;
#pragma unroll
  for (int c = 0; c < CTS; ++c) {
    const float gv = gamma[col0 + c * 16 + l15];
    const float bv = beta[col0 + c * 16 + l15];
#pragma unroll
    for (int i = 0; i < 4; ++i) {
      float y = fmaxf((acc[0][c][i] - mean[i]) * inv[i] * gv + bv, 0.f);
      const u16 h = bf16_rne(y);
      const int ad = dst + (4 * g + i) * dstr + c * 16 + l15;
      smu[ad] = h;
      smu[ad + dplane] = bf16_rne(y - __uint_as_float((u32)h << 16));
    }
  }
}

// normalize + ReLU + RNE double-split store, stats from LDS (shared layers)
template<int RGS, int CTS>
__device__ __forceinline__ void nps(const f32x4 (&acc)[RGS][CTS], u16* smu, float* smf,
                                    int st_dw, const float* __restrict__ gamma,
                                    const float* __restrict__ beta, int col0,
                                    int dst, int dstr, int dplane, int dcol0) {
  const int lane = threadIdx.x & 63;
  const int l15 = lane & 15, g = lane >> 4;
  float gv[CTS], bv[CTS];
#pragma unroll
  for (int c = 0; c < CTS; ++c) {
    gv[c] = gamma[col0 + c * 16 + l15];
    bv[c] = beta[col0 + c * 16 + l15];
  }
#pragma unroll
  for (int rg = 0; rg < RGS; ++rg)
#pragma unroll
    for (int i = 0; i < 4; ++i) {
      const int row = rg * 16 + 4 * g + i;
      const float mean = smf[st_dw + row * 2];
      const float inv  = smf[st_dw + row * 2 + 1];
#pragma unroll
      for (int c = 0; c < CTS; ++c) {
        float y = fmaxf((acc[rg][c][i] - mean) * inv * gv[c] + bv[c], 0.f);
        const u16 h = bf16_rne(y);
        const int ad = dst + row * dstr + dcol0 + c * 16 + l15;
        smu[ad] = h;
        smu[ad + dplane] = bf16_rne(y - __uint_as_float((u32)h << 16));
      }
    }
}

__global__ void __launch_bounds__(NTH, 1) moe_v7(
    const float* __restrict__ x,
    const float* __restrict__ bb1, const float* __restrict__ bg1, const float* __restrict__ bbt1,
    const float* __restrict__ bb2, const float* __restrict__ bg2, const float* __restrict__ bbt2,
    const float* __restrict__ cb1, const float* __restrict__ cg1, const float* __restrict__ cbt1,
    const float* __restrict__ cb2, const float* __restrict__ cg2, const float* __restrict__ cbt2,
    const float* __restrict__ chW, const float* __restrict__ chb,
    const float* __restrict__ rb1, const float* __restrict__ rg1, const float* __restrict__ rbt1,
    const float* __restrict__ rb2, const float* __restrict__ rg2, const float* __restrict__ rbt2,
    const float* __restrict__ rhb,
    float* __restrict__ out, const uint4* __restrict__ wp, const float* __restrict__ cs) {
  __shared__ __align__(16) u32 sm[SMEM_DW];
  u16* smu = (u16*)sm;
  float* smf = (float*)sm;
  const int t = threadIdx.x;
  const int w = t >> 6;
  const int lane = t & 63;
  const int row0 = blockIdx.x * R_TILE;

  // ---- stage chW fp32 into RH region (free until reg-head) ----
  for (int i = t; i < 512; i += NTH) smf[RH_DW + i] = chW[i];

  // ---- stage x (RNE double-split pair, K zero-padded to 32) ----
  {
    const int r = t >> 3, k0 = (t & 7) * 4;
#pragma unroll
    for (int i = 0; i < 4; ++i) {
      const int k = k0 + i;
      const float v = (k < 5) ? x[(size_t)(row0 + r) * 5 + k] : 0.f;
      const u16 h = bf16_rne(v);
      smu[U_X + r * X_STR + k] = h;
      smu[U_X + X_PLANE + r * X_STR + k] = bf16_rne(v - __uint_as_float((u32)h << 16));
    }
  }
  // ---- closed-form LN(h) stats ----
  if (t < 64) {
    float xv[5];
#pragma unroll
    for (int k = 0; k < 5; ++k) xv[k] = x[(size_t)(row0 + t) * 5 + k];
    float mean = cs[5];
#pragma unroll
    for (int k = 0; k < 5; ++k) mean += xv[k] * cs[k];
    float e2 = cs[26];
    int p = 0;
#pragma unroll
    for (int k = 0; k < 5; ++k) {
      e2 += xv[k] * cs[21 + k];
#pragma unroll
      for (int k2 = 0; k2 <= k; ++k2) e2 += cs[6 + p++] * xv[k] * xv[k2];
    }
    const float var = e2 - mean * mean;
    smf[RS_DW + t * 2]     = mean;
    smf[RS_DW + t * 2 + 1] = rsqrtf(fmaxf(var, 0.f) + 1e-5f);
  }
  __syncthreads();

  // ---- phase 1: L1 -> LN -> pack -> partial L2 over 128-col chunks (R3 order) ----
  f32x4 accS[4][2];
  zero_acc<4, 2>(accS);
  for (int kc = 0; kc < 4; ++kc) {
    f32x4 acc1[4][1];
    zero_acc<4, 1>(acc1);
    gemm16<1, 1, 4, 1, true, true>(smu, U_X, X_STR, X_PLANE,
        wp + L0H + (kc * 8 + w) * 64 + lane,
        wp + L0H + L0N + (kc * 8 + w) * 64 + lane, acc1);
    add_bias<4, 1>(acc1, bb1, kc * 128 + w * 16);
    nps<4, 1>(acc1, smu, smf, RS_DW, bg1, bbt1, kc * 128 + w * 16,
              U_B1, B_STR, B_PLANE, w * 16);
    __syncthreads();
    gemm16<4, 2, 4, 16, true, true>(smu, U_B1, B_STR, B_PLANE,
        wp + L1H + (w * 32 + kc * 4) * 64 + lane,
        wp + L1H + L1N + (w * 32 + kc * 4) * 64 + lane, accS);
    __syncthreads();
  }

  // ---- s: bias-after + in-reg LN -> pair pack ----
  add_bias<4, 2>(accS, bb2, w * 32);
  stats_partial<4, 2>(accS, smf, w);
  __syncthreads();
  combine_shared<256>(smf, t);
  __syncthreads();
  nps<4, 2>(accS, smu, smf, RS_DW, bg2, bbt2, w * 32, U_S, S_STR, S_PLANE, w * 32);
  __syncthreads();

  // ---- class expert L1 ----
  {
    f32x4 accC[4][1];
    zero_acc<4, 1>(accC);
    gemm16<8, 1, 4, 8, true, true>(smu, U_S, S_STR, S_PLANE,
        wp + L2H + (w * 8) * 64 + lane, wp + L2H + L2N + (w * 8) * 64 + lane, accC);
    add_bias<4, 1>(accC, cb1, w * 16);
    stats_partial<4, 1>(accC, smf, w);
    __syncthreads();
    combine_shared<128>(smf, t);
    __syncthreads();
    nps<4, 1>(accC, smu, smf, RS_DW, cg1, cbt1, w * 16, U_B2, B_STR, B_PLANE, w * 16);
    __syncthreads();
  }

  // ---- class expert L2 -> c2 (buf1) ----
  {
    f32x4 accD[4][1];
    zero_acc<4, 1>(accD);
    gemm16<4, 1, 4, 4, true, true>(smu, U_B2, B_STR, B_PLANE,
        wp + L3H + (w * 4) * 64 + lane, wp + L3H + L3N + (w * 4) * 64 + lane, accD);
    add_bias<4, 1>(accD, cb2, w * 16);
    stats_partial<4, 1>(accD, smf, w);
    __syncthreads();
    combine_shared<128>(smf, t);
    __syncthreads();
    nps<4, 1>(accD, smu, smf, RS_DW, cg2, cbt2, w * 16, U_B1, B_STR, B_PLANE, w * 16);
    __syncthreads();
  }

  // ---- class head: scalar fp32 from c2 pair × chW (R3's exact recipe) ----
  {
    const int r = t >> 3, o = (t >> 1) & 3, q = t & 1;
    const u16* hp = smu + U_B1 + r * B_STR + q * 64;
    const u16* lp = hp + B_PLANE;
    float s = 0.f;
#pragma unroll
    for (int kk = 0; kk < 64; ++kk) {
      const float a = __uint_as_float((u32)hp[kk] << 16) +
                      __uint_as_float((u32)lp[kk] << 16);
      s += a * smf[RH_DW + (q * 64 + kk) * 4 + o];
    }
    s += __shfl_xor(s, 1);
    if (q == 0) {
      const float v = s + chb[o];
      smf[LG_DW + r * 4 + o] = v;
      out[(size_t)(row0 + r) * 4 + o] = v;
    }
  }
  __syncthreads();
  if (t < 64) {  // argmax (first max == jnp.argmax)
    float best = smf[LG_DW + t * 4];
    int bi = 0;
#pragma unroll
    for (int n = 1; n < 4; ++n) {
      const float v = smf[LG_DW + t * 4 + n];
      if (v > best) { best = v; bi = n; }
    }
    sm[IDX_DW + t] = (u32)bi;
  }

  // ---- reg experts: 2 row-halves, wave (wm2,wn): rows [32h+16wm2,+16) x expert wn ----
  // Full pair storage + 3-term GEMMs. e1/e2 ping-pong in E region (overlays B1/B2).
  const int wm2 = w >> 2, wn = w & 3;
#pragma unroll 1
  for (int h = 0; h < 2; ++h) {
    const int r0 = 32 * h + 16 * wm2;
    const int eb = E_OFF + (wn * 32 + 16 * wm2) * E_STR2;
    // L1: K=256 from s (pair, 3-term)
    {
      f32x4 aE[1][8];
      init_bias<1, 8>(aE, rb1, wn * 128);
      gemm16<8, 8, 1, 8, true, true>(smu, U_S + r0 * S_STR, S_STR, S_PLANE,
          wp + L4H + (wn * 64) * 64 + lane, wp + L4H + L4N + (wn * 64) * 64 + lane, aE);
      float mn[4], iv[4];
      stats_reg<8>(aE, mn, iv);
      __syncthreads();   // prior readers of E region (class head / prev-half head) done
      nps_reg<8>(aE, mn, iv, rg1, rbt1, wn * 128, smu, eb, E_STR2, E_PLANE);
    }
    __syncthreads();
    // L2: K=128 from e1 (pair, 3-term), in-place ping-pong
    {
      f32x4 aF[1][8];
      init_bias<1, 8>(aF, rb2, wn * 128);
      gemm16<4, 8, 1, 4, true, true>(smu, eb, E_STR2, E_PLANE,
          wp + L5H + (wn * 32) * 64 + lane, wp + L5H + L5N + (wn * 32) * 64 + lane, aF);
      float mn[4], iv[4];
      stats_reg<8>(aF, mn, iv);
      __syncthreads();   // all waves done reading e1
      nps_reg<8>(aF, mn, iv, rg2, rbt2, wn * 128, smu, eb, E_STR2, E_PLANE);
    }
    __syncthreads();
    // head: K=128 per-expert (pair, 3-term) -> RH[wn][row][0..2]
    {
      f32x4 aH[1][1];
      aH[0][0] = (f32x4){0.f, 0.f, 0.f, 0.f};
      gemm16<4, 1, 1, 4, true, true>(smu, eb, E_STR2, E_PLANE,
          wp + L7H + (wn * 4) * 64 + lane, wp + L7H + L7N + (wn * 4) * 64 + lane, aH);
      const int l15 = lane & 15, g = lane >> 4;
      if (l15 < 3) {
#pragma unroll
        for (int i = 0; i < 4; ++i)
          smf[RH_DW + (wn * 64 + r0 + 4 * g + i) * 4 + l15] = aH[0][0][i];
      }
    }
    __syncthreads();
  }

  // ---- gather chosen expert + softmax ----
  if (t < 64) {
    const int e = (int)sm[IDX_DW + t];
    const float v0 = smf[RH_DW + (e * 64 + t) * 4 + 0] + rhb[3 * e + 0];
    const float v1 = smf[RH_DW + (e * 64 + t) * 4 + 1] + rhb[3 * e + 1];
    const float v2 = smf[RH_DW + (e * 64 + t) * 4 + 2] + rhb[3 * e + 2];
    const float mx = fmaxf(v0, fmaxf(v1, v2));
    const float e0 = expf(v0 - mx), e1 = expf(v1 - mx), e2 = expf(v2 - mx);
    const float inv = 1.f / (e0 + e1 + e2);
    float* po = out + (size_t)B_ROWS * 4 + (size_t)(row0 + t) * 3;
    po[0] = e0 * inv; po[1] = e1 * inv; po[2] = e2 * inv;
  }
}

// =================== fallback: round-1 fp32 kernel (used if ws too small) ===================
#define TILE 16
#define S_H 516
#define S_Sf 260
#define S_N 132
#define F_OFF_H 0
#define F_OFF_C1 0
#define F_OFF_C2 2112
#define F_OFF_E2 4224
#define F_OFF_S 8256
#define F_OFF_E1 8256
#define F_OFF_X 12416
#define F_OFF_HEAD 12544
#define F_OFF_RH 12608
#define F_OFF_INT 12672
#define F_SMEM 12704

template<int K, int N, int RB, int CB, int INS, int OUTS, bool BAR>
__device__ __forceinline__ void dense(const float* __restrict__ W, const float* __restrict__ bias,
                                      const float* IN, float* OUT, int tid) {
  constexpr int CBLK = N / CB;
  const int cb = tid % CBLK, rg = tid / CBLK;
  const int c0 = cb * CB, r0 = rg * RB;
  float acc[RB][CB];
#pragma unroll
  for (int i = 0; i < RB; ++i)
#pragma unroll
    for (int j = 0; j < CB; ++j) acc[i][j] = 0.f;
  for (int k = 0; k < K; k += 4) {
    float4 a[RB];
#pragma unroll
    for (int i = 0; i < RB; ++i) a[i] = *(const float4*)(IN + (r0 + i) * INS + k);
#pragma unroll
    for (int kk = 0; kk < 4; ++kk) {
      float wv2[CB];
      if constexpr (CB == 2) { float2 wv = *(const float2*)(W + (k + kk) * N + c0); wv2[0] = wv.x; wv2[1] = wv.y; }
      else wv2[0] = W[(k + kk) * N + c0];
#pragma unroll
      for (int i = 0; i < RB; ++i) {
        const float av = ((const float*)&a[i])[kk];
#pragma unroll
        for (int j = 0; j < CB; ++j) acc[i][j] += av * wv2[j];
      }
    }
  }
  if (BAR) __syncthreads();
#pragma unroll
  for (int i = 0; i < RB; ++i)
#pragma unroll
    for (int j = 0; j < CB; ++j) OUT[(r0 + i) * OUTS + c0 + j] = acc[i][j] + bias[c0 + j];
}

template<int K, int N, int RB, int CB, int INS, int OUTS, bool GATHER, bool BAR>
__device__ __forceinline__ void dense_ex(const float* __restrict__ Wb, const float* __restrict__ Bb,
                                         const int* sOrd, const int* sExp,
                                         const float* IN, float* OUT, int tid) {
  constexpr int CBLK = N / CB;
  const int cb = tid % CBLK, rg = tid / CBLK;
  const int c0 = cb * CB, r0 = rg * RB;
  int e[RB], ir[RB];
#pragma unroll
  for (int i = 0; i < RB; ++i) { e[i] = sExp[r0 + i]; ir[i] = GATHER ? sOrd[r0 + i] : (r0 + i); }
  float acc[RB][CB];
#pragma unroll
  for (int i = 0; i < RB; ++i)
#pragma unroll
    for (int j = 0; j < CB; ++j) acc[i][j] = 0.f;
  const float* Wp[RB];
#pragma unroll
  for (int i = 0; i < RB; ++i) Wp[i] = Wb + (size_t)e[i] * K * N;
  for (int k = 0; k < K; k += 4) {
    float4 a[RB];
#pragma unroll
    for (int i = 0; i < RB; ++i) a[i] = *(const float4*)(IN + ir[i] * INS + k);
#pragma unroll
    for (int kk = 0; kk < 4; ++kk) {
#pragma unroll
      for (int i = 0; i < RB; ++i) {
        float wv2[CB];
        if constexpr (CB == 2) { float2 wv = *(const float2*)(Wp[i] + (k + kk) * N + c0); wv2[0] = wv.x; wv2[1] = wv.y; }
        else wv2[0] = Wp[i][(k + kk) * N + c0];
        const float av = ((const float*)&a[i])[kk];
#pragma unroll
        for (int j = 0; j < CB; ++j) acc[i][j] += av * wv2[j];
      }
    }
  }
  if (BAR) __syncthreads();
#pragma unroll
  for (int i = 0; i < RB; ++i)
#pragma unroll
    for (int j = 0; j < CB; ++j) OUT[(r0 + i) * OUTS + c0 + j] = acc[i][j] + Bb[e[i] * N + c0 + j];
}

template<int N, int S, bool RELU>
__device__ __forceinline__ void ln_rows(float* buf, const float* __restrict__ g,
                                        const float* __restrict__ b, int tid) {
  const int r = tid >> 4, j = tid & 15;
  float* rp = buf + r * S;
  float s = 0.f;
  for (int c = j; c < N; c += 16) s += rp[c];
#pragma unroll
  for (int m = 8; m; m >>= 1) s += __shfl_xor(s, m);
  const float mean = s * (1.f / N);
  float v = 0.f;
  for (int c = j; c < N; c += 16) { const float d = rp[c] - mean; v += d * d; }
#pragma unroll
  for (int m = 8; m; m >>= 1) v += __shfl_xor(v, m);
  const float inv = 1.f / sqrtf(v * (1.f / N) + 1e-5f);
  for (int c = j; c < N; c += 16) {
    const float y = (rp[c] - mean) * inv * g[c] + b[c];
    rp[c] = RELU ? fmaxf(y, 0.f) : y;
  }
}

template<int N, int S>
__device__ __forceinline__ void ln_rows_ex(float* buf, const float* __restrict__ Gb,
                                           const float* __restrict__ Bb, const int* sExp, int tid) {
  const int r = tid >> 4, j = tid & 15;
  const int e = sExp[r];
  const float* g = Gb + e * N;
  const float* b = Bb + e * N;
  float* rp = buf + r * S;
  float s = 0.f;
  for (int c = j; c < N; c += 16) s += rp[c];
#pragma unroll
  for (int m = 8; m; m >>= 1) s += __shfl_xor(s, m);
  const float mean = s * (1.f / N);
  float v = 0.f;
  for (int c = j; c < N; c += 16) { const float d = rp[c] - mean; v += d * d; }
#pragma unroll
  for (int m = 8; m; m >>= 1) v += __shfl_xor(v, m);
  const float inv = 1.f / sqrtf(v * (1.f / N) + 1e-5f);
  for (int c = j; c < N; c += 16) {
    const float y = (rp[c] - mean) * inv * g[c] + b[c];
    rp[c] = fmaxf(y, 0.f);
  }
}

__global__ void __launch_bounds__(256)
moe_fused(const float* __restrict__ x,
          const float* __restrict__ bW1, const float* __restrict__ bb1,
          const float* __restrict__ bg1, const float* __restrict__ bbt1,
          const float* __restrict__ bW2, const float* __restrict__ bb2,
          const float* __restrict__ bg2, const float* __restrict__ bbt2,
          const float* __restrict__ cW1, const float* __restrict__ cb1,
          const float* __restrict__ cg1, const float* __restrict__ cbt1,
          const float* __restrict__ cW2, const float* __restrict__ cb2,
          const float* __restrict__ cg2, const float* __restrict__ cbt2,
          const float* __restrict__ chW, const float* __restrict__ chb,
          const float* __restrict__ rW1, const float* __restrict__ rb1,
          const float* __restrict__ rg1, const float* __restrict__ rbt1,
          const float* __restrict__ rW2, const float* __restrict__ rb2,
          const float* __restrict__ rg2, const float* __restrict__ rbt2,
          const float* __restrict__ rhW, const float* __restrict__ rhb,
          float* __restrict__ out) {
  __shared__ __align__(16) float smf[F_SMEM];
  const int tid = threadIdx.x;
  const int row0 = blockIdx.x * TILE;
  float* sH = smf + F_OFF_H;
  float* sS = smf + F_OFF_S;
  float* sC1 = smf + F_OFF_C1;
  float* sC2 = smf + F_OFF_C2;
  float* sE2 = smf + F_OFF_E2;
  float* sE1 = smf + F_OFF_E1;
  float* sX = smf + F_OFF_X;
  float* sHd = smf + F_OFF_HEAD;
  float* sRH = smf + F_OFF_RH;
  int* sOrd = (int*)(smf + F_OFF_INT);
  int* sExp = sOrd + TILE;

  if (tid < TILE * 5) {
    const int r = tid / 5, k = tid % 5;
    sX[r * 8 + k] = x[(size_t)(row0 + r) * 5 + k];
  }
  __syncthreads();
  for (int o = tid; o < TILE * 512; o += 256) {
    const int r = o >> 9, c = o & 511;
    float a = 0.f;
#pragma unroll
    for (int k = 0; k < 5; ++k) a += sX[r * 8 + k] * bW1[k * 512 + c];
    sH[r * S_H + c] = a + bb1[c];
  }
  __syncthreads();
  ln_rows<512, S_H, true>(sH, bg1, bbt1, tid);
  __syncthreads();
  dense<512, 256, 8, 2, S_H, S_Sf, false>(bW2, bb2, sH, sS, tid);
  __syncthreads();
  ln_rows<256, S_Sf, true>(sS, bg2, bbt2, tid);
  __syncthreads();
  dense<256, 128, 8, 1, S_Sf, S_N, false>(cW1, cb1, sS, sC1, tid);
  __syncthreads();
  ln_rows<128, S_N, true>(sC1, cg1, cbt1, tid);
  __syncthreads();
  dense<128, 128, 8, 1, S_N, S_N, false>(cW2, cb2, sC1, sC2, tid);
  __syncthreads();
  ln_rows<128, S_N, true>(sC2, cg2, cbt2, tid);
  __syncthreads();
  if (tid < TILE * 4) {
    const int r = tid >> 2, n = tid & 3;
    float a = 0.f;
    for (int k = 0; k < 128; ++k) a += sC2[r * S_N + k] * chW[k * 4 + n];
    a += chb[n];
    sHd[r * 4 + n] = a;
    out[(size_t)(row0 + r) * 4 + n] = a;
  }
  __syncthreads();
  if (tid == 0) {
    int idx[TILE];
    for (int r = 0; r < TILE; ++r) {
      float best = sHd[r * 4]; int bi = 0;
      for (int n = 1; n < 4; ++n) {
        const float vv = sHd[r * 4 + n];
        if (vv > best) { best = vv; bi = n; }
      }
      idx[r] = bi;
    }
    int p = 0;
    for (int e = 0; e < 4; ++e)
      for (int r = 0; r < TILE; ++r)
        if (idx[r] == e) { sOrd[p] = r; sExp[p] = e; ++p; }
  }
  __syncthreads();
  dense_ex<256, 128, 4, 2, S_Sf, S_N, true, true>(rW1, rb1, sOrd, sExp, sS, sE1, tid);
  __syncthreads();
  ln_rows_ex<128, S_N>(sE1, rg1, rbt1, sExp, tid);
  __syncthreads();
  dense_ex<128, 128, 4, 2, S_N, S_N, false, false>(rW2, rb2, sOrd, sExp, sE1, sE2, tid);
  __syncthreads();
  ln_rows_ex<128, S_N>(sE2, rg2, rbt2, sExp, tid);
  __syncthreads();
  if (tid < TILE * 3) {
    const int rr = tid / 3, n = tid % 3;
    const int e = sExp[rr];
    float a = 0.f;
    for (int k = 0; k < 128; ++k) a += sE2[rr * S_N + k] * rhW[(size_t)(e * 128 + k) * 3 + n];
    a += rhb[e * 3 + n];
    sRH[rr * 4 + n] = a;
  }
  __syncthreads();
  if (tid < TILE) {
    const int rr = tid;
    const float v0 = sRH[rr * 4 + 0];
    const float v1 = sRH[rr * 4 + 1];
    const float v2 = sRH[rr * 4 + 2];
    const float mx = fmaxf(v0, fmaxf(v1, v2));
    const float e0 = expf(v0 - mx), e1 = expf(v1 - mx), e2 = expf(v2 - mx);
    const float inv = 1.f / (e0 + e1 + e2);
    const size_t orow = (size_t)row0 + sOrd[rr];
    float* po = out + (size_t)B_ROWS * 4 + orow * 3;
    po[0] = e0 * inv; po[1] = e1 * inv; po[2] = e2 * inv;
  }
}

extern "C" void kernel_launch(void* const* d_in, const int* in_sizes, int n_in,
                              void* d_out, int out_size, void* d_ws, size_t ws_size,
                              hipStream_t stream) {
  (void)in_sizes; (void)n_in; (void)out_size;
  const float* p[29];
  for (int i = 0; i < 29; ++i) p[i] = (const float*)d_in[i];
  if (ws_size >= WS_NEEDED) {
    float* wsf = (float*)((char*)d_ws + (size_t)WS_FRAGS * 16);
    pack_weights<<<197, 256, 0, stream>>>(p[1], p[5], p[9], p[13], p[19], p[23],
                                          p[17], p[27], (uint4*)d_ws);
    pack_stats<<<1, 256, 0, stream>>>(p[1], p[2], wsf);
    moe_v7<<<B_ROWS / R_TILE, NTH, 0, stream>>>(
        p[0],
        p[2], p[3], p[4],
        p[6], p[7], p[8],
        p[10], p[11], p[12],
        p[14], p[15], p[16],
        p[17], p[18],
        p[20], p[21], p[22],
        p[24], p[25], p[26],
        p[28],
        (float*)d_out, (const uint4*)d_ws, wsf);
  } else {
    moe_fused<<<B_ROWS / TILE, 256, 0, stream>>>(
        p[0], p[1], p[2], p[3], p[4], p[5], p[6], p[7], p[8],
        p[9], p[10], p[11], p[12], p[13], p[14], p[15], p[16],
        p[17], p[18], p[19], p[20], p[21], p[22], p[23], p[24],
        p[25], p[26], p[27], p[28],
        (float*)d_out);
  }
}

// Round 9
// 3075.432 us; speedup vs baseline: 1.0301x; 1.0301x over previous
//
#include <hip/hip_runtime.h>
#include <math.h>

typedef unsigned int u32;
typedef unsigned short u16;
typedef short bf16x8 __attribute__((ext_vector_type(8)));
typedef float f32x4 __attribute__((ext_vector_type(4)));

#define B_ROWS 131072
#define R_TILE 64
#define NTH 512

// ---------------- packed-weight layout in d_ws (16B frag units) ----------------
#define L0H 0        // bW1 K=32(pad) N=512: ct=32, ks=1
#define L0N 2048
#define L1H 4096     // bW2 K=512 N=256: ct=16, ks=16
#define L1N 16384
#define L2H 36864    // cW1 K=256 N=128: ct=8, ks=8
#define L2N 4096
#define L3H 45056    // cW2 K=128 N=128: ct=8, ks=4
#define L3N 2048
#define L4H 49152    // rW1 concat K=256 N=512: ct=32, ks=8
#define L4N 16384
#define L5H 81920    // rW2 concat K=128 N=512: ct=32, ks=4
#define L5N 8192
#define L6H 98304    // chW K=128 N=16(pad): ct=1, ks=4 (unused by main kernel)
#define L6N 256
#define L7H 98816    // rhW per-expert K=128 N=16(cols 0..2 valid): ct=expert(4), ks=4
#define L7N 1024
#define WS_FRAGS 100864
#define WS_NEEDED ((size_t)WS_FRAGS * 16 + 128)

// ---------------- LDS arena ----------------
// u16 offsets (activation planes; each buffer = [hi plane][lo plane])
#define U_S      0       // s [64][264] x2 planes = 33792 u16 (never overwritten)
#define S_STR    264
#define S_PLANE  16896
#define U_B1     33792   // chunk h -> c2 [64][136] x2 = 17408 u16
#define U_B2     51200   // c1 [64][136] x2 = 17408 u16
#define B_STR    136
#define B_PLANE  8704
#define U_X      68608   // x [64][40] x2 = 5120 u16
#define X_STR    40
#define X_PLANE  2560
// reg-phase e1/e2 ping-pong buffer: [4 experts][32 rows][136] x2 planes = 34816 u16
// occupies exactly B1+B2 ([33792, 68608)), both dead after the class head.
#define E_OFF    33792
#define E_STR2   136
#define E_PLANE  17408
// dword (f32) offsets
#define WP_DW    36864   // wave stats partials [8][64][2] = 1024 dw (shared layers only)
#define RS_DW    37888   // row stats [64][2] (+ spare) = 512 dw
#define LG_DW    38400   // class logits [64][4] = 256 dw
#define IDX_DW   38656   // argmax [64]
#define RH_DW    38720   // chW staged (512 f32) -> later reg head out [4][64][4] = 1024 dw
#define SMEM_DW  39744   // 158,976 B

__device__ __forceinline__ u16 bf16_rne(float f) {
  u32 u = __float_as_uint(f);
  u32 r = u + 0x7fffu + ((u >> 16) & 1u);
  return (u16)(r >> 16);
}
__device__ __forceinline__ f32x4 mfma16(bf16x8 a, bf16x8 b, f32x4 c) {
  return __builtin_amdgcn_mfma_f32_16x16x32_bf16(a, b, c, 0, 0, 0);
}

// ---------------- weight pre-pack kernel (RNE hi/lo planes, frag layout) ----------------
__global__ void __launch_bounds__(256) pack_weights(
    const float* __restrict__ bW1, const float* __restrict__ bW2,
    const float* __restrict__ cW1, const float* __restrict__ cW2,
    const float* __restrict__ rW1, const float* __restrict__ rW2,
    const float* __restrict__ chW, const float* __restrict__ rhW,
    uint4* __restrict__ ws) {
  int t = blockIdx.x * 256 + threadIdx.x;  // 0..50431
  int base, nlanes, layer;
  if (t < 2048)       { layer = 0; base = L0H; nlanes = L0N; }
  else if (t < 18432) { layer = 1; base = L1H; nlanes = L1N; t -= 2048; }
  else if (t < 22528) { layer = 2; base = L2H; nlanes = L2N; t -= 18432; }
  else if (t < 24576) { layer = 3; base = L3H; nlanes = L3N; t -= 22528; }
  else if (t < 40960) { layer = 4; base = L4H; nlanes = L4N; t -= 24576; }
  else if (t < 49152) { layer = 5; base = L5H; nlanes = L5N; t -= 40960; }
  else if (t < 49408) { layer = 6; base = L6H; nlanes = L6N; t -= 49152; }
  else                { layer = 7; base = L7H; nlanes = L7N; t -= 49408; }
  const int ksteps = (layer == 0) ? 1 : (layer == 1) ? 16 : (layer == 2) ? 8 :
                     (layer == 3) ? 4 : (layer == 4) ? 8 : (layer == 5) ? 4 : 4;
  const int li = t;
  const int lane = li & 63;
  const int fi = li >> 6;
  const int ct = fi / ksteps;
  const int ks = fi - ct * ksteps;
  const int g = lane >> 4;
  const int col = ct * 16 + (lane & 15);
  const int kb = ks * 32 + 8 * g;
  float w[8];
#pragma unroll
  for (int e = 0; e < 8; ++e) {
    const int k = kb + e;
    float v;
    if (layer == 0)      v = (k < 5) ? bW1[k * 512 + col] : 0.f;
    else if (layer == 1) v = bW2[k * 256 + col];
    else if (layer == 2) v = cW1[k * 128 + col];
    else if (layer == 3) v = cW2[k * 128 + col];
    else if (layer == 4) v = rW1[((col >> 7) * 256 + k) * 128 + (col & 127)];
    else if (layer == 5) v = rW2[((col >> 7) * 128 + k) * 128 + (col & 127)];
    else if (layer == 6) v = (col < 4) ? chW[k * 4 + col] : 0.f;
    else {
      const int ex = col >> 4, cl = col & 15;
      v = (cl < 3) ? rhW[(ex * 128 + k) * 3 + cl] : 0.f;
    }
    w[e] = v;
  }
  u16 hi[8], lo[8];
#pragma unroll
  for (int e = 0; e < 8; ++e) {
    hi[e] = bf16_rne(w[e]);
    lo[e] = bf16_rne(w[e] - __uint_as_float((u32)hi[e] << 16));
  }
  uint4 H, L;
  H.x = (u32)hi[0] | ((u32)hi[1] << 16); H.y = (u32)hi[2] | ((u32)hi[3] << 16);
  H.z = (u32)hi[4] | ((u32)hi[5] << 16); H.w = (u32)hi[6] | ((u32)hi[7] << 16);
  L.x = (u32)lo[0] | ((u32)lo[1] << 16); L.y = (u32)lo[2] | ((u32)lo[3] << 16);
  L.z = (u32)lo[4] | ((u32)lo[5] << 16); L.w = (u32)lo[6] | ((u32)lo[7] << 16);
  ws[base + li] = H;
  ws[base + nlanes + li] = L;
}

// ---------------- LN(h) closed-form constants (quadratic form in x) ----------------
__global__ void __launch_bounds__(256) pack_stats(const float* __restrict__ bW1,
                                                  const float* __restrict__ bb1,
                                                  float* __restrict__ wsf) {
  __shared__ float red[27 * 256];
  const int t = threadIdx.x;
  float part[27];
#pragma unroll
  for (int j = 0; j < 27; ++j) part[j] = 0.f;
  for (int c = t; c < 512; c += 256) {
    float wv[5];
#pragma unroll
    for (int k = 0; k < 5; ++k) wv[k] = bW1[k * 512 + c];
    const float bc = bb1[c];
#pragma unroll
    for (int k = 0; k < 5; ++k) part[k] += wv[k];
    part[5] += bc;
    int p = 0;
#pragma unroll
    for (int k = 0; k < 5; ++k)
#pragma unroll
      for (int k2 = 0; k2 <= k; ++k2) part[6 + p++] += wv[k] * wv[k2];
#pragma unroll
    for (int k = 0; k < 5; ++k) part[21 + k] += wv[k] * bc;
    part[26] += bc * bc;
  }
#pragma unroll
  for (int j = 0; j < 27; ++j) red[j * 256 + t] = part[j];
  __syncthreads();
  if (t < 27) {
    float s = 0.f;
    for (int i = 0; i < 256; ++i) s += red[t * 256 + i];
    s *= (1.f / 512.f);
    if (t >= 6 && t < 21) {
      const int p = t - 6;
      const bool diag = (p == 0 || p == 2 || p == 5 || p == 9 || p == 14);
      if (!diag) s *= 2.f;
    }
    if (t >= 21 && t < 26) s *= 2.f;
    wsf[t] = s;
  }
}

// ---------------- main kernel building blocks ----------------
// GEMM on u16 bf16 planes in LDS: acc += Ahi*Whi [+ Alo*Whi] [+ Ahi*Wlo]
// NOTE: ks loop is a PLAIN for (R3's proven pattern). R4-R7 had `#pragma unroll`
// here, which hoisted all weight loads -> ~2.8KB/thread scratch spill -> 6 GB
// of HBM spill traffic per dispatch (R7 counters: FETCH 2.9GB, WRITE 2.9GB).
template<int KSTEPS, int CTS, int RGS, int LKS, bool ALO, bool WLO>
__device__ __forceinline__ void gemm16(const u16* smu, int a_off, int a_str, int a_plane,
                                       const uint4* __restrict__ wh,
                                       const uint4* __restrict__ wl,
                                       f32x4 (&acc)[RGS][CTS]) {
  const int lane = threadIdx.x & 63;
  const int l15 = lane & 15, g = lane >> 4;
  for (int ks = 0; ks < KSTEPS; ++ks) {
    bf16x8 ah[RGS], al[RGS];
#pragma unroll
    for (int rg = 0; rg < RGS; ++rg) {
      const int ao = a_off + (rg * 16 + l15) * a_str + ks * 32 + 8 * g;
      ah[rg] = *(const bf16x8*)(smu + ao);
      if (ALO) al[rg] = *(const bf16x8*)(smu + ao + a_plane);
    }
#pragma unroll
    for (int c = 0; c < CTS; ++c) {
      bf16x8 bh = __builtin_bit_cast(bf16x8, wh[(c * LKS + ks) * 64]);
#pragma unroll
      for (int rg = 0; rg < RGS; ++rg) acc[rg][c] = mfma16(ah[rg], bh, acc[rg][c]);
      if (ALO) {
#pragma unroll
        for (int rg = 0; rg < RGS; ++rg) acc[rg][c] = mfma16(al[rg], bh, acc[rg][c]);
      }
      if (WLO) {
        bf16x8 bl = __builtin_bit_cast(bf16x8, wl[(c * LKS + ks) * 64]);
#pragma unroll
        for (int rg = 0; rg < RGS; ++rg) acc[rg][c] = mfma16(ah[rg], bl, acc[rg][c]);
      }
    }
  }
}

template<int RGS, int CTS>
__device__ __forceinline__ void zero_acc(f32x4 (&acc)[RGS][CTS]) {
#pragma unroll
  for (int rg = 0; rg < RGS; ++rg)
#pragma unroll
    for (int c = 0; c < CTS; ++c) acc[rg][c] = (f32x4){0.f, 0.f, 0.f, 0.f};
}

// bias added AFTER the GEMM (R3 rounding order — class path depends on this)
template<int RGS, int CTS>
__device__ __forceinline__ void add_bias(f32x4 (&acc)[RGS][CTS],
                                         const float* __restrict__ bias, int col0) {
  const int l15 = threadIdx.x & 15;
#pragma unroll
  for (int c = 0; c < CTS; ++c) {
    const float bv = bias[col0 + c * 16 + l15];
#pragma unroll
    for (int rg = 0; rg < RGS; ++rg)
#pragma unroll
      for (int i = 0; i < 4; ++i) acc[rg][c][i] += bv;
  }
}

template<int RGS, int CTS>
__device__ __forceinline__ void init_bias(f32x4 (&acc)[RGS][CTS],
                                          const float* __restrict__ bias, int col0) {
  const int l15 = threadIdx.x & 15;
#pragma unroll
  for (int c = 0; c < CTS; ++c) {
    const float bv = bias[col0 + c * 16 + l15];
#pragma unroll
    for (int rg = 0; rg < RGS; ++rg)
#pragma unroll
      for (int i = 0; i < 4; ++i) acc[rg][c][i] = bv;
  }
}

// per-wave LN stats partials -> WP[w][row][2]  (shared layers)
template<int RGS, int CTS>
__device__ __forceinline__ void stats_partial(const f32x4 (&acc)[RGS][CTS], float* smf, int w) {
  const int lane = threadIdx.x & 63;
  const int l15 = lane & 15, g = lane >> 4;
  float s1[RGS][4], s2[RGS][4];
#pragma unroll
  for (int rg = 0; rg < RGS; ++rg)
#pragma unroll
    for (int i = 0; i < 4; ++i) {
      float a = 0.f, b = 0.f;
#pragma unroll
      for (int c = 0; c < CTS; ++c) { const float v = acc[rg][c][i]; a += v; b += v * v; }
      s1[rg][i] = a; s2[rg][i] = b;
    }
#pragma unroll
  for (int m = 1; m <= 8; m <<= 1)
#pragma unroll
    for (int rg = 0; rg < RGS; ++rg)
#pragma unroll
      for (int i = 0; i < 4; ++i) {
        s1[rg][i] += __shfl_xor(s1[rg][i], m);
        s2[rg][i] += __shfl_xor(s2[rg][i], m);
      }
  if (l15 == 0) {
#pragma unroll
    for (int rg = 0; rg < RGS; ++rg)
#pragma unroll
      for (int i = 0; i < 4; ++i) {
        const int row = rg * 16 + 4 * g + i;
        smf[WP_DW + (w * 64 + row) * 2]     = s1[rg][i];
        smf[WP_DW + (w * 64 + row) * 2 + 1] = s2[rg][i];
      }
  }
}

template<int N>
__device__ __forceinline__ void combine_shared(float* smf, int t) {
  if (t < 64) {
    float a = 0.f, b = 0.f;
#pragma unroll
    for (int w = 0; w < 8; ++w) {
      a += smf[WP_DW + (w * 64 + t) * 2];
      b += smf[WP_DW + (w * 64 + t) * 2 + 1];
    }
    const float mean = a * (1.f / N);
    const float var = b * (1.f / N) - mean * mean;
    smf[RS_DW + t * 2]     = mean;
    smf[RS_DW + t * 2 + 1] = rsqrtf(fmaxf(var, 0.f) + 1e-5f);
  }
}

// in-register LN stats over 128 cols (RGS=1, CTS=8)
template<int CTS>
__device__ __forceinline__ void stats_reg(const f32x4 (&acc)[1][CTS],
                                          float (&mean)[4], float (&inv)[4]) {
#pragma unroll
  for (int i = 0; i < 4; ++i) {
    float a = 0.f, b = 0.f;
#pragma unroll
    for (int c = 0; c < CTS; ++c) { const float v = acc[0][c][i]; a += v; b += v * v; }
#pragma unroll
    for (int m = 1; m <= 8; m <<= 1) { a += __shfl_xor(a, m); b += __shfl_xor(b, m); }
    const float mn = a * (1.f / 128.f);
    const float var = b * (1.f / 128.f) - mn * mn;
    mean[i] = mn;
    inv[i] = rsqrtf(fmaxf(var, 0.f) + 1e-5f);
  }
}

// normalize + ReLU + RNE double-split PAIR store (stats from registers)
template<int CTS>
__device__ __forceinline__ void nps_reg(const f32x4 (&acc)[1][CTS],
    const float (&mean)[4], const float (&inv)[4],
    const float* __restrict__ gamma, const float* __restrict__ beta, int col0,
    u16* smu, int dst, int dstr, int dplane) {
  const int lane = threadIdx.x & 63;
  const int l15 = lane & 15, g = lane >> 4;
#pragma unroll
  for (int c = 0; c < CTS; ++c) {
    const float gv = gamma[col0 + c * 16 + l15];
    const float bv = beta[col0 + c * 16 + l15];
#pragma unroll
    for (int i = 0; i < 4; ++i) {
      float y = fmaxf((acc[0][c][i] - mean[i]) * inv[i] * gv + bv, 0.f);
      const u16 h = bf16_rne(y);
      const int ad = dst + (4 * g + i) * dstr + c * 16 + l15;
      smu[ad] = h;
      smu[ad + dplane] = bf16_rne(y - __uint_as_float((u32)h << 16));
    }
  }
}

// normalize + ReLU + RNE double-split store, stats from LDS (shared layers)
template<int RGS, int CTS>
__device__ __forceinline__ void nps(const f32x4 (&acc)[RGS][CTS], u16* smu, float* smf,
                                    int st_dw, const float* __restrict__ gamma,
                                    const float* __restrict__ beta, int col0,
                                    int dst, int dstr, int dplane, int dcol0) {
  const int lane = threadIdx.x & 63;
  const int l15 = lane & 15, g = lane >> 4;
  float gv[CTS], bv[CTS];
#pragma unroll
  for (int c = 0; c < CTS; ++c) {
    gv[c] = gamma[col0 + c * 16 + l15];
    bv[c] = beta[col0 + c * 16 + l15];
  }
#pragma unroll
  for (int rg = 0; rg < RGS; ++rg)
#pragma unroll
    for (int i = 0; i < 4; ++i) {
      const int row = rg * 16 + 4 * g + i;
      const float mean = smf[st_dw + row * 2];
      const float inv  = smf[st_dw + row * 2 + 1];
#pragma unroll
      for (int c = 0; c < CTS; ++c) {
        float y = fmaxf((acc[rg][c][i] - mean) * inv * gv[c] + bv[c], 0.f);
        const u16 h = bf16_rne(y);
        const int ad = dst + row * dstr + dcol0 + c * 16 + l15;
        smu[ad] = h;
        smu[ad + dplane] = bf16_rne(y - __uint_as_float((u32)h << 16));
      }
    }
}

__global__ void __launch_bounds__(NTH, 1) moe_v8(
    const float* __restrict__ x,
    const float* __restrict__ bb1, const float* __restrict__ bg1, const float* __restrict__ bbt1,
    const float* __restrict__ bb2, const float* __restrict__ bg2, const float* __restrict__ bbt2,
    const float* __restrict__ cb1, const float* __restrict__ cg1, const float* __restrict__ cbt1,
    const float* __restrict__ cb2, const float* __restrict__ cg2, const float* __restrict__ cbt2,
    const float* __restrict__ chW, const float* __restrict__ chb,
    const float* __restrict__ rb1, const float* __restrict__ rg1, const float* __restrict__ rbt1,
    const float* __restrict__ rb2, const float* __restrict__ rg2, const float* __restrict__ rbt2,
    const float* __restrict__ rhb,
    float* __restrict__ out, const uint4* __restrict__ wp, const float* __restrict__ cs) {
  __shared__ __align__(16) u32 sm[SMEM_DW];
  u16* smu = (u16*)sm;
  float* smf = (float*)sm;
  const int t = threadIdx.x;
  const int w = t >> 6;
  const int lane = t & 63;
  const int row0 = blockIdx.x * R_TILE;

  // ---- stage chW fp32 into RH region (free until reg-head) ----
  for (int i = t; i < 512; i += NTH) smf[RH_DW + i] = chW[i];

  // ---- stage x (RNE double-split pair, K zero-padded to 32) ----
  {
    const int r = t >> 3, k0 = (t & 7) * 4;
#pragma unroll
    for (int i = 0; i < 4; ++i) {
      const int k = k0 + i;
      const float v = (k < 5) ? x[(size_t)(row0 + r) * 5 + k] : 0.f;
      const u16 h = bf16_rne(v);
      smu[U_X + r * X_STR + k] = h;
      smu[U_X + X_PLANE + r * X_STR + k] = bf16_rne(v - __uint_as_float((u32)h << 16));
    }
  }
  // ---- closed-form LN(h) stats ----
  if (t < 64) {
    float xv[5];
#pragma unroll
    for (int k = 0; k < 5; ++k) xv[k] = x[(size_t)(row0 + t) * 5 + k];
    float mean = cs[5];
#pragma unroll
    for (int k = 0; k < 5; ++k) mean += xv[k] * cs[k];
    float e2 = cs[26];
    int p = 0;
#pragma unroll
    for (int k = 0; k < 5; ++k) {
      e2 += xv[k] * cs[21 + k];
#pragma unroll
      for (int k2 = 0; k2 <= k; ++k2) e2 += cs[6 + p++] * xv[k] * xv[k2];
    }
    const float var = e2 - mean * mean;
    smf[RS_DW + t * 2]     = mean;
    smf[RS_DW + t * 2 + 1] = rsqrtf(fmaxf(var, 0.f) + 1e-5f);
  }
  __syncthreads();

  // ---- phase 1: L1 -> LN -> pack -> partial L2 over 128-col chunks (R3 order) ----
  f32x4 accS[4][2];
  zero_acc<4, 2>(accS);
  for (int kc = 0; kc < 4; ++kc) {
    f32x4 acc1[4][1];
    zero_acc<4, 1>(acc1);
    gemm16<1, 1, 4, 1, true, true>(smu, U_X, X_STR, X_PLANE,
        wp + L0H + (kc * 8 + w) * 64 + lane,
        wp + L0H + L0N + (kc * 8 + w) * 64 + lane, acc1);
    add_bias<4, 1>(acc1, bb1, kc * 128 + w * 16);
    nps<4, 1>(acc1, smu, smf, RS_DW, bg1, bbt1, kc * 128 + w * 16,
              U_B1, B_STR, B_PLANE, w * 16);
    __syncthreads();
    gemm16<4, 2, 4, 16, true, true>(smu, U_B1, B_STR, B_PLANE,
        wp + L1H + (w * 32 + kc * 4) * 64 + lane,
        wp + L1H + L1N + (w * 32 + kc * 4) * 64 + lane, accS);
    __syncthreads();
  }

  // ---- s: bias-after + in-reg LN -> pair pack ----
  add_bias<4, 2>(accS, bb2, w * 32);
  stats_partial<4, 2>(accS, smf, w);
  __syncthreads();
  combine_shared<256>(smf, t);
  __syncthreads();
  nps<4, 2>(accS, smu, smf, RS_DW, bg2, bbt2, w * 32, U_S, S_STR, S_PLANE, w * 32);
  __syncthreads();

  // ---- class expert L1 ----
  {
    f32x4 accC[4][1];
    zero_acc<4, 1>(accC);
    gemm16<8, 1, 4, 8, true, true>(smu, U_S, S_STR, S_PLANE,
        wp + L2H + (w * 8) * 64 + lane, wp + L2H + L2N + (w * 8) * 64 + lane, accC);
    add_bias<4, 1>(accC, cb1, w * 16);
    stats_partial<4, 1>(accC, smf, w);
    __syncthreads();
    combine_shared<128>(smf, t);
    __syncthreads();
    nps<4, 1>(accC, smu, smf, RS_DW, cg1, cbt1, w * 16, U_B2, B_STR, B_PLANE, w * 16);
    __syncthreads();
  }

  // ---- class expert L2 -> c2 (buf1) ----
  {
    f32x4 accD[4][1];
    zero_acc<4, 1>(accD);
    gemm16<4, 1, 4, 4, true, true>(smu, U_B2, B_STR, B_PLANE,
        wp + L3H + (w * 4) * 64 + lane, wp + L3H + L3N + (w * 4) * 64 + lane, accD);
    add_bias<4, 1>(accD, cb2, w * 16);
    stats_partial<4, 1>(accD, smf, w);
    __syncthreads();
    combine_shared<128>(smf, t);
    __syncthreads();
    nps<4, 1>(accD, smu, smf, RS_DW, cg2, cbt2, w * 16, U_B1, B_STR, B_PLANE, w * 16);
    __syncthreads();
  }

  // ---- class head: scalar fp32 from c2 pair × chW (R3's exact recipe) ----
  {
    const int r = t >> 3, o = (t >> 1) & 3, q = t & 1;
    const u16* hp = smu + U_B1 + r * B_STR + q * 64;
    const u16* lp = hp + B_PLANE;
    float s = 0.f;
#pragma unroll
    for (int kk = 0; kk < 64; ++kk) {
      const float a = __uint_as_float((u32)hp[kk] << 16) +
                      __uint_as_float((u32)lp[kk] << 16);
      s += a * smf[RH_DW + (q * 64 + kk) * 4 + o];
    }
    s += __shfl_xor(s, 1);
    if (q == 0) {
      const float v = s + chb[o];
      smf[LG_DW + r * 4 + o] = v;
      out[(size_t)(row0 + r) * 4 + o] = v;
    }
  }
  __syncthreads();
  if (t < 64) {  // argmax (first max == jnp.argmax)
    float best = smf[LG_DW + t * 4];
    int bi = 0;
#pragma unroll
    for (int n = 1; n < 4; ++n) {
      const float v = smf[LG_DW + t * 4 + n];
      if (v > best) { best = v; bi = n; }
    }
    sm[IDX_DW + t] = (u32)bi;
  }

  // ---- reg experts: 2 row-halves, wave (wm2,wn): rows [32h+16wm2,+16) x expert wn ----
  // Full pair storage + 3-term GEMMs. e1/e2 ping-pong in E region (overlays B1/B2).
  const int wm2 = w >> 2, wn = w & 3;
#pragma unroll 1
  for (int h = 0; h < 2; ++h) {
    const int r0 = 32 * h + 16 * wm2;
    const int eb = E_OFF + (wn * 32 + 16 * wm2) * E_STR2;
    // L1: K=256 from s (pair, 3-term)
    {
      f32x4 aE[1][8];
      init_bias<1, 8>(aE, rb1, wn * 128);
      gemm16<8, 8, 1, 8, true, true>(smu, U_S + r0 * S_STR, S_STR, S_PLANE,
          wp + L4H + (wn * 64) * 64 + lane, wp + L4H + L4N + (wn * 64) * 64 + lane, aE);
      float mn[4], iv[4];
      stats_reg<8>(aE, mn, iv);
      __syncthreads();   // prior readers of E region (class head / prev-half head) done
      nps_reg<8>(aE, mn, iv, rg1, rbt1, wn * 128, smu, eb, E_STR2, E_PLANE);
    }
    __syncthreads();
    // L2: K=128 from e1 (pair, 3-term), in-place ping-pong
    {
      f32x4 aF[1][8];
      init_bias<1, 8>(aF, rb2, wn * 128);
      gemm16<4, 8, 1, 4, true, true>(smu, eb, E_STR2, E_PLANE,
          wp + L5H + (wn * 32) * 64 + lane, wp + L5H + L5N + (wn * 32) * 64 + lane, aF);
      float mn[4], iv[4];
      stats_reg<8>(aF, mn, iv);
      __syncthreads();   // all waves done reading e1
      nps_reg<8>(aF, mn, iv, rg2, rbt2, wn * 128, smu, eb, E_STR2, E_PLANE);
    }
    __syncthreads();
    // head: K=128 per-expert (pair, 3-term) -> RH[wn][row][0..2]
    {
      f32x4 aH[1][1];
      aH[0][0] = (f32x4){0.f, 0.f, 0.f, 0.f};
      gemm16<4, 1, 1, 4, true, true>(smu, eb, E_STR2, E_PLANE,
          wp + L7H + (wn * 4) * 64 + lane, wp + L7H + L7N + (wn * 4) * 64 + lane, aH);
      const int l15 = lane & 15, g = lane >> 4;
      if (l15 < 3) {
#pragma unroll
        for (int i = 0; i < 4; ++i)
          smf[RH_DW + (wn * 64 + r0 + 4 * g + i) * 4 + l15] = aH[0][0][i];
      }
    }
    __syncthreads();
  }

  // ---- gather chosen expert + softmax ----
  if (t < 64) {
    const int e = (int)sm[IDX_DW + t];
    const float v0 = smf[RH_DW + (e * 64 + t) * 4 + 0] + rhb[3 * e + 0];
    const float v1 = smf[RH_DW + (e * 64 + t) * 4 + 1] + rhb[3 * e + 1];
    const float v2 = smf[RH_DW + (e * 64 + t) * 4 + 2] + rhb[3 * e + 2];
    const float mx = fmaxf(v0, fmaxf(v1, v2));
    const float e0 = expf(v0 - mx), e1 = expf(v1 - mx), e2 = expf(v2 - mx);
    const float inv = 1.f / (e0 + e1 + e2);
    float* po = out + (size_t)B_ROWS * 4 + (size_t)(row0 + t) * 3;
    po[0] = e0 * inv; po[1] = e1 * inv; po[2] = e2 * inv;
  }
}

// =================== fallback: round-1 fp32 kernel (used if ws too small) ===================
#define TILE 16
#define S_H 516
#define S_Sf 260
#define S_N 132
#define F_OFF_H 0
#define F_OFF_C1 0
#define F_OFF_C2 2112
#define F_OFF_E2 4224
#define F_OFF_S 8256
#define F_OFF_E1 8256
#define F_OFF_X 12416
#define F_OFF_HEAD 12544
#define F_OFF_RH 12608
#define F_OFF_INT 12672
#define F_SMEM 12704

template<int K, int N, int RB, int CB, int INS, int OUTS, bool BAR>
__device__ __forceinline__ void dense(const float* __restrict__ W, const float* __restrict__ bias,
                                      const float* IN, float* OUT, int tid) {
  constexpr int CBLK = N / CB;
  const int cb = tid % CBLK, rg = tid / CBLK;
  const int c0 = cb * CB, r0 = rg * RB;
  float acc[RB][CB];
#pragma unroll
  for (int i = 0; i < RB; ++i)
#pragma unroll
    for (int j = 0; j < CB; ++j) acc[i][j] = 0.f;
  for (int k = 0; k < K; k += 4) {
    float4 a[RB];
#pragma unroll
    for (int i = 0; i < RB; ++i) a[i] = *(const float4*)(IN + (r0 + i) * INS + k);
#pragma unroll
    for (int kk = 0; kk < 4; ++kk) {
      float wv2[CB];
      if constexpr (CB == 2) { float2 wv = *(const float2*)(W + (k + kk) * N + c0); wv2[0] = wv.x; wv2[1] = wv.y; }
      else wv2[0] = W[(k + kk) * N + c0];
#pragma unroll
      for (int i = 0; i < RB; ++i) {
        const float av = ((const float*)&a[i])[kk];
#pragma unroll
        for (int j = 0; j < CB; ++j) acc[i][j] += av * wv2[j];
      }
    }
  }
  if (BAR) __syncthreads();
#pragma unroll
  for (int i = 0; i < RB; ++i)
#pragma unroll
    for (int j = 0; j < CB; ++j) OUT[(r0 + i) * OUTS + c0 + j] = acc[i][j] + bias[c0 + j];
}

template<int K, int N, int RB, int CB, int INS, int OUTS, bool GATHER, bool BAR>
__device__ __forceinline__ void dense_ex(const float* __restrict__ Wb, const float* __restrict__ Bb,
                                         const int* sOrd, const int* sExp,
                                         const float* IN, float* OUT, int tid) {
  constexpr int CBLK = N / CB;
  const int cb = tid % CBLK, rg = tid / CBLK;
  const int c0 = cb * CB, r0 = rg * RB;
  int e[RB], ir[RB];
#pragma unroll
  for (int i = 0; i < RB; ++i) { e[i] = sExp[r0 + i]; ir[i] = GATHER ? sOrd[r0 + i] : (r0 + i); }
  float acc[RB][CB];
#pragma unroll
  for (int i = 0; i < RB; ++i)
#pragma unroll
    for (int j = 0; j < CB; ++j) acc[i][j] = 0.f;
  const float* Wp[RB];
#pragma unroll
  for (int i = 0; i < RB; ++i) Wp[i] = Wb + (size_t)e[i] * K * N;
  for (int k = 0; k < K; k += 4) {
    float4 a[RB];
#pragma unroll
    for (int i = 0; i < RB; ++i) a[i] = *(const float4*)(IN + ir[i] * INS + k);
#pragma unroll
    for (int kk = 0; kk < 4; ++kk) {
#pragma unroll
      for (int i = 0; i < RB; ++i) {
        float wv2[CB];
        if constexpr (CB == 2) { float2 wv = *(const float2*)(Wp[i] + (k + kk) * N + c0); wv2[0] = wv.x; wv2[1] = wv.y; }
        else wv2[0] = Wp[i][(k + kk) * N + c0];
        const float av = ((const float*)&a[i])[kk];
#pragma unroll
        for (int j = 0; j < CB; ++j) acc[i][j] += av * wv2[j];
      }
    }
  }
  if (BAR) __syncthreads();
#pragma unroll
  for (int i = 0; i < RB; ++i)
#pragma unroll
    for (int j = 0; j < CB; ++j) OUT[(r0 + i) * OUTS + c0 + j] = acc[i][j] + Bb[e[i] * N + c0 + j];
}

template<int N, int S, bool RELU>
__device__ __forceinline__ void ln_rows(float* buf, const float* __restrict__ g,
                                        const float* __restrict__ b, int tid) {
  const int r = tid >> 4, j = tid & 15;
  float* rp = buf + r * S;
  float s = 0.f;
  for (int c = j; c < N; c += 16) s += rp[c];
#pragma unroll
  for (int m = 8; m; m >>= 1) s += __shfl_xor(s, m);
  const float mean = s * (1.f / N);
  float v = 0.f;
  for (int c = j; c < N; c += 16) { const float d = rp[c] - mean; v += d * d; }
#pragma unroll
  for (int m = 8; m; m >>= 1) v += __shfl_xor(v, m);
  const float inv = 1.f / sqrtf(v * (1.f / N) + 1e-5f);
  for (int c = j; c < N; c += 16) {
    const float y = (rp[c] - mean) * inv * g[c] + b[c];
    rp[c] = RELU ? fmaxf(y, 0.f) : y;
  }
}

template<int N, int S>
__device__ __forceinline__ void ln_rows_ex(float* buf, const float* __restrict__ Gb,
                                           const float* __restrict__ Bb, const int* sExp, int tid) {
  const int r = tid >> 4, j = tid & 15;
  const int e = sExp[r];
  const float* g = Gb + e * N;
  const float* b = Bb + e * N;
  float* rp = buf + r * S;
  float s = 0.f;
  for (int c = j; c < N; c += 16) s += rp[c];
#pragma unroll
  for (int m = 8; m; m >>= 1) s += __shfl_xor(s, m);
  const float mean = s * (1.f / N);
  float v = 0.f;
  for (int c = j; c < N; c += 16) { const float d = rp[c] - mean; v += d * d; }
#pragma unroll
  for (int m = 8; m; m >>= 1) v += __shfl_xor(v, m);
  const float inv = 1.f / sqrtf(v * (1.f / N) + 1e-5f);
  for (int c = j; c < N; c += 16) {
    const float y = (rp[c] - mean) * inv * g[c] + b[c];
    rp[c] = fmaxf(y, 0.f);
  }
}

__global__ void __launch_bounds__(256)
moe_fused(const float* __restrict__ x,
          const float* __restrict__ bW1, const float* __restrict__ bb1,
          const float* __restrict__ bg1, const float* __restrict__ bbt1,
          const float* __restrict__ bW2, const float* __restrict__ bb2,
          const float* __restrict__ bg2, const float* __restrict__ bbt2,
          const float* __restrict__ cW1, const float* __restrict__ cb1,
          const float* __restrict__ cg1, const float* __restrict__ cbt1,
          const float* __restrict__ cW2, const float* __restrict__ cb2,
          const float* __restrict__ cg2, const float* __restrict__ cbt2,
          const float* __restrict__ chW, const float* __restrict__ chb,
          const float* __restrict__ rW1, const float* __restrict__ rb1,
          const float* __restrict__ rg1, const float* __restrict__ rbt1,
          const float* __restrict__ rW2, const float* __restrict__ rb2,
          const float* __restrict__ rg2, const float* __restrict__ rbt2,
          const float* __restrict__ rhW, const float* __restrict__ rhb,
          float* __restrict__ out) {
  __shared__ __align__(16) float smf[F_SMEM];
  const int tid = threadIdx.x;
  const int row0 = blockIdx.x * TILE;
  float* sH = smf + F_OFF_H;
  float* sS = smf + F_OFF_S;
  float* sC1 = smf + F_OFF_C1;
  float* sC2 = smf + F_OFF_C2;
  float* sE2 = smf + F_OFF_E2;
  float* sE1 = smf + F_OFF_E1;
  float* sX = smf + F_OFF_X;
  float* sHd = smf + F_OFF_HEAD;
  float* sRH = smf + F_OFF_RH;
  int* sOrd = (int*)(smf + F_OFF_INT);
  int* sExp = sOrd + TILE;

  if (tid < TILE * 5) {
    const int r = tid / 5, k = tid % 5;
    sX[r * 8 + k] = x[(size_t)(row0 + r) * 5 + k];
  }
  __syncthreads();
  for (int o = tid; o < TILE * 512; o += 256) {
    const int r = o >> 9, c = o & 511;
    float a = 0.f;
#pragma unroll
    for (int k = 0; k < 5; ++k) a += sX[r * 8 + k] * bW1[k * 512 + c];
    sH[r * S_H + c] = a + bb1[c];
  }
  __syncthreads();
  ln_rows<512, S_H, true>(sH, bg1, bbt1, tid);
  __syncthreads();
  dense<512, 256, 8, 2, S_H, S_Sf, false>(bW2, bb2, sH, sS, tid);
  __syncthreads();
  ln_rows<256, S_Sf, true>(sS, bg2, bbt2, tid);
  __syncthreads();
  dense<256, 128, 8, 1, S_Sf, S_N, false>(cW1, cb1, sS, sC1, tid);
  __syncthreads();
  ln_rows<128, S_N, true>(sC1, cg1, cbt1, tid);
  __syncthreads();
  dense<128, 128, 8, 1, S_N, S_N, false>(cW2, cb2, sC1, sC2, tid);
  __syncthreads();
  ln_rows<128, S_N, true>(sC2, cg2, cbt2, tid);
  __syncthreads();
  if (tid < TILE * 4) {
    const int r = tid >> 2, n = tid & 3;
    float a = 0.f;
    for (int k = 0; k < 128; ++k) a += sC2[r * S_N + k] * chW[k * 4 + n];
    a += chb[n];
    sHd[r * 4 + n] = a;
    out[(size_t)(row0 + r) * 4 + n] = a;
  }
  __syncthreads();
  if (tid == 0) {
    int idx[TILE];
    for (int r = 0; r < TILE; ++r) {
      float best = sHd[r * 4]; int bi = 0;
      for (int n = 1; n < 4; ++n) {
        const float vv = sHd[r * 4 + n];
        if (vv > best) { best = vv; bi = n; }
      }
      idx[r] = bi;
    }
    int p = 0;
    for (int e = 0; e < 4; ++e)
      for (int r = 0; r < TILE; ++r)
        if (idx[r] == e) { sOrd[p] = r; sExp[p] = e; ++p; }
  }
  __syncthreads();
  dense_ex<256, 128, 4, 2, S_Sf, S_N, true, true>(rW1, rb1, sOrd, sExp, sS, sE1, tid);
  __syncthreads();
  ln_rows_ex<128, S_N>(sE1, rg1, rbt1, sExp, tid);
  __syncthreads();
  dense_ex<128, 128, 4, 2, S_N, S_N, false, false>(rW2, rb2, sOrd, sExp, sE1, sE2, tid);
  __syncthreads();
  ln_rows_ex<128, S_N>(sE2, rg2, rbt2, sExp, tid);
  __syncthreads();
  if (tid < TILE * 3) {
    const int rr = tid / 3, n = tid % 3;
    const int e = sExp[rr];
    float a = 0.f;
    for (int k = 0; k < 128; ++k) a += sE2[rr * S_N + k] * rhW[(size_t)(e * 128 + k) * 3 + n];
    a += rhb[e * 3 + n];
    sRH[rr * 4 + n] = a;
  }
  __syncthreads();
  if (tid < TILE) {
    const int rr = tid;
    const float v0 = sRH[rr * 4 + 0];
    const float v1 = sRH[rr * 4 + 1];
    const float v2 = sRH[rr * 4 + 2];
    const float mx = fmaxf(v0, fmaxf(v1, v2));
    const float e0 = expf(v0 - mx), e1 = expf(v1 - mx), e2 = expf(v2 - mx);
    const float inv = 1.f / (e0 + e1 + e2);
    const size_t orow = (size_t)row0 + sOrd[rr];
    float* po = out + (size_t)B_ROWS * 4 + orow * 3;
    po[0] = e0 * inv; po[1] = e1 * inv; po[2] = e2 * inv;
  }
}

extern "C" void kernel_launch(void* const* d_in, const int* in_sizes, int n_in,
                              void* d_out, int out_size, void* d_ws, size_t ws_size,
                              hipStream_t stream) {
  (void)in_sizes; (void)n_in; (void)out_size;
  const float* p[29];
  for (int i = 0; i < 29; ++i) p[i] = (const float*)d_in[i];
  if (ws_size >= WS_NEEDED) {
    float* wsf = (float*)((char*)d_ws + (size_t)WS_FRAGS * 16);
    pack_weights<<<197, 256, 0, stream>>>(p[1], p[5], p[9], p[13], p[19], p[23],
                                          p[17], p[27], (uint4*)d_ws);
    pack_stats<<<1, 256, 0, stream>>>(p[1], p[2], wsf);
    moe_v8<<<B_ROWS / R_TILE, NTH, 0, stream>>>(
        p[0],
        p[2], p[3], p[4],
        p[6], p[7], p[8],
        p[10], p[11], p[12],
        p[14], p[15], p[16],
        p[17], p[18],
        p[20], p[21], p[22],
        p[24], p[25], p[26],
        p[28],
        (float*)d_out, (const uint4*)d_ws, wsf);
  } else {
    moe_fused<<<B_ROWS / TILE, 256, 0, stream>>>(
        p[0], p[1], p[2], p[3], p[4], p[5], p[6], p[7], p[8],
        p[9], p[10], p[11], p[12], p[13], p[14], p[15], p[16],
        p[17], p[18], p[19], p[20], p[21], p[22], p[23], p[24],
        p[25], p[26], p[27], p[28],
        (float*)d_out);
  }
}

// Round 10
// 503.675 us; speedup vs baseline: 6.2900x; 6.1060x over previous
//
#include <hip/hip_runtime.h>
#include <math.h>

typedef unsigned int u32;
typedef unsigned short u16;
typedef short bf16x8 __attribute__((ext_vector_type(8)));
typedef float f32x4 __attribute__((ext_vector_type(4)));

#define B_ROWS 131072
#define R_TILE 64
#define NTH 512

// ---------------- packed-weight layout in d_ws (16B frag units) ----------------
#define L0H 0        // bW1 K=32(pad) N=512: ct=32, ks=1 -> 2048 frags/plane
#define L0N 2048
#define L1H 4096     // bW2 K=512 N=256: ct=16, ks=16 -> 16384
#define L1N 16384
#define L2H 36864    // cW1 K=256 N=128: ct=8, ks=8 -> 4096
#define L2N 4096
#define L3H 45056    // cW2 K=128 N=128: ct=8, ks=4 -> 2048
#define L3N 2048
#define L4H 49152    // rW1 concat K=256 N=512: ct=32, ks=8 -> 16384
#define L4N 16384
#define L5H 81920    // rW2 concat K=128 N=512: ct=32, ks=4 -> 8192
#define L5N 8192
#define WS_FRAGS 98304
#define WS_NEEDED ((size_t)WS_FRAGS * 16 + 128)   // + LN-stats constants (27 floats)

// ---------------- LDS arena (dword offsets), main kernel ----------------
#define A_X      0      // x packed [64][36] = 2304   (dead after phase1; inside E region)
#define A_CHUNK  2304   // h-chunk packed [64][132] = 8448 ; later c2 packed
#define A_S      10752  // s packed [64][260] = 16640
#define A_C1     27392  // c1 packed [64][132] = 8448  (ends 35840)
#define A_E      0      // e1/e2 packed concat [64][532] = 34048 (expert col off e*132)
#define A_WP     35840  // wave partials [8][64][2] = 1024
#define A_RS     36864  // row stats [4][64][2] = 512 (e=0 for shared layers; also hstats)
#define A_LG     37376  // class logits [64][4] = 256
#define A_IDX    37632  // argmax [64]
#define A_RH     37696  // reg head out [4][64][4] = 1024
#define SMEM_DW  38720  // 154880 B

#define SEL_HI 0x07060302u
#define SEL_LO 0x05040100u

__device__ __forceinline__ u16 bf16_rne(float f) {
  u32 u = __float_as_uint(f);
  u32 r = u + 0x7fffu + ((u >> 16) & 1u);
  return (u16)(r >> 16);
}
__device__ __forceinline__ u32 pack_split(float v) {
  u16 h = bf16_rne(v);
  float fh = __uint_as_float((u32)h << 16);
  u16 l = bf16_rne(v - fh);
  return ((u32)h << 16) | (u32)l;
}
__device__ __forceinline__ float unpack_hl(u32 d) {
  return __uint_as_float(d & 0xffff0000u) + __uint_as_float(d << 16);
}
__device__ __forceinline__ f32x4 mfma16(bf16x8 a, bf16x8 b, f32x4 c) {
  return __builtin_amdgcn_mfma_f32_16x16x32_bf16(a, b, c, 0, 0, 0);
}

// ---------------- weight pre-pack kernel (frag layout, hi/lo planes) ----------------
__global__ void __launch_bounds__(256) pack_weights(
    const float* __restrict__ bW1, const float* __restrict__ bW2,
    const float* __restrict__ cW1, const float* __restrict__ cW2,
    const float* __restrict__ rW1, const float* __restrict__ rW2,
    uint4* __restrict__ ws) {
  int t = blockIdx.x * 256 + threadIdx.x;  // 0..49151
  int base, nlanes, ksteps, layer;
  if (t < 2048)                { layer = 0; base = L0H; nlanes = L0N; ksteps = 1;  }
  else if (t < 2048+16384)     { layer = 1; base = L1H; nlanes = L1N; ksteps = 16; t -= 2048; }
  else if (t < 2048+16384+4096){ layer = 2; base = L2H; nlanes = L2N; ksteps = 8;  t -= 2048+16384; }
  else if (t < 2048+16384+4096+2048) { layer = 3; base = L3H; nlanes = L3N; ksteps = 4; t -= 2048+16384+4096; }
  else if (t < 2048+16384+4096+2048+16384) { layer = 4; base = L4H; nlanes = L4N; ksteps = 8; t -= 2048+16384+4096+2048; }
  else { layer = 5; base = L5H; nlanes = L5N; ksteps = 4; t -= 2048+16384+4096+2048+16384; }
  const int li = t;
  const int lane = li & 63;
  const int fi = li >> 6;
  const int ct = fi / ksteps;
  const int ks = fi - ct * ksteps;
  const int g = lane >> 4;
  const int col = ct * 16 + (lane & 15);
  const int kb = ks * 32 + 8 * g;
  float w[8];
#pragma unroll
  for (int e = 0; e < 8; ++e) {
    const int k = kb + e;
    float v;
    if (layer == 0)      v = (k < 5) ? bW1[k * 512 + col] : 0.f;
    else if (layer == 1) v = bW2[k * 256 + col];
    else if (layer == 2) v = cW1[k * 128 + col];
    else if (layer == 3) v = cW2[k * 128 + col];
    else if (layer == 4) v = rW1[((col >> 7) * 256 + k) * 128 + (col & 127)];
    else                 v = rW2[((col >> 7) * 128 + k) * 128 + (col & 127)];
    w[e] = v;
  }
  u16 hi[8], lo[8];
#pragma unroll
  for (int e = 0; e < 8; ++e) {
    hi[e] = bf16_rne(w[e]);
    lo[e] = bf16_rne(w[e] - __uint_as_float((u32)hi[e] << 16));
  }
  uint4 H, L;
  H.x = (u32)hi[0] | ((u32)hi[1] << 16); H.y = (u32)hi[2] | ((u32)hi[3] << 16);
  H.z = (u32)hi[4] | ((u32)hi[5] << 16); H.w = (u32)hi[6] | ((u32)hi[7] << 16);
  L.x = (u32)lo[0] | ((u32)lo[1] << 16); L.y = (u32)lo[2] | ((u32)lo[3] << 16);
  L.z = (u32)lo[4] | ((u32)lo[5] << 16); L.w = (u32)lo[6] | ((u32)lo[7] << 16);
  ws[base + li] = H;
  ws[base + nlanes + li] = L;
}

// ---------------- LN(h) closed-form constants ----------------
// mean_r = cs[5] + sum_k x_rk*cs[k]
// E[h^2]_r = cs[26] + sum_k x_rk*cs[21+k] + sum_{k>=k2} cs[6+p]*x_rk*x_rk2 (off-diag pre-doubled)
__global__ void __launch_bounds__(256) pack_stats(const float* __restrict__ bW1,
                                                  const float* __restrict__ bb1,
                                                  float* __restrict__ wsf) {
  __shared__ float red[27 * 256];
  const int t = threadIdx.x;
  float part[27];
#pragma unroll
  for (int j = 0; j < 27; ++j) part[j] = 0.f;
  for (int c = t; c < 512; c += 256) {
    float wv[5];
#pragma unroll
    for (int k = 0; k < 5; ++k) wv[k] = bW1[k * 512 + c];
    const float bc = bb1[c];
#pragma unroll
    for (int k = 0; k < 5; ++k) part[k] += wv[k];
    part[5] += bc;
    int p = 0;
#pragma unroll
    for (int k = 0; k < 5; ++k)
#pragma unroll
      for (int k2 = 0; k2 <= k; ++k2) part[6 + p++] += wv[k] * wv[k2];
#pragma unroll
    for (int k = 0; k < 5; ++k) part[21 + k] += wv[k] * bc;
    part[26] += bc * bc;
  }
#pragma unroll
  for (int j = 0; j < 27; ++j) red[j * 256 + t] = part[j];
  __syncthreads();
  if (t < 27) {
    float s = 0.f;
    for (int i = 0; i < 256; ++i) s += red[t * 256 + i];
    s *= (1.f / 512.f);
    if (t >= 6 && t < 21) {
      const int p = t - 6;
      const bool diag = (p == 0 || p == 2 || p == 5 || p == 9 || p == 14);
      if (!diag) s *= 2.f;
    }
    if (t >= 21 && t < 26) s *= 2.f;
    wsf[t] = s;
  }
}

// ---------------- main kernel building blocks ----------------
// GEMM: A packed(hi|lo) u32 in LDS (lane l15 = batch row within rowgroup),
// W frags from global. acc[rg][ct] += Ahi*Whi + Alo*Whi + Ahi*Wlo.
template<int KSTEPS, int CTS, int RGS, int LKS>
__device__ __forceinline__ void gemm_rg(const u32* sm, int a_base, int a_stride,
                                        const uint4* __restrict__ wh,
                                        const uint4* __restrict__ wl,
                                        f32x4 (&acc)[RGS][CTS]) {
  const int lane = threadIdx.x & 63;
  const int l15 = lane & 15, g = lane >> 4;
  for (int ks = 0; ks < KSTEPS; ++ks) {
    bf16x8 ah[RGS], al[RGS];
#pragma unroll
    for (int rg = 0; rg < RGS; ++rg) {
      const uint4* ap = (const uint4*)(sm + a_base + (rg * 16 + l15) * a_stride + ks * 32 + 8 * g);
      uint4 dA = ap[0], dB = ap[1];
      uint4 h4, l4;
      h4.x = __builtin_amdgcn_perm(dA.y, dA.x, SEL_HI);
      h4.y = __builtin_amdgcn_perm(dA.w, dA.z, SEL_HI);
      h4.z = __builtin_amdgcn_perm(dB.y, dB.x, SEL_HI);
      h4.w = __builtin_amdgcn_perm(dB.w, dB.z, SEL_HI);
      l4.x = __builtin_amdgcn_perm(dA.y, dA.x, SEL_LO);
      l4.y = __builtin_amdgcn_perm(dA.w, dA.z, SEL_LO);
      l4.z = __builtin_amdgcn_perm(dB.y, dB.x, SEL_LO);
      l4.w = __builtin_amdgcn_perm(dB.w, dB.z, SEL_LO);
      ah[rg] = __builtin_bit_cast(bf16x8, h4);
      al[rg] = __builtin_bit_cast(bf16x8, l4);
    }
#pragma unroll
    for (int c = 0; c < CTS; ++c) {
      uint4 wH = wh[(c * LKS + ks) * 64];
      uint4 wL = wl[(c * LKS + ks) * 64];
      bf16x8 bh = __builtin_bit_cast(bf16x8, wH);
      bf16x8 bl = __builtin_bit_cast(bf16x8, wL);
#pragma unroll
      for (int rg = 0; rg < RGS; ++rg) {
        acc[rg][c] = mfma16(ah[rg], bh, acc[rg][c]);
        acc[rg][c] = mfma16(al[rg], bh, acc[rg][c]);
        acc[rg][c] = mfma16(ah[rg], bl, acc[rg][c]);
      }
    }
  }
}

template<int RGS, int CTS>
__device__ __forceinline__ void add_bias(f32x4 (&acc)[RGS][CTS],
                                         const float* __restrict__ bias, int col0) {
  const int l15 = threadIdx.x & 15;
#pragma unroll
  for (int c = 0; c < CTS; ++c) {
    const float bv = bias[col0 + c * 16 + l15];
#pragma unroll
    for (int rg = 0; rg < RGS; ++rg)
#pragma unroll
      for (int i = 0; i < 4; ++i) acc[rg][c][i] += bv;
  }
}

// per-wave LN stats partials -> A_WP[w][row][2]  (acc row = rg*16 + 4g + i)
template<int RGS, int CTS>
__device__ __forceinline__ void stats_partial(const f32x4 (&acc)[RGS][CTS], float* smf, int w) {
  const int lane = threadIdx.x & 63;
  const int l15 = lane & 15, g = lane >> 4;
  float s1[RGS][4], s2[RGS][4];
#pragma unroll
  for (int rg = 0; rg < RGS; ++rg)
#pragma unroll
    for (int i = 0; i < 4; ++i) {
      float a = 0.f, b = 0.f;
#pragma unroll
      for (int c = 0; c < CTS; ++c) { const float v = acc[rg][c][i]; a += v; b += v * v; }
      s1[rg][i] = a; s2[rg][i] = b;
    }
#pragma unroll
  for (int m = 1; m <= 8; m <<= 1)
#pragma unroll
    for (int rg = 0; rg < RGS; ++rg)
#pragma unroll
      for (int i = 0; i < 4; ++i) {
        s1[rg][i] += __shfl_xor(s1[rg][i], m);
        s2[rg][i] += __shfl_xor(s2[rg][i], m);
      }
  if (l15 == 0) {
#pragma unroll
    for (int rg = 0; rg < RGS; ++rg)
#pragma unroll
      for (int i = 0; i < 4; ++i) {
        const int row = rg * 16 + 4 * g + i;
        smf[A_WP + (w * 64 + row) * 2]     = s1[rg][i];
        smf[A_WP + (w * 64 + row) * 2 + 1] = s2[rg][i];
      }
  }
}

// combine all 8 waves (shared layers) -> A_RS[0]
template<int N>
__device__ __forceinline__ void combine_shared(float* smf, int t) {
  if (t < 64) {
    float a = 0.f, b = 0.f;
#pragma unroll
    for (int w = 0; w < 8; ++w) {
      a += smf[A_WP + (w * 64 + t) * 2];
      b += smf[A_WP + (w * 64 + t) * 2 + 1];
    }
    const float mean = a * (1.f / N);
    const float var = b * (1.f / N) - mean * mean;
    smf[A_RS + t * 2]     = mean;
    smf[A_RS + t * 2 + 1] = rsqrtf(fmaxf(var, 0.f) + 1e-5f);
  }
}

// combine wave pairs (expert layers, N=128) -> A_RS[e]
__device__ __forceinline__ void combine_expert(float* smf, int t) {
  if (t < 256) {
    const int e = t >> 6, r = t & 63;
    const float a = smf[A_WP + ((2 * e) * 64 + r) * 2]     + smf[A_WP + ((2 * e + 1) * 64 + r) * 2];
    const float b = smf[A_WP + ((2 * e) * 64 + r) * 2 + 1] + smf[A_WP + ((2 * e + 1) * 64 + r) * 2 + 1];
    const float mean = a * (1.f / 128.f);
    const float var = b * (1.f / 128.f) - mean * mean;
    smf[A_RS + e * 128 + r * 2]     = mean;
    smf[A_RS + e * 128 + r * 2 + 1] = rsqrtf(fmaxf(var, 0.f) + 1e-5f);
  }
}

// normalize acc with stats at st_ofs, scale/shift, ReLU, pack hi|lo, store to LDS
template<int RGS, int CTS>
__device__ __forceinline__ void norm_pack_store(const f32x4 (&acc)[RGS][CTS], u32* sm,
    int st_ofs, const float* __restrict__ gamma, const float* __restrict__ beta,
    int col0, int dst, int dstr, int dcol0) {
  float* smf = (float*)sm;
  const int lane = threadIdx.x & 63;
  const int l15 = lane & 15, g = lane >> 4;
  float gv[CTS], bv[CTS];
#pragma unroll
  for (int c = 0; c < CTS; ++c) {
    gv[c] = gamma[col0 + c * 16 + l15];
    bv[c] = beta[col0 + c * 16 + l15];
  }
#pragma unroll
  for (int rg = 0; rg < RGS; ++rg)
#pragma unroll
    for (int i = 0; i < 4; ++i) {
      const int row = rg * 16 + 4 * g + i;
      const float mean = smf[st_ofs + row * 2];
      const float inv  = smf[st_ofs + row * 2 + 1];
#pragma unroll
      for (int c = 0; c < CTS; ++c) {
        float y = (acc[rg][c][i] - mean) * inv * gv[c] + bv[c];
        y = fmaxf(y, 0.f);
        sm[dst + row * dstr + dcol0 + c * 16 + l15] = pack_split(y);
      }
    }
}

__global__ void __launch_bounds__(NTH, 1) moe_v3(
    const float* __restrict__ x,
    const float* __restrict__ bb1, const float* __restrict__ bg1, const float* __restrict__ bbt1,
    const float* __restrict__ bb2, const float* __restrict__ bg2, const float* __restrict__ bbt2,
    const float* __restrict__ cb1, const float* __restrict__ cg1, const float* __restrict__ cbt1,
    const float* __restrict__ cb2, const float* __restrict__ cg2, const float* __restrict__ cbt2,
    const float* __restrict__ chW, const float* __restrict__ chb,
    const float* __restrict__ rb1, const float* __restrict__ rg1, const float* __restrict__ rbt1,
    const float* __restrict__ rb2, const float* __restrict__ rg2, const float* __restrict__ rbt2,
    const float* __restrict__ rhW, const float* __restrict__ rhb,
    float* __restrict__ out, const uint4* __restrict__ wp, const float* __restrict__ cs) {
  __shared__ __align__(16) u32 sm[SMEM_DW];
  float* smf = (float*)sm;
  const int t = threadIdx.x;
  const int w = t >> 6;
  const int row0 = blockIdx.x * R_TILE;

  // ---- stage x packed [64][36] (K zero-padded to 32) ----
  {
    const int r = t >> 3, k0 = (t & 7) * 4;
#pragma unroll
    for (int i = 0; i < 4; ++i) {
      const int k = k0 + i;
      const float v = (k < 5) ? x[(size_t)(row0 + r) * 5 + k] : 0.f;
      sm[A_X + r * 36 + k] = pack_split(v);
    }
  }
  // ---- closed-form LN(h) stats per row -> A_RS[0] ----
  if (t < 64) {
    float xv[5];
#pragma unroll
    for (int k = 0; k < 5; ++k) xv[k] = x[(size_t)(row0 + t) * 5 + k];
    float mean = cs[5];
#pragma unroll
    for (int k = 0; k < 5; ++k) mean += xv[k] * cs[k];
    float e2 = cs[26];
    int p = 0;
#pragma unroll
    for (int k = 0; k < 5; ++k) {
      e2 += xv[k] * cs[21 + k];
#pragma unroll
      for (int k2 = 0; k2 <= k; ++k2) e2 += cs[6 + p++] * xv[k] * xv[k2];
    }
    const float var = e2 - mean * mean;
    smf[A_RS + t * 2]     = mean;
    smf[A_RS + t * 2 + 1] = rsqrtf(fmaxf(var, 0.f) + 1e-5f);
  }
  __syncthreads();

  // ---- phase 1: fused L1 -> LN -> pack -> partial L2, h in 128-col chunks ----
  f32x4 accS[4][2];
#pragma unroll
  for (int rg = 0; rg < 4; ++rg)
#pragma unroll
    for (int c = 0; c < 2; ++c) accS[rg][c] = (f32x4){0.f, 0.f, 0.f, 0.f};
  for (int kc = 0; kc < 4; ++kc) {
    f32x4 acc1[4][1];
#pragma unroll
    for (int rg = 0; rg < 4; ++rg) acc1[rg][0] = (f32x4){0.f, 0.f, 0.f, 0.f};
    gemm_rg<1, 1, 4, 1>(sm, A_X, 36,
        wp + L0H + (kc * 8 + w) * 64 + (t & 63),
        wp + L0H + L0N + (kc * 8 + w) * 64 + (t & 63), acc1);
    add_bias<4, 1>(acc1, bb1, kc * 128 + w * 16);
    norm_pack_store<4, 1>(acc1, sm, A_RS, bg1, bbt1, kc * 128 + w * 16, A_CHUNK, 132, w * 16);
    __syncthreads();
    gemm_rg<4, 2, 4, 16>(sm, A_CHUNK, 132,
        wp + L1H + (w * 32 + kc * 4) * 64 + (t & 63),
        wp + L1H + L1N + (w * 32 + kc * 4) * 64 + (t & 63), accS);
    __syncthreads();
  }

  // ---- s: bias + in-reg LN + pack -> A_S ----
  add_bias<4, 2>(accS, bb2, w * 32);
  stats_partial<4, 2>(accS, smf, w);
  __syncthreads();
  combine_shared<256>(smf, t);
  __syncthreads();
  norm_pack_store<4, 2>(accS, sm, A_RS, bg2, bbt2, w * 32, A_S, 260, w * 32);
  __syncthreads();

  // ---- class expert L1: K=256 -> c1 ----
  {
    f32x4 accC[4][1];
#pragma unroll
    for (int rg = 0; rg < 4; ++rg) accC[rg][0] = (f32x4){0.f, 0.f, 0.f, 0.f};
    gemm_rg<8, 1, 4, 8>(sm, A_S, 260,
        wp + L2H + (w * 8) * 64 + (t & 63),
        wp + L2H + L2N + (w * 8) * 64 + (t & 63), accC);
    add_bias<4, 1>(accC, cb1, w * 16);
    stats_partial<4, 1>(accC, smf, w);
    __syncthreads();
    combine_shared<128>(smf, t);
    __syncthreads();
    norm_pack_store<4, 1>(accC, sm, A_RS, cg1, cbt1, w * 16, A_C1, 132, w * 16);
    __syncthreads();
  }

  // ---- class expert L2: K=128 -> c2 (into chunk buf) ----
  {
    f32x4 accD[4][1];
#pragma unroll
    for (int rg = 0; rg < 4; ++rg) accD[rg][0] = (f32x4){0.f, 0.f, 0.f, 0.f};
    gemm_rg<4, 1, 4, 4>(sm, A_C1, 132,
        wp + L3H + (w * 4) * 64 + (t & 63),
        wp + L3H + L3N + (w * 4) * 64 + (t & 63), accD);
    add_bias<4, 1>(accD, cb2, w * 16);
    stats_partial<4, 1>(accD, smf, w);
    __syncthreads();
    combine_shared<128>(smf, t);
    __syncthreads();
    norm_pack_store<4, 1>(accD, sm, A_RS, cg2, cbt2, w * 16, A_CHUNK, 132, w * 16);
    __syncthreads();
  }

  // ---- class head + logits out ----
  {
    const int r = t >> 3, o = (t >> 1) & 3, q = t & 1;
    const uint4* cp = (const uint4*)(sm + A_CHUNK + r * 132 + q * 64);
    float s = 0.f;
#pragma unroll
    for (int i = 0; i < 16; ++i) {
      uint4 d = cp[i];
      const int kb = q * 64 + 4 * i;
      s += unpack_hl(d.x) * chW[(kb + 0) * 4 + o];
      s += unpack_hl(d.y) * chW[(kb + 1) * 4 + o];
      s += unpack_hl(d.z) * chW[(kb + 2) * 4 + o];
      s += unpack_hl(d.w) * chW[(kb + 3) * 4 + o];
    }
    s += __shfl_xor(s, 1);
    if (q == 0) {
      const float v = s + chb[o];
      smf[A_LG + r * 4 + o] = v;
      out[(size_t)(row0 + r) * 4 + o] = v;
    }
  }
  __syncthreads();
  if (t < 64) {  // argmax (first max, matches jnp.argmax)
    float best = smf[A_LG + t * 4];
    int bi = 0;
#pragma unroll
    for (int n = 1; n < 4; ++n) {
      const float v = smf[A_LG + t * 4 + n];
      if (v > best) { best = v; bi = n; }
    }
    sm[A_IDX + t] = (u32)bi;
  }

  // ---- reg experts L1 (concat N=512): K=256 from s ----
  {
    f32x4 accE[4][4];
#pragma unroll
    for (int rg = 0; rg < 4; ++rg)
#pragma unroll
      for (int c = 0; c < 4; ++c) accE[rg][c] = (f32x4){0.f, 0.f, 0.f, 0.f};
    gemm_rg<8, 4, 4, 8>(sm, A_S, 260,
        wp + L4H + (w * 32) * 64 + (t & 63),
        wp + L4H + L4N + (w * 32) * 64 + (t & 63), accE);
    add_bias<4, 4>(accE, rb1, w * 64);      // rb1 flat [E*128] == concat col
    stats_partial<4, 4>(accE, smf, w);
    __syncthreads();                        // also: all waves done reading s / head done
    combine_expert(smf, t);
    __syncthreads();
    norm_pack_store<4, 4>(accE, sm, A_RS + (w >> 1) * 128, rg1, rbt1, w * 64,
                          A_E, 532, (w >> 1) * 132 + (w & 1) * 64);
    __syncthreads();
  }

  // ---- reg experts L2 (concat): K=128 from e1 ----
  {
    f32x4 accF[4][4];
#pragma unroll
    for (int rg = 0; rg < 4; ++rg)
#pragma unroll
      for (int c = 0; c < 4; ++c) accF[rg][c] = (f32x4){0.f, 0.f, 0.f, 0.f};
    gemm_rg<4, 4, 4, 4>(sm, A_E + (w >> 1) * 132, 532,
        wp + L5H + (w * 16) * 64 + (t & 63),
        wp + L5H + L5N + (w * 16) * 64 + (t & 63), accF);
    add_bias<4, 4>(accF, rb2, w * 64);
    stats_partial<4, 4>(accF, smf, w);
    __syncthreads();                        // all waves done reading e1
    combine_expert(smf, t);
    __syncthreads();
    norm_pack_store<4, 4>(accF, sm, A_RS + (w >> 1) * 128, rg2, rbt2, w * 64,
                          A_E, 532, (w >> 1) * 132 + (w & 1) * 64);
    __syncthreads();
  }

  // ---- reg heads (all experts): e2[e] @ rhW[e][128][3] ----
  for (int u = t; u < 768; u += NTH) {
    const int r = u & 63, rest = u >> 6;    // rest 0..11 = e*3+o
    const int e = rest / 3, o = rest - 3 * e;
    float s = rhb[e * 3 + o];
    const u32* ep = sm + A_E + r * 532 + e * 132;
    for (int k = 0; k < 128; ++k)
      s += unpack_hl(ep[k]) * rhW[(e * 128 + k) * 3 + o];
    smf[A_RH + e * 256 + r * 4 + o] = s;
  }
  __syncthreads();

  // ---- gather chosen expert + softmax ----
  if (t < 64) {
    const int e = (int)sm[A_IDX + t];
    const float v0 = smf[A_RH + e * 256 + t * 4 + 0];
    const float v1 = smf[A_RH + e * 256 + t * 4 + 1];
    const float v2 = smf[A_RH + e * 256 + t * 4 + 2];
    const float mx = fmaxf(v0, fmaxf(v1, v2));
    const float e0 = expf(v0 - mx), e1 = expf(v1 - mx), e2 = expf(v2 - mx);
    const float inv = 1.f / (e0 + e1 + e2);
    float* po = out + (size_t)B_ROWS * 4 + (size_t)(row0 + t) * 3;
    po[0] = e0 * inv; po[1] = e1 * inv; po[2] = e2 * inv;
  }
}

// =================== fallback: round-1 fp32 kernel (used if ws too small) ===================
#define TILE 16
#define S_H 516
#define S_S 260
#define S_N 132
#define F_OFF_H 0
#define F_OFF_C1 0
#define F_OFF_C2 2112
#define F_OFF_E2 4224
#define F_OFF_S 8256
#define F_OFF_E1 8256
#define F_OFF_X 12416
#define F_OFF_HEAD 12544
#define F_OFF_RH 12608
#define F_OFF_INT 12672
#define F_SMEM 12704

template<int K, int N, int RB, int CB, int INS, int OUTS, bool BAR>
__device__ __forceinline__ void dense(const float* __restrict__ W, const float* __restrict__ bias,
                                      const float* IN, float* OUT, int tid) {
  constexpr int CBLK = N / CB;
  const int cb = tid % CBLK, rg = tid / CBLK;
  const int c0 = cb * CB, r0 = rg * RB;
  float acc[RB][CB];
#pragma unroll
  for (int i = 0; i < RB; ++i)
#pragma unroll
    for (int j = 0; j < CB; ++j) acc[i][j] = 0.f;
  for (int k = 0; k < K; k += 4) {
    float4 a[RB];
#pragma unroll
    for (int i = 0; i < RB; ++i) a[i] = *(const float4*)(IN + (r0 + i) * INS + k);
#pragma unroll
    for (int kk = 0; kk < 4; ++kk) {
      float wv2[CB];
      if constexpr (CB == 2) { float2 wv = *(const float2*)(W + (k + kk) * N + c0); wv2[0] = wv.x; wv2[1] = wv.y; }
      else wv2[0] = W[(k + kk) * N + c0];
#pragma unroll
      for (int i = 0; i < RB; ++i) {
        const float av = ((const float*)&a[i])[kk];
#pragma unroll
        for (int j = 0; j < CB; ++j) acc[i][j] += av * wv2[j];
      }
    }
  }
  if (BAR) __syncthreads();
#pragma unroll
  for (int i = 0; i < RB; ++i)
#pragma unroll
    for (int j = 0; j < CB; ++j) OUT[(r0 + i) * OUTS + c0 + j] = acc[i][j] + bias[c0 + j];
}

template<int K, int N, int RB, int CB, int INS, int OUTS, bool GATHER, bool BAR>
__device__ __forceinline__ void dense_ex(const float* __restrict__ Wb, const float* __restrict__ Bb,
                                         const int* sOrd, const int* sExp,
                                         const float* IN, float* OUT, int tid) {
  constexpr int CBLK = N / CB;
  const int cb = tid % CBLK, rg = tid / CBLK;
  const int c0 = cb * CB, r0 = rg * RB;
  int e[RB], ir[RB];
#pragma unroll
  for (int i = 0; i < RB; ++i) { e[i] = sExp[r0 + i]; ir[i] = GATHER ? sOrd[r0 + i] : (r0 + i); }
  float acc[RB][CB];
#pragma unroll
  for (int i = 0; i < RB; ++i)
#pragma unroll
    for (int j = 0; j < CB; ++j) acc[i][j] = 0.f;
  const float* Wp[RB];
#pragma unroll
  for (int i = 0; i < RB; ++i) Wp[i] = Wb + (size_t)e[i] * K * N;
  for (int k = 0; k < K; k += 4) {
    float4 a[RB];
#pragma unroll
    for (int i = 0; i < RB; ++i) a[i] = *(const float4*)(IN + ir[i] * INS + k);
#pragma unroll
    for (int kk = 0; kk < 4; ++kk) {
#pragma unroll
      for (int i = 0; i < RB; ++i) {
        float wv2[CB];
        if constexpr (CB == 2) { float2 wv = *(const float2*)(Wp[i] + (k + kk) * N + c0); wv2[0] = wv.x; wv2[1] = wv.y; }
        else wv2[0] = Wp[i][(k + kk) * N + c0];
        const float av = ((const float*)&a[i])[kk];
#pragma unroll
        for (int j = 0; j < CB; ++j) acc[i][j] += av * wv2[j];
      }
    }
  }
  if (BAR) __syncthreads();
#pragma unroll
  for (int i = 0; i < RB; ++i)
#pragma unroll
    for (int j = 0; j < CB; ++j) OUT[(r0 + i) * OUTS + c0 + j] = acc[i][j] + Bb[e[i] * N + c0 + j];
}

template<int N, int S, bool RELU>
__device__ __forceinline__ void ln_rows(float* buf, const float* __restrict__ g,
                                        const float* __restrict__ b, int tid) {
  const int r = tid >> 4, j = tid & 15;
  float* rp = buf + r * S;
  float s = 0.f;
  for (int c = j; c < N; c += 16) s += rp[c];
#pragma unroll
  for (int m = 8; m; m >>= 1) s += __shfl_xor(s, m);
  const float mean = s * (1.f / N);
  float v = 0.f;
  for (int c = j; c < N; c += 16) { const float d = rp[c] - mean; v += d * d; }
#pragma unroll
  for (int m = 8; m; m >>= 1) v += __shfl_xor(v, m);
  const float inv = 1.f / sqrtf(v * (1.f / N) + 1e-5f);
  for (int c = j; c < N; c += 16) {
    const float y = (rp[c] - mean) * inv * g[c] + b[c];
    rp[c] = RELU ? fmaxf(y, 0.f) : y;
  }
}

template<int N, int S>
__device__ __forceinline__ void ln_rows_ex(float* buf, const float* __restrict__ Gb,
                                           const float* __restrict__ Bb, const int* sExp, int tid) {
  const int r = tid >> 4, j = tid & 15;
  const int e = sExp[r];
  const float* g = Gb + e * N;
  const float* b = Bb + e * N;
  float* rp = buf + r * S;
  float s = 0.f;
  for (int c = j; c < N; c += 16) s += rp[c];
#pragma unroll
  for (int m = 8; m; m >>= 1) s += __shfl_xor(s, m);
  const float mean = s * (1.f / N);
  float v = 0.f;
  for (int c = j; c < N; c += 16) { const float d = rp[c] - mean; v += d * d; }
#pragma unroll
  for (int m = 8; m; m >>= 1) v += __shfl_xor(v, m);
  const float inv = 1.f / sqrtf(v * (1.f / N) + 1e-5f);
  for (int c = j; c < N; c += 16) {
    const float y = (rp[c] - mean) * inv * g[c] + b[c];
    rp[c] = fmaxf(y, 0.f);
  }
}

__global__ void __launch_bounds__(256)
moe_fused(const float* __restrict__ x,
          const float* __restrict__ bW1, const float* __restrict__ bb1,
          const float* __restrict__ bg1, const float* __restrict__ bbt1,
          const float* __restrict__ bW2, const float* __restrict__ bb2,
          const float* __restrict__ bg2, const float* __restrict__ bbt2,
          const float* __restrict__ cW1, const float* __restrict__ cb1,
          const float* __restrict__ cg1, const float* __restrict__ cbt1,
          const float* __restrict__ cW2, const float* __restrict__ cb2,
          const float* __restrict__ cg2, const float* __restrict__ cbt2,
          const float* __restrict__ chW, const float* __restrict__ chb,
          const float* __restrict__ rW1, const float* __restrict__ rb1,
          const float* __restrict__ rg1, const float* __restrict__ rbt1,
          const float* __restrict__ rW2, const float* __restrict__ rb2,
          const float* __restrict__ rg2, const float* __restrict__ rbt2,
          const float* __restrict__ rhW, const float* __restrict__ rhb,
          float* __restrict__ out) {
  __shared__ __align__(16) float smf[F_SMEM];
  const int tid = threadIdx.x;
  const int row0 = blockIdx.x * TILE;
  float* sH = smf + F_OFF_H;
  float* sS = smf + F_OFF_S;
  float* sC1 = smf + F_OFF_C1;
  float* sC2 = smf + F_OFF_C2;
  float* sE2 = smf + F_OFF_E2;
  float* sE1 = smf + F_OFF_E1;
  float* sX = smf + F_OFF_X;
  float* sHd = smf + F_OFF_HEAD;
  float* sRH = smf + F_OFF_RH;
  int* sOrd = (int*)(smf + F_OFF_INT);
  int* sExp = sOrd + TILE;

  if (tid < TILE * 5) {
    const int r = tid / 5, k = tid % 5;
    sX[r * 8 + k] = x[(size_t)(row0 + r) * 5 + k];
  }
  __syncthreads();
  for (int o = tid; o < TILE * 512; o += 256) {
    const int r = o >> 9, c = o & 511;
    float a = 0.f;
#pragma unroll
    for (int k = 0; k < 5; ++k) a += sX[r * 8 + k] * bW1[k * 512 + c];
    sH[r * S_H + c] = a + bb1[c];
  }
  __syncthreads();
  ln_rows<512, S_H, true>(sH, bg1, bbt1, tid);
  __syncthreads();
  dense<512, 256, 8, 2, S_H, S_S, false>(bW2, bb2, sH, sS, tid);
  __syncthreads();
  ln_rows<256, S_S, true>(sS, bg2, bbt2, tid);
  __syncthreads();
  dense<256, 128, 8, 1, S_S, S_N, false>(cW1, cb1, sS, sC1, tid);
  __syncthreads();
  ln_rows<128, S_N, true>(sC1, cg1, cbt1, tid);
  __syncthreads();
  dense<128, 128, 8, 1, S_N, S_N, false>(cW2, cb2, sC1, sC2, tid);
  __syncthreads();
  ln_rows<128, S_N, true>(sC2, cg2, cbt2, tid);
  __syncthreads();
  if (tid < TILE * 4) {
    const int r = tid >> 2, n = tid & 3;
    float a = 0.f;
    for (int k = 0; k < 128; ++k) a += sC2[r * S_N + k] * chW[k * 4 + n];
    a += chb[n];
    sHd[r * 4 + n] = a;
    out[(size_t)(row0 + r) * 4 + n] = a;
  }
  __syncthreads();
  if (tid == 0) {
    int idx[TILE];
    for (int r = 0; r < TILE; ++r) {
      float best = sHd[r * 4]; int bi = 0;
      for (int n = 1; n < 4; ++n) {
        const float vv = sHd[r * 4 + n];
        if (vv > best) { best = vv; bi = n; }
      }
      idx[r] = bi;
    }
    int p = 0;
    for (int e = 0; e < 4; ++e)
      for (int r = 0; r < TILE; ++r)
        if (idx[r] == e) { sOrd[p] = r; sExp[p] = e; ++p; }
  }
  __syncthreads();
  dense_ex<256, 128, 4, 2, S_S, S_N, true, true>(rW1, rb1, sOrd, sExp, sS, sE1, tid);
  __syncthreads();
  ln_rows_ex<128, S_N>(sE1, rg1, rbt1, sExp, tid);
  __syncthreads();
  dense_ex<128, 128, 4, 2, S_N, S_N, false, false>(rW2, rb2, sOrd, sExp, sE1, sE2, tid);
  __syncthreads();
  ln_rows_ex<128, S_N>(sE2, rg2, rbt2, sExp, tid);
  __syncthreads();
  if (tid < TILE * 3) {
    const int rr = tid / 3, n = tid % 3;
    const int e = sExp[rr];
    float a = 0.f;
    for (int k = 0; k < 128; ++k) a += sE2[rr * S_N + k] * rhW[(size_t)(e * 128 + k) * 3 + n];
    a += rhb[e * 3 + n];
    sRH[rr * 4 + n] = a;
  }
  __syncthreads();
  if (tid < TILE) {
    const int rr = tid;
    const float v0 = sRH[rr * 4 + 0];
    const float v1 = sRH[rr * 4 + 1];
    const float v2 = sRH[rr * 4 + 2];
    const float mx = fmaxf(v0, fmaxf(v1, v2));
    const float e0 = expf(v0 - mx), e1 = expf(v1 - mx), e2 = expf(v2 - mx);
    const float inv = 1.f / (e0 + e1 + e2);
    const size_t orow = (size_t)row0 + sOrd[rr];
    float* po = out + (size_t)B_ROWS * 4 + orow * 3;
    po[0] = e0 * inv; po[1] = e1 * inv; po[2] = e2 * inv;
  }
}

extern "C" void kernel_launch(void* const* d_in, const int* in_sizes, int n_in,
                              void* d_out, int out_size, void* d_ws, size_t ws_size,
                              hipStream_t stream) {
  (void)in_sizes; (void)n_in; (void)out_size;
  const float* p[29];
  for (int i = 0; i < 29; ++i) p[i] = (const float*)d_in[i];
  if (ws_size >= WS_NEEDED) {
    float* wsf = (float*)((char*)d_ws + (size_t)WS_FRAGS * 16);
    pack_weights<<<192, 256, 0, stream>>>(p[1], p[5], p[9], p[13], p[19], p[23], (uint4*)d_ws);
    pack_stats<<<1, 256, 0, stream>>>(p[1], p[2], wsf);
    moe_v3<<<B_ROWS / R_TILE, NTH, 0, stream>>>(
        p[0],
        p[2], p[3], p[4],
        p[6], p[7], p[8],
        p[10], p[11], p[12],
        p[14], p[15], p[16],
        p[17], p[18],
        p[20], p[21], p[22],
        p[24], p[25], p[26],
        p[27], p[28],
        (float*)d_out, (const uint4*)d_ws, wsf);
  } else {
    moe_fused<<<B_ROWS / TILE, 256, 0, stream>>>(
        p[0], p[1], p[2], p[3], p[4], p[5], p[6], p[7], p[8],
        p[9], p[10], p[11], p[12], p[13], p[14], p[15], p[16],
        p[17], p[18], p[19], p[20], p[21], p[22], p[23], p[24],
        p[25], p[26], p[27], p[28],
        (float*)d_out);
  }
}

// Round 11
// 466.789 us; speedup vs baseline: 6.7871x; 1.0790x over previous
//
#include <hip/hip_runtime.h>
#include <math.h>

typedef unsigned int u32;
typedef unsigned short u16;
typedef short bf16x8 __attribute__((ext_vector_type(8)));
typedef float f32x4 __attribute__((ext_vector_type(4)));

#define B_ROWS 131072
#define R_TILE 64
#define NTH 512

// ---------------- packed-weight layout in d_ws (16B frag units) ----------------
#define L0H 0        // bW1 K=32(pad) N=512: ct=32, ks=1 -> 2048 frags/plane
#define L0N 2048
#define L1H 4096     // bW2 K=512 N=256: ct=16, ks=16 -> 16384
#define L1N 16384
#define L2H 36864    // cW1 K=256 N=128: ct=8, ks=8 -> 4096
#define L2N 4096
#define L3H 45056    // cW2 K=128 N=128: ct=8, ks=4 -> 2048
#define L3N 2048
#define L4H 49152    // rW1 concat K=256 N=512: ct=32, ks=8 -> 16384
#define L4N 16384
#define L5H 81920    // rW2 concat K=128 N=512: ct=32, ks=4 -> 8192
#define L5N 8192
#define L7H 98304    // rhW per-expert K=128 N=16 (cols 0..2 valid): ct=expert(4), ks=4 -> 1024
#define L7N 1024
#define WS_FRAGS 100352
#define WS_NEEDED ((size_t)WS_FRAGS * 16 + 128)   // + LN-stats constants (27 floats)

// ---------------- LDS arena (dword offsets), main kernel ----------------
#define A_X      0      // x packed [64][36] = 2304   (dead after phase1; inside E region)
#define A_CHUNK  2304   // h-chunk packed [64][132] = 8448 ; later c2 packed
#define A_S      10752  // s packed [64][260] = 16640
#define A_C1     27392  // c1 packed [64][132] = 8448  (ends 35840)
#define A_E      0      // e1/e2 packed concat [64][532] = 34048 (expert col off e*132)
#define A_WP     35840  // wave partials [8][64][2] = 1024
#define A_RS     36864  // row stats [4][64][2] = 512 (e=0 for shared layers; also hstats)
#define A_LG     37376  // class logits [64][4] = 256
#define A_IDX    37632  // argmax [64]
#define A_RH     37696  // reg head out [4][64][4] = 1024
#define SMEM_DW  38720  // 154880 B

#define SEL_HI 0x07060302u
#define SEL_LO 0x05040100u

__device__ __forceinline__ u16 bf16_rne(float f) {
  u32 u = __float_as_uint(f);
  u32 r = u + 0x7fffu + ((u >> 16) & 1u);
  return (u16)(r >> 16);
}
__device__ __forceinline__ u32 pack_split(float v) {
  u16 h = bf16_rne(v);
  float fh = __uint_as_float((u32)h << 16);
  u16 l = bf16_rne(v - fh);
  return ((u32)h << 16) | (u32)l;
}
__device__ __forceinline__ float unpack_hl(u32 d) {
  return __uint_as_float(d & 0xffff0000u) + __uint_as_float(d << 16);
}
__device__ __forceinline__ f32x4 mfma16(bf16x8 a, bf16x8 b, f32x4 c) {
  return __builtin_amdgcn_mfma_f32_16x16x32_bf16(a, b, c, 0, 0, 0);
}

// ---------------- weight pre-pack kernel (frag layout, hi/lo planes) ----------------
__global__ void __launch_bounds__(256) pack_weights(
    const float* __restrict__ bW1, const float* __restrict__ bW2,
    const float* __restrict__ cW1, const float* __restrict__ cW2,
    const float* __restrict__ rW1, const float* __restrict__ rW2,
    const float* __restrict__ rhW,
    uint4* __restrict__ ws) {
  int t = blockIdx.x * 256 + threadIdx.x;  // 0..50175
  int base, nlanes, ksteps, layer;
  if (t < 2048)                { layer = 0; base = L0H; nlanes = L0N; ksteps = 1;  }
  else if (t < 2048+16384)     { layer = 1; base = L1H; nlanes = L1N; ksteps = 16; t -= 2048; }
  else if (t < 2048+16384+4096){ layer = 2; base = L2H; nlanes = L2N; ksteps = 8;  t -= 2048+16384; }
  else if (t < 2048+16384+4096+2048) { layer = 3; base = L3H; nlanes = L3N; ksteps = 4; t -= 2048+16384+4096; }
  else if (t < 2048+16384+4096+2048+16384) { layer = 4; base = L4H; nlanes = L4N; ksteps = 8; t -= 2048+16384+4096+2048; }
  else if (t < 2048+16384+4096+2048+16384+8192) { layer = 5; base = L5H; nlanes = L5N; ksteps = 4; t -= 2048+16384+4096+2048+16384; }
  else { layer = 7; base = L7H; nlanes = L7N; ksteps = 4; t -= 2048+16384+4096+2048+16384+8192; }
  const int li = t;
  const int lane = li & 63;
  const int fi = li >> 6;
  const int ct = fi / ksteps;
  const int ks = fi - ct * ksteps;
  const int g = lane >> 4;
  const int col = ct * 16 + (lane & 15);
  const int kb = ks * 32 + 8 * g;
  float w[8];
#pragma unroll
  for (int e = 0; e < 8; ++e) {
    const int k = kb + e;
    float v;
    if (layer == 0)      v = (k < 5) ? bW1[k * 512 + col] : 0.f;
    else if (layer == 1) v = bW2[k * 256 + col];
    else if (layer == 2) v = cW1[k * 128 + col];
    else if (layer == 3) v = cW2[k * 128 + col];
    else if (layer == 4) v = rW1[((col >> 7) * 256 + k) * 128 + (col & 127)];
    else if (layer == 5) v = rW2[((col >> 7) * 128 + k) * 128 + (col & 127)];
    else {
      // per-expert head: expert = col>>4 (=ct), local col = col&15 (0..2 valid), k in [0,128)
      const int ex = col >> 4, cl = col & 15;
      v = (cl < 3) ? rhW[(ex * 128 + k) * 3 + cl] : 0.f;
    }
    w[e] = v;
  }
  u16 hi[8], lo[8];
#pragma unroll
  for (int e = 0; e < 8; ++e) {
    hi[e] = bf16_rne(w[e]);
    lo[e] = bf16_rne(w[e] - __uint_as_float((u32)hi[e] << 16));
  }
  uint4 H, L;
  H.x = (u32)hi[0] | ((u32)hi[1] << 16); H.y = (u32)hi[2] | ((u32)hi[3] << 16);
  H.z = (u32)hi[4] | ((u32)hi[5] << 16); H.w = (u32)hi[6] | ((u32)hi[7] << 16);
  L.x = (u32)lo[0] | ((u32)lo[1] << 16); L.y = (u32)lo[2] | ((u32)lo[3] << 16);
  L.z = (u32)lo[4] | ((u32)lo[5] << 16); L.w = (u32)lo[6] | ((u32)lo[7] << 16);
  ws[base + li] = H;
  ws[base + nlanes + li] = L;
}

// ---------------- LN(h) closed-form constants ----------------
// mean_r = cs[5] + sum_k x_rk*cs[k]
// E[h^2]_r = cs[26] + sum_k x_rk*cs[21+k] + sum_{k>=k2} cs[6+p]*x_rk*x_rk2 (off-diag pre-doubled)
__global__ void __launch_bounds__(256) pack_stats(const float* __restrict__ bW1,
                                                  const float* __restrict__ bb1,
                                                  float* __restrict__ wsf) {
  __shared__ float red[27 * 256];
  const int t = threadIdx.x;
  float part[27];
#pragma unroll
  for (int j = 0; j < 27; ++j) part[j] = 0.f;
  for (int c = t; c < 512; c += 256) {
    float wv[5];
#pragma unroll
    for (int k = 0; k < 5; ++k) wv[k] = bW1[k * 512 + c];
    const float bc = bb1[c];
#pragma unroll
    for (int k = 0; k < 5; ++k) part[k] += wv[k];
    part[5] += bc;
    int p = 0;
#pragma unroll
    for (int k = 0; k < 5; ++k)
#pragma unroll
      for (int k2 = 0; k2 <= k; ++k2) part[6 + p++] += wv[k] * wv[k2];
#pragma unroll
    for (int k = 0; k < 5; ++k) part[21 + k] += wv[k] * bc;
    part[26] += bc * bc;
  }
#pragma unroll
  for (int j = 0; j < 27; ++j) red[j * 256 + t] = part[j];
  __syncthreads();
  if (t < 27) {
    float s = 0.f;
    for (int i = 0; i < 256; ++i) s += red[t * 256 + i];
    s *= (1.f / 512.f);
    if (t >= 6 && t < 21) {
      const int p = t - 6;
      const bool diag = (p == 0 || p == 2 || p == 5 || p == 9 || p == 14);
      if (!diag) s *= 2.f;
    }
    if (t >= 21 && t < 26) s *= 2.f;
    wsf[t] = s;
  }
}

// ---------------- main kernel building blocks ----------------
// GEMM: A packed(hi|lo) u32 in LDS (lane l15 = batch row within rowgroup),
// W frags from global. acc[rg][ct] += Ahi*Whi + Alo*Whi + Ahi*Wlo.
template<int KSTEPS, int CTS, int RGS, int LKS>
__device__ __forceinline__ void gemm_rg(const u32* sm, int a_base, int a_stride,
                                        const uint4* __restrict__ wh,
                                        const uint4* __restrict__ wl,
                                        f32x4 (&acc)[RGS][CTS]) {
  const int lane = threadIdx.x & 63;
  const int l15 = lane & 15, g = lane >> 4;
  for (int ks = 0; ks < KSTEPS; ++ks) {
    bf16x8 ah[RGS], al[RGS];
#pragma unroll
    for (int rg = 0; rg < RGS; ++rg) {
      const uint4* ap = (const uint4*)(sm + a_base + (rg * 16 + l15) * a_stride + ks * 32 + 8 * g);
      uint4 dA = ap[0], dB = ap[1];
      uint4 h4, l4;
      h4.x = __builtin_amdgcn_perm(dA.y, dA.x, SEL_HI);
      h4.y = __builtin_amdgcn_perm(dA.w, dA.z, SEL_HI);
      h4.z = __builtin_amdgcn_perm(dB.y, dB.x, SEL_HI);
      h4.w = __builtin_amdgcn_perm(dB.w, dB.z, SEL_HI);
      l4.x = __builtin_amdgcn_perm(dA.y, dA.x, SEL_LO);
      l4.y = __builtin_amdgcn_perm(dA.w, dA.z, SEL_LO);
      l4.z = __builtin_amdgcn_perm(dB.y, dB.x, SEL_LO);
      l4.w = __builtin_amdgcn_perm(dB.w, dB.z, SEL_LO);
      ah[rg] = __builtin_bit_cast(bf16x8, h4);
      al[rg] = __builtin_bit_cast(bf16x8, l4);
    }
#pragma unroll
    for (int c = 0; c < CTS; ++c) {
      uint4 wH = wh[(c * LKS + ks) * 64];
      uint4 wL = wl[(c * LKS + ks) * 64];
      bf16x8 bh = __builtin_bit_cast(bf16x8, wH);
      bf16x8 bl = __builtin_bit_cast(bf16x8, wL);
#pragma unroll
      for (int rg = 0; rg < RGS; ++rg) {
        acc[rg][c] = mfma16(ah[rg], bh, acc[rg][c]);
        acc[rg][c] = mfma16(al[rg], bh, acc[rg][c]);
        acc[rg][c] = mfma16(ah[rg], bl, acc[rg][c]);
      }
    }
  }
}

template<int RGS, int CTS>
__device__ __forceinline__ void add_bias(f32x4 (&acc)[RGS][CTS],
                                         const float* __restrict__ bias, int col0) {
  const int l15 = threadIdx.x & 15;
#pragma unroll
  for (int c = 0; c < CTS; ++c) {
    const float bv = bias[col0 + c * 16 + l15];
#pragma unroll
    for (int rg = 0; rg < RGS; ++rg)
#pragma unroll
      for (int i = 0; i < 4; ++i) acc[rg][c][i] += bv;
  }
}

// per-wave LN stats partials -> A_WP[w][row][2]  (acc row = rg*16 + 4g + i)
template<int RGS, int CTS>
__device__ __forceinline__ void stats_partial(const f32x4 (&acc)[RGS][CTS], float* smf, int w) {
  const int lane = threadIdx.x & 63;
  const int l15 = lane & 15, g = lane >> 4;
  float s1[RGS][4], s2[RGS][4];
#pragma unroll
  for (int rg = 0; rg < RGS; ++rg)
#pragma unroll
    for (int i = 0; i < 4; ++i) {
      float a = 0.f, b = 0.f;
#pragma unroll
      for (int c = 0; c < CTS; ++c) { const float v = acc[rg][c][i]; a += v; b += v * v; }
      s1[rg][i] = a; s2[rg][i] = b;
    }
#pragma unroll
  for (int m = 1; m <= 8; m <<= 1)
#pragma unroll
    for (int rg = 0; rg < RGS; ++rg)
#pragma unroll
      for (int i = 0; i < 4; ++i) {
        s1[rg][i] += __shfl_xor(s1[rg][i], m);
        s2[rg][i] += __shfl_xor(s2[rg][i], m);
      }
  if (l15 == 0) {
#pragma unroll
    for (int rg = 0; rg < RGS; ++rg)
#pragma unroll
      for (int i = 0; i < 4; ++i) {
        const int row = rg * 16 + 4 * g + i;
        smf[A_WP + (w * 64 + row) * 2]     = s1[rg][i];
        smf[A_WP + (w * 64 + row) * 2 + 1] = s2[rg][i];
      }
  }
}

// combine all 8 waves (shared layers) -> A_RS[0]
template<int N>
__device__ __forceinline__ void combine_shared(float* smf, int t) {
  if (t < 64) {
    float a = 0.f, b = 0.f;
#pragma unroll
    for (int w = 0; w < 8; ++w) {
      a += smf[A_WP + (w * 64 + t) * 2];
      b += smf[A_WP + (w * 64 + t) * 2 + 1];
    }
    const float mean = a * (1.f / N);
    const float var = b * (1.f / N) - mean * mean;
    smf[A_RS + t * 2]     = mean;
    smf[A_RS + t * 2 + 1] = rsqrtf(fmaxf(var, 0.f) + 1e-5f);
  }
}

// combine wave pairs (expert layers, N=128) -> A_RS[e]
__device__ __forceinline__ void combine_expert(float* smf, int t) {
  if (t < 256) {
    const int e = t >> 6, r = t & 63;
    const float a = smf[A_WP + ((2 * e) * 64 + r) * 2]     + smf[A_WP + ((2 * e + 1) * 64 + r) * 2];
    const float b = smf[A_WP + ((2 * e) * 64 + r) * 2 + 1] + smf[A_WP + ((2 * e + 1) * 64 + r) * 2 + 1];
    const float mean = a * (1.f / 128.f);
    const float var = b * (1.f / 128.f) - mean * mean;
    smf[A_RS + e * 128 + r * 2]     = mean;
    smf[A_RS + e * 128 + r * 2 + 1] = rsqrtf(fmaxf(var, 0.f) + 1e-5f);
  }
}

// normalize acc with stats at st_ofs, scale/shift, ReLU, pack hi|lo, store to LDS
template<int RGS, int CTS>
__device__ __forceinline__ void norm_pack_store(const f32x4 (&acc)[RGS][CTS], u32* sm,
    int st_ofs, const float* __restrict__ gamma, const float* __restrict__ beta,
    int col0, int dst, int dstr, int dcol0) {
  float* smf = (float*)sm;
  const int lane = threadIdx.x & 63;
  const int l15 = lane & 15, g = lane >> 4;
  float gv[CTS], bv[CTS];
#pragma unroll
  for (int c = 0; c < CTS; ++c) {
    gv[c] = gamma[col0 + c * 16 + l15];
    bv[c] = beta[col0 + c * 16 + l15];
  }
#pragma unroll
  for (int rg = 0; rg < RGS; ++rg)
#pragma unroll
    for (int i = 0; i < 4; ++i) {
      const int row = rg * 16 + 4 * g + i;
      const float mean = smf[st_ofs + row * 2];
      const float inv  = smf[st_ofs + row * 2 + 1];
#pragma unroll
      for (int c = 0; c < CTS; ++c) {
        float y = (acc[rg][c][i] - mean) * inv * gv[c] + bv[c];
        y = fmaxf(y, 0.f);
        sm[dst + row * dstr + dcol0 + c * 16 + l15] = pack_split(y);
      }
    }
}

__global__ void __launch_bounds__(NTH, 1) moe_v10(
    const float* __restrict__ x,
    const float* __restrict__ bb1, const float* __restrict__ bg1, const float* __restrict__ bbt1,
    const float* __restrict__ bb2, const float* __restrict__ bg2, const float* __restrict__ bbt2,
    const float* __restrict__ cb1, const float* __restrict__ cg1, const float* __restrict__ cbt1,
    const float* __restrict__ cb2, const float* __restrict__ cg2, const float* __restrict__ cbt2,
    const float* __restrict__ chW, const float* __restrict__ chb,
    const float* __restrict__ rb1, const float* __restrict__ rg1, const float* __restrict__ rbt1,
    const float* __restrict__ rb2, const float* __restrict__ rg2, const float* __restrict__ rbt2,
    const float* __restrict__ rhb,
    float* __restrict__ out, const uint4* __restrict__ wp, const float* __restrict__ cs) {
  __shared__ __align__(16) u32 sm[SMEM_DW];
  float* smf = (float*)sm;
  const int t = threadIdx.x;
  const int w = t >> 6;
  const int row0 = blockIdx.x * R_TILE;

  // ---- stage x packed [64][36] (K zero-padded to 32) ----
  {
    const int r = t >> 3, k0 = (t & 7) * 4;
#pragma unroll
    for (int i = 0; i < 4; ++i) {
      const int k = k0 + i;
      const float v = (k < 5) ? x[(size_t)(row0 + r) * 5 + k] : 0.f;
      sm[A_X + r * 36 + k] = pack_split(v);
    }
  }
  // ---- closed-form LN(h) stats per row -> A_RS[0] ----
  if (t < 64) {
    float xv[5];
#pragma unroll
    for (int k = 0; k < 5; ++k) xv[k] = x[(size_t)(row0 + t) * 5 + k];
    float mean = cs[5];
#pragma unroll
    for (int k = 0; k < 5; ++k) mean += xv[k] * cs[k];
    float e2 = cs[26];
    int p = 0;
#pragma unroll
    for (int k = 0; k < 5; ++k) {
      e2 += xv[k] * cs[21 + k];
#pragma unroll
      for (int k2 = 0; k2 <= k; ++k2) e2 += cs[6 + p++] * xv[k] * xv[k2];
    }
    const float var = e2 - mean * mean;
    smf[A_RS + t * 2]     = mean;
    smf[A_RS + t * 2 + 1] = rsqrtf(fmaxf(var, 0.f) + 1e-5f);
  }
  __syncthreads();

  // ---- phase 1: fused L1 -> LN -> pack -> partial L2, h in 128-col chunks ----
  f32x4 accS[4][2];
#pragma unroll
  for (int rg = 0; rg < 4; ++rg)
#pragma unroll
    for (int c = 0; c < 2; ++c) accS[rg][c] = (f32x4){0.f, 0.f, 0.f, 0.f};
  for (int kc = 0; kc < 4; ++kc) {
    f32x4 acc1[4][1];
#pragma unroll
    for (int rg = 0; rg < 4; ++rg) acc1[rg][0] = (f32x4){0.f, 0.f, 0.f, 0.f};
    gemm_rg<1, 1, 4, 1>(sm, A_X, 36,
        wp + L0H + (kc * 8 + w) * 64 + (t & 63),
        wp + L0H + L0N + (kc * 8 + w) * 64 + (t & 63), acc1);
    add_bias<4, 1>(acc1, bb1, kc * 128 + w * 16);
    norm_pack_store<4, 1>(acc1, sm, A_RS, bg1, bbt1, kc * 128 + w * 16, A_CHUNK, 132, w * 16);
    __syncthreads();
    gemm_rg<4, 2, 4, 16>(sm, A_CHUNK, 132,
        wp + L1H + (w * 32 + kc * 4) * 64 + (t & 63),
        wp + L1H + L1N + (w * 32 + kc * 4) * 64 + (t & 63), accS);
    __syncthreads();
  }

  // ---- s: bias + in-reg LN + pack -> A_S ----
  add_bias<4, 2>(accS, bb2, w * 32);
  stats_partial<4, 2>(accS, smf, w);
  __syncthreads();
  combine_shared<256>(smf, t);
  __syncthreads();
  norm_pack_store<4, 2>(accS, sm, A_RS, bg2, bbt2, w * 32, A_S, 260, w * 32);
  __syncthreads();

  // ---- class expert L1: K=256 -> c1 ----
  {
    f32x4 accC[4][1];
#pragma unroll
    for (int rg = 0; rg < 4; ++rg) accC[rg][0] = (f32x4){0.f, 0.f, 0.f, 0.f};
    gemm_rg<8, 1, 4, 8>(sm, A_S, 260,
        wp + L2H + (w * 8) * 64 + (t & 63),
        wp + L2H + L2N + (w * 8) * 64 + (t & 63), accC);
    add_bias<4, 1>(accC, cb1, w * 16);
    stats_partial<4, 1>(accC, smf, w);
    __syncthreads();
    combine_shared<128>(smf, t);
    __syncthreads();
    norm_pack_store<4, 1>(accC, sm, A_RS, cg1, cbt1, w * 16, A_C1, 132, w * 16);
    __syncthreads();
  }

  // ---- class expert L2: K=128 -> c2 (into chunk buf) ----
  {
    f32x4 accD[4][1];
#pragma unroll
    for (int rg = 0; rg < 4; ++rg) accD[rg][0] = (f32x4){0.f, 0.f, 0.f, 0.f};
    gemm_rg<4, 1, 4, 4>(sm, A_C1, 132,
        wp + L3H + (w * 4) * 64 + (t & 63),
        wp + L3H + L3N + (w * 4) * 64 + (t & 63), accD);
    add_bias<4, 1>(accD, cb2, w * 16);
    stats_partial<4, 1>(accD, smf, w);
    __syncthreads();
    combine_shared<128>(smf, t);
    __syncthreads();
    norm_pack_store<4, 1>(accD, sm, A_RS, cg2, cbt2, w * 16, A_CHUNK, 132, w * 16);
    __syncthreads();
  }

  // ---- class head + logits out (R3's exact recipe -> argmax bit-identical) ----
  {
    const int r = t >> 3, o = (t >> 1) & 3, q = t & 1;
    const uint4* cp = (const uint4*)(sm + A_CHUNK + r * 132 + q * 64);
    float s = 0.f;
#pragma unroll
    for (int i = 0; i < 16; ++i) {
      uint4 d = cp[i];
      const int kb = q * 64 + 4 * i;
      s += unpack_hl(d.x) * chW[(kb + 0) * 4 + o];
      s += unpack_hl(d.y) * chW[(kb + 1) * 4 + o];
      s += unpack_hl(d.z) * chW[(kb + 2) * 4 + o];
      s += unpack_hl(d.w) * chW[(kb + 3) * 4 + o];
    }
    s += __shfl_xor(s, 1);
    if (q == 0) {
      const float v = s + chb[o];
      smf[A_LG + r * 4 + o] = v;
      out[(size_t)(row0 + r) * 4 + o] = v;
    }
  }
  __syncthreads();
  if (t < 64) {  // argmax (first max, matches jnp.argmax)
    float best = smf[A_LG + t * 4];
    int bi = 0;
#pragma unroll
    for (int n = 1; n < 4; ++n) {
      const float v = smf[A_LG + t * 4 + n];
      if (v > best) { best = v; bi = n; }
    }
    sm[A_IDX + t] = (u32)bi;
  }

  // ---- reg experts L1 (concat N=512): K=256 from s ----
  {
    f32x4 accE[4][4];
#pragma unroll
    for (int rg = 0; rg < 4; ++rg)
#pragma unroll
      for (int c = 0; c < 4; ++c) accE[rg][c] = (f32x4){0.f, 0.f, 0.f, 0.f};
    gemm_rg<8, 4, 4, 8>(sm, A_S, 260,
        wp + L4H + (w * 32) * 64 + (t & 63),
        wp + L4H + L4N + (w * 32) * 64 + (t & 63), accE);
    add_bias<4, 4>(accE, rb1, w * 64);      // rb1 flat [E*128] == concat col
    stats_partial<4, 4>(accE, smf, w);
    __syncthreads();                        // also: all waves done reading s / head done
    combine_expert(smf, t);
    __syncthreads();
    norm_pack_store<4, 4>(accE, sm, A_RS + (w >> 1) * 128, rg1, rbt1, w * 64,
                          A_E, 532, (w >> 1) * 132 + (w & 1) * 64);
    __syncthreads();
  }

  // ---- reg experts L2 (concat): K=128 from e1 ----
  {
    f32x4 accF[4][4];
#pragma unroll
    for (int rg = 0; rg < 4; ++rg)
#pragma unroll
      for (int c = 0; c < 4; ++c) accF[rg][c] = (f32x4){0.f, 0.f, 0.f, 0.f};
    gemm_rg<4, 4, 4, 4>(sm, A_E + (w >> 1) * 132, 532,
        wp + L5H + (w * 16) * 64 + (t & 63),
        wp + L5H + L5N + (w * 16) * 64 + (t & 63), accF);
    add_bias<4, 4>(accF, rb2, w * 64);
    stats_partial<4, 4>(accF, smf, w);
    __syncthreads();                        // all waves done reading e1
    combine_expert(smf, t);
    __syncthreads();
    norm_pack_store<4, 4>(accF, sm, A_RS + (w >> 1) * 128, rg2, rbt2, w * 64,
                          A_E, 532, (w >> 1) * 132 + (w & 1) * 64);
    __syncthreads();
  }

  // ---- reg heads via MFMA: per-expert K=128, N=16 (cols 0..2 valid) ----
  // 16 (rowgroup x expert) tasks over 8 waves x 2 iterations. Replaces the
  // scalar loop whose 64-lane row-major reads at stride 532 were an 8-way
  // bank conflict x128 serial k-iterations (R9's biggest remaining LDS sin).
  // Reg-head values shift O(1e-5) vs scalar order: argmax-irrelevant (class only).
  {
#pragma unroll 1
    for (int it = 0; it < 2; ++it) {
      const int task = w + 8 * it;        // 0..15
      const int e = task & 3, rgp = task >> 2;
      f32x4 aH[1][1];
      aH[0][0] = (f32x4){0.f, 0.f, 0.f, 0.f};
      gemm_rg<4, 1, 1, 4>(sm, A_E + rgp * 16 * 532 + e * 132, 532,
          wp + L7H + (e * 4) * 64 + (t & 63),
          wp + L7H + L7N + (e * 4) * 64 + (t & 63), aH);
      const int l15 = t & 15, g = (t & 63) >> 4;
      if (l15 < 3) {
#pragma unroll
        for (int i = 0; i < 4; ++i)
          smf[A_RH + e * 256 + (rgp * 16 + 4 * g + i) * 4 + l15] =
              aH[0][0][i] + rhb[e * 3 + l15];
      }
    }
  }
  __syncthreads();

  // ---- gather chosen expert + softmax ----
  if (t < 64) {
    const int e = (int)sm[A_IDX + t];
    const float v0 = smf[A_RH + e * 256 + t * 4 + 0];
    const float v1 = smf[A_RH + e * 256 + t * 4 + 1];
    const float v2 = smf[A_RH + e * 256 + t * 4 + 2];
    const float mx = fmaxf(v0, fmaxf(v1, v2));
    const float e0 = expf(v0 - mx), e1 = expf(v1 - mx), e2 = expf(v2 - mx);
    const float inv = 1.f / (e0 + e1 + e2);
    float* po = out + (size_t)B_ROWS * 4 + (size_t)(row0 + t) * 3;
    po[0] = e0 * inv; po[1] = e1 * inv; po[2] = e2 * inv;
  }
}

// =================== fallback: round-1 fp32 kernel (used if ws too small) ===================
#define TILE 16
#define S_H 516
#define S_S 260
#define S_N 132
#define F_OFF_H 0
#define F_OFF_C1 0
#define F_OFF_C2 2112
#define F_OFF_E2 4224
#define F_OFF_S 8256
#define F_OFF_E1 8256
#define F_OFF_X 12416
#define F_OFF_HEAD 12544
#define F_OFF_RH 12608
#define F_OFF_INT 12672
#define F_SMEM 12704

template<int K, int N, int RB, int CB, int INS, int OUTS, bool BAR>
__device__ __forceinline__ void dense(const float* __restrict__ W, const float* __restrict__ bias,
                                      const float* IN, float* OUT, int tid) {
  constexpr int CBLK = N / CB;
  const int cb = tid % CBLK, rg = tid / CBLK;
  const int c0 = cb * CB, r0 = rg * RB;
  float acc[RB][CB];
#pragma unroll
  for (int i = 0; i < RB; ++i)
#pragma unroll
    for (int j = 0; j < CB; ++j) acc[i][j] = 0.f;
  for (int k = 0; k < K; k += 4) {
    float4 a[RB];
#pragma unroll
    for (int i = 0; i < RB; ++i) a[i] = *(const float4*)(IN + (r0 + i) * INS + k);
#pragma unroll
    for (int kk = 0; kk < 4; ++kk) {
      float wv2[CB];
      if constexpr (CB == 2) { float2 wv = *(const float2*)(W + (k + kk) * N + c0); wv2[0] = wv.x; wv2[1] = wv.y; }
      else wv2[0] = W[(k + kk) * N + c0];
#pragma unroll
      for (int i = 0; i < RB; ++i) {
        const float av = ((const float*)&a[i])[kk];
#pragma unroll
        for (int j = 0; j < CB; ++j) acc[i][j] += av * wv2[j];
      }
    }
  }
  if (BAR) __syncthreads();
#pragma unroll
  for (int i = 0; i < RB; ++i)
#pragma unroll
    for (int j = 0; j < CB; ++j) OUT[(r0 + i) * OUTS + c0 + j] = acc[i][j] + bias[c0 + j];
}

template<int K, int N, int RB, int CB, int INS, int OUTS, bool GATHER, bool BAR>
__device__ __forceinline__ void dense_ex(const float* __restrict__ Wb, const float* __restrict__ Bb,
                                         const int* sOrd, const int* sExp,
                                         const float* IN, float* OUT, int tid) {
  constexpr int CBLK = N / CB;
  const int cb = tid % CBLK, rg = tid / CBLK;
  const int c0 = cb * CB, r0 = rg * RB;
  int e[RB], ir[RB];
#pragma unroll
  for (int i = 0; i < RB; ++i) { e[i] = sExp[r0 + i]; ir[i] = GATHER ? sOrd[r0 + i] : (r0 + i); }
  float acc[RB][CB];
#pragma unroll
  for (int i = 0; i < RB; ++i)
#pragma unroll
    for (int j = 0; j < CB; ++j) acc[i][j] = 0.f;
  const float* Wp[RB];
#pragma unroll
  for (int i = 0; i < RB; ++i) Wp[i] = Wb + (size_t)e[i] * K * N;
  for (int k = 0; k < K; k += 4) {
    float4 a[RB];
#pragma unroll
    for (int i = 0; i < RB; ++i) a[i] = *(const float4*)(IN + ir[i] * INS + k);
#pragma unroll
    for (int kk = 0; kk < 4; ++kk) {
#pragma unroll
      for (int i = 0; i < RB; ++i) {
        float wv2[CB];
        if constexpr (CB == 2) { float2 wv = *(const float2*)(Wp[i] + (k + kk) * N + c0); wv2[0] = wv.x; wv2[1] = wv.y; }
        else wv2[0] = Wp[i][(k + kk) * N + c0];
        const float av = ((const float*)&a[i])[kk];
#pragma unroll
        for (int j = 0; j < CB; ++j) acc[i][j] += av * wv2[j];
      }
    }
  }
  if (BAR) __syncthreads();
#pragma unroll
  for (int i = 0; i < RB; ++i)
#pragma unroll
    for (int j = 0; j < CB; ++j) OUT[(r0 + i) * OUTS + c0 + j] = acc[i][j] + Bb[e[i] * N + c0 + j];
}

template<int N, int S, bool RELU>
__device__ __forceinline__ void ln_rows(float* buf, const float* __restrict__ g,
                                        const float* __restrict__ b, int tid) {
  const int r = tid >> 4, j = tid & 15;
  float* rp = buf + r * S;
  float s = 0.f;
  for (int c = j; c < N; c += 16) s += rp[c];
#pragma unroll
  for (int m = 8; m; m >>= 1) s += __shfl_xor(s, m);
  const float mean = s * (1.f / N);
  float v = 0.f;
  for (int c = j; c < N; c += 16) { const float d = rp[c] - mean; v += d * d; }
#pragma unroll
  for (int m = 8; m; m >>= 1) v += __shfl_xor(v, m);
  const float inv = 1.f / sqrtf(v * (1.f / N) + 1e-5f);
  for (int c = j; c < N; c += 16) {
    const float y = (rp[c] - mean) * inv * g[c] + b[c];
    rp[c] = RELU ? fmaxf(y, 0.f) : y;
  }
}

template<int N, int S>
__device__ __forceinline__ void ln_rows_ex(float* buf, const float* __restrict__ Gb,
                                           const float* __restrict__ Bb, const int* sExp, int tid) {
  const int r = tid >> 4, j = tid & 15;
  const int e = sExp[r];
  const float* g = Gb + e * N;
  const float* b = Bb + e * N;
  float* rp = buf + r * S;
  float s = 0.f;
  for (int c = j; c < N; c += 16) s += rp[c];
#pragma unroll
  for (int m = 8; m; m >>= 1) s += __shfl_xor(s, m);
  const float mean = s * (1.f / N);
  float v = 0.f;
  for (int c = j; c < N; c += 16) { const float d = rp[c] - mean; v += d * d; }
#pragma unroll
  for (int m = 8; m; m >>= 1) v += __shfl_xor(v, m);
  const float inv = 1.f / sqrtf(v * (1.f / N) + 1e-5f);
  for (int c = j; c < N; c += 16) {
    const float y = (rp[c] - mean) * inv * g[c] + b[c];
    rp[c] = fmaxf(y, 0.f);
  }
}

__global__ void __launch_bounds__(256)
moe_fused(const float* __restrict__ x,
          const float* __restrict__ bW1, const float* __restrict__ bb1,
          const float* __restrict__ bg1, const float* __restrict__ bbt1,
          const float* __restrict__ bW2, const float* __restrict__ bb2,
          const float* __restrict__ bg2, const float* __restrict__ bbt2,
          const float* __restrict__ cW1, const float* __restrict__ cb1,
          const float* __restrict__ cg1, const float* __restrict__ cbt1,
          const float* __restrict__ cW2, const float* __restrict__ cb2,
          const float* __restrict__ cg2, const float* __restrict__ cbt2,
          const float* __restrict__ chW, const float* __restrict__ chb,
          const float* __restrict__ rW1, const float* __restrict__ rb1,
          const float* __restrict__ rg1, const float* __restrict__ rbt1,
          const float* __restrict__ rW2, const float* __restrict__ rb2,
          const float* __restrict__ rg2, const float* __restrict__ rbt2,
          const float* __restrict__ rhW, const float* __restrict__ rhb,
          float* __restrict__ out) {
  __shared__ __align__(16) float smf[F_SMEM];
  const int tid = threadIdx.x;
  const int row0 = blockIdx.x * TILE;
  float* sH = smf + F_OFF_H;
  float* sS = smf + F_OFF_S;
  float* sC1 = smf + F_OFF_C1;
  float* sC2 = smf + F_OFF_C2;
  float* sE2 = smf + F_OFF_E2;
  float* sE1 = smf + F_OFF_E1;
  float* sX = smf + F_OFF_X;
  float* sHd = smf + F_OFF_HEAD;
  float* sRH = smf + F_OFF_RH;
  int* sOrd = (int*)(smf + F_OFF_INT);
  int* sExp = sOrd + TILE;

  if (tid < TILE * 5) {
    const int r = tid / 5, k = tid % 5;
    sX[r * 8 + k] = x[(size_t)(row0 + r) * 5 + k];
  }
  __syncthreads();
  for (int o = tid; o < TILE * 512; o += 256) {
    const int r = o >> 9, c = o & 511;
    float a = 0.f;
#pragma unroll
    for (int k = 0; k < 5; ++k) a += sX[r * 8 + k] * bW1[k * 512 + c];
    sH[r * S_H + c] = a + bb1[c];
  }
  __syncthreads();
  ln_rows<512, S_H, true>(sH, bg1, bbt1, tid);
  __syncthreads();
  dense<512, 256, 8, 2, S_H, S_S, false>(bW2, bb2, sH, sS, tid);
  __syncthreads();
  ln_rows<256, S_S, true>(sS, bg2, bbt2, tid);
  __syncthreads();
  dense<256, 128, 8, 1, S_S, S_N, false>(cW1, cb1, sS, sC1, tid);
  __syncthreads();
  ln_rows<128, S_N, true>(sC1, cg1, cbt1, tid);
  __syncthreads();
  dense<128, 128, 8, 1, S_N, S_N, false>(cW2, cb2, sC1, sC2, tid);
  __syncthreads();
  ln_rows<128, S_N, true>(sC2, cg2, cbt2, tid);
  __syncthreads();
  if (tid < TILE * 4) {
    const int r = tid >> 2, n = tid & 3;
    float a = 0.f;
    for (int k = 0; k < 128; ++k) a += sC2[r * S_N + k] * chW[k * 4 + n];
    a += chb[n];
    sHd[r * 4 + n] = a;
    out[(size_t)(row0 + r) * 4 + n] = a;
  }
  __syncthreads();
  if (tid == 0) {
    int idx[TILE];
    for (int r = 0; r < TILE; ++r) {
      float best = sHd[r * 4]; int bi = 0;
      for (int n = 1; n < 4; ++n) {
        const float vv = sHd[r * 4 + n];
        if (vv > best) { best = vv; bi = n; }
      }
      idx[r] = bi;
    }
    int p = 0;
    for (int e = 0; e < 4; ++e)
      for (int r = 0; r < TILE; ++r)
        if (idx[r] == e) { sOrd[p] = r; sExp[p] = e; ++p; }
  }
  __syncthreads();
  dense_ex<256, 128, 4, 2, S_S, S_N, true, true>(rW1, rb1, sOrd, sExp, sS, sE1, tid);
  __syncthreads();
  ln_rows_ex<128, S_N>(sE1, rg1, rbt1, sExp, tid);
  __syncthreads();
  dense_ex<128, 128, 4, 2, S_N, S_N, false, false>(rW2, rb2, sOrd, sExp, sE1, sE2, tid);
  __syncthreads();
  ln_rows_ex<128, S_N>(sE2, rg2, rbt2, sExp, tid);
  __syncthreads();
  if (tid < TILE * 3) {
    const int rr = tid / 3, n = tid % 3;
    const int e = sExp[rr];
    float a = 0.f;
    for (int k = 0; k < 128; ++k) a += sE2[rr * S_N + k] * rhW[(size_t)(e * 128 + k) * 3 + n];
    a += rhb[e * 3 + n];
    sRH[rr * 4 + n] = a;
  }
  __syncthreads();
  if (tid < TILE) {
    const int rr = tid;
    const float v0 = sRH[rr * 4 + 0];
    const float v1 = sRH[rr * 4 + 1];
    const float v2 = sRH[rr * 4 + 2];
    const float mx = fmaxf(v0, fmaxf(v1, v2));
    const float e0 = expf(v0 - mx), e1 = expf(v1 - mx), e2 = expf(v2 - mx);
    const float inv = 1.f / (e0 + e1 + e2);
    const size_t orow = (size_t)row0 + sOrd[rr];
    float* po = out + (size_t)B_ROWS * 4 + orow * 3;
    po[0] = e0 * inv; po[1] = e1 * inv; po[2] = e2 * inv;
  }
}

extern "C" void kernel_launch(void* const* d_in, const int* in_sizes, int n_in,
                              void* d_out, int out_size, void* d_ws, size_t ws_size,
                              hipStream_t stream) {
  (void)in_sizes; (void)n_in; (void)out_size;
  const float* p[29];
  for (int i = 0; i < 29; ++i) p[i] = (const float*)d_in[i];
  if (ws_size >= WS_NEEDED) {
    float* wsf = (float*)((char*)d_ws + (size_t)WS_FRAGS * 16);
    pack_weights<<<196, 256, 0, stream>>>(p[1], p[5], p[9], p[13], p[19], p[23],
                                          p[27], (uint4*)d_ws);
    pack_stats<<<1, 256, 0, stream>>>(p[1], p[2], wsf);
    moe_v10<<<B_ROWS / R_TILE, NTH, 0, stream>>>(
        p[0],
        p[2], p[3], p[4],
        p[6], p[7], p[8],
        p[10], p[11], p[12],
        p[14], p[15], p[16],
        p[17], p[18],
        p[20], p[21], p[22],
        p[24], p[25], p[26],
        p[28],
        (float*)d_out, (const uint4*)d_ws, wsf);
  } else {
    moe_fused<<<B_ROWS / TILE, 256, 0, stream>>>(
        p[0], p[1], p[2], p[3], p[4], p[5], p[6], p[7], p[8],
        p[9], p[10], p[11], p[12], p[13], p[14], p[15], p[16],
        p[17], p[18], p[19], p[20], p[21], p[22], p[23], p[24],
        p[25], p[26], p[27], p[28],
        (float*)d_out);
  }
}

// Round 12
// 442.330 us; speedup vs baseline: 7.1624x; 1.0553x over previous
//
#include <hip/hip_runtime.h>
#include <math.h>

typedef unsigned int u32;
typedef unsigned short u16;
typedef short bf16x8 __attribute__((ext_vector_type(8)));
typedef float f32x4 __attribute__((ext_vector_type(4)));

#define B_ROWS 131072
#define R_TILE 64
#define NTH 512

// ---------------- packed-weight layout in d_ws (16B frag units) ----------------
#define L0H 0        // bW1 K=32(pad) N=512: ct=32, ks=1 -> 2048 frags/plane
#define L0N 2048
#define L1H 4096     // bW2 K=512 N=256: ct=16, ks=16 -> 16384
#define L1N 16384
#define L2H 36864    // cW1 K=256 N=128: ct=8, ks=8 -> 4096
#define L2N 4096
#define L3H 45056    // cW2 K=128 N=128: ct=8, ks=4 -> 2048
#define L3N 2048
#define L4H 49152    // rW1 concat K=256 N=512: ct=32, ks=8 -> 16384
#define L4N 16384
#define L5H 81920    // rW2 concat K=128 N=512: ct=32, ks=4 -> 8192
#define L5N 8192
#define L7H 98304    // rhW per-expert K=128 N=16 (cols 0..2 valid): ct=expert(4), ks=4 -> 1024
#define L7N 1024
#define WS_FRAGS 100352
#define WS_NEEDED ((size_t)WS_FRAGS * 16 + 128)   // + LN-stats constants (27 floats)

// ---------------- LDS arena (dword offsets), main kernel ----------------
#define A_X      0      // x packed [64][36] = 2304   (dead after phase1; inside E region)
#define A_CHUNK  2304   // h-chunk packed [64][132] = 8448 ; later c2 packed
#define A_S      10752  // s packed [64][260] = 16640
#define A_C1     27392  // c1 packed [64][132] = 8448  (ends 35840)
#define A_E      0      // e1/e2 packed concat [64][532] = 34048 (expert col off e*132)
#define A_WP     35840  // wave partials [8][64][2] = 1024
#define A_RS     36864  // row stats [4][64][2] = 512 (e=0 for shared layers; also hstats)
#define A_LG     37376  // class logits [64][4] = 256
#define A_IDX    37632  // argmax [64]
#define A_RH     37696  // reg head out [4][64][4] = 1024
#define SMEM_DW  38720  // 154880 B

#define SEL_HI 0x07060302u
#define SEL_LO 0x05040100u

__device__ __forceinline__ u16 bf16_rne(float f) {
  u32 u = __float_as_uint(f);
  u32 r = u + 0x7fffu + ((u >> 16) & 1u);
  return (u16)(r >> 16);
}
__device__ __forceinline__ u32 pack_split(float v) {
  u16 h = bf16_rne(v);
  float fh = __uint_as_float((u32)h << 16);
  u16 l = bf16_rne(v - fh);
  return ((u32)h << 16) | (u32)l;
}
// RNE bf16 in the hi half, zero lo half (for bf16-activation reg path): 4 VALU vs ~13
__device__ __forceinline__ u32 pack_hi_rne(float v) {
  u32 u = __float_as_uint(v);
  u32 r = u + 0x7fffu + ((u >> 16) & 1u);
  return r & 0xffff0000u;
}
__device__ __forceinline__ float unpack_hl(u32 d) {
  return __uint_as_float(d & 0xffff0000u) + __uint_as_float(d << 16);
}
__device__ __forceinline__ f32x4 mfma16(bf16x8 a, bf16x8 b, f32x4 c) {
  return __builtin_amdgcn_mfma_f32_16x16x32_bf16(a, b, c, 0, 0, 0);
}

// ---------------- weight pre-pack kernel (frag layout, hi/lo planes) ----------------
__global__ void __launch_bounds__(256) pack_weights(
    const float* __restrict__ bW1, const float* __restrict__ bW2,
    const float* __restrict__ cW1, const float* __restrict__ cW2,
    const float* __restrict__ rW1, const float* __restrict__ rW2,
    const float* __restrict__ rhW,
    uint4* __restrict__ ws) {
  int t = blockIdx.x * 256 + threadIdx.x;  // 0..50175
  int base, nlanes, ksteps, layer;
  if (t < 2048)                { layer = 0; base = L0H; nlanes = L0N; ksteps = 1;  }
  else if (t < 2048+16384)     { layer = 1; base = L1H; nlanes = L1N; ksteps = 16; t -= 2048; }
  else if (t < 2048+16384+4096){ layer = 2; base = L2H; nlanes = L2N; ksteps = 8;  t -= 2048+16384; }
  else if (t < 2048+16384+4096+2048) { layer = 3; base = L3H; nlanes = L3N; ksteps = 4; t -= 2048+16384+4096; }
  else if (t < 2048+16384+4096+2048+16384) { layer = 4; base = L4H; nlanes = L4N; ksteps = 8; t -= 2048+16384+4096+2048; }
  else if (t < 2048+16384+4096+2048+16384+8192) { layer = 5; base = L5H; nlanes = L5N; ksteps = 4; t -= 2048+16384+4096+2048+16384; }
  else { layer = 7; base = L7H; nlanes = L7N; ksteps = 4; t -= 2048+16384+4096+2048+16384+8192; }
  const int li = t;
  const int lane = li & 63;
  const int fi = li >> 6;
  const int ct = fi / ksteps;
  const int ks = fi - ct * ksteps;
  const int g = lane >> 4;
  const int col = ct * 16 + (lane & 15);
  const int kb = ks * 32 + 8 * g;
  float w[8];
#pragma unroll
  for (int e = 0; e < 8; ++e) {
    const int k = kb + e;
    float v;
    if (layer == 0)      v = (k < 5) ? bW1[k * 512 + col] : 0.f;
    else if (layer == 1) v = bW2[k * 256 + col];
    else if (layer == 2) v = cW1[k * 128 + col];
    else if (layer == 3) v = cW2[k * 128 + col];
    else if (layer == 4) v = rW1[((col >> 7) * 256 + k) * 128 + (col & 127)];
    else if (layer == 5) v = rW2[((col >> 7) * 128 + k) * 128 + (col & 127)];
    else {
      const int ex = col >> 4, cl = col & 15;
      v = (cl < 3) ? rhW[(ex * 128 + k) * 3 + cl] : 0.f;
    }
    w[e] = v;
  }
  u16 hi[8], lo[8];
#pragma unroll
  for (int e = 0; e < 8; ++e) {
    hi[e] = bf16_rne(w[e]);
    lo[e] = bf16_rne(w[e] - __uint_as_float((u32)hi[e] << 16));
  }
  uint4 H, L;
  H.x = (u32)hi[0] | ((u32)hi[1] << 16); H.y = (u32)hi[2] | ((u32)hi[3] << 16);
  H.z = (u32)hi[4] | ((u32)hi[5] << 16); H.w = (u32)hi[6] | ((u32)hi[7] << 16);
  L.x = (u32)lo[0] | ((u32)lo[1] << 16); L.y = (u32)lo[2] | ((u32)lo[3] << 16);
  L.z = (u32)lo[4] | ((u32)lo[5] << 16); L.w = (u32)lo[6] | ((u32)lo[7] << 16);
  ws[base + li] = H;
  ws[base + nlanes + li] = L;
}

// ---------------- LN(h) closed-form constants ----------------
__global__ void __launch_bounds__(256) pack_stats(const float* __restrict__ bW1,
                                                  const float* __restrict__ bb1,
                                                  float* __restrict__ wsf) {
  __shared__ float red[27 * 256];
  const int t = threadIdx.x;
  float part[27];
#pragma unroll
  for (int j = 0; j < 27; ++j) part[j] = 0.f;
  for (int c = t; c < 512; c += 256) {
    float wv[5];
#pragma unroll
    for (int k = 0; k < 5; ++k) wv[k] = bW1[k * 512 + c];
    const float bc = bb1[c];
#pragma unroll
    for (int k = 0; k < 5; ++k) part[k] += wv[k];
    part[5] += bc;
    int p = 0;
#pragma unroll
    for (int k = 0; k < 5; ++k)
#pragma unroll
      for (int k2 = 0; k2 <= k; ++k2) part[6 + p++] += wv[k] * wv[k2];
#pragma unroll
    for (int k = 0; k < 5; ++k) part[21 + k] += wv[k] * bc;
    part[26] += bc * bc;
  }
#pragma unroll
  for (int j = 0; j < 27; ++j) red[j * 256 + t] = part[j];
  __syncthreads();
  if (t < 27) {
    float s = 0.f;
    for (int i = 0; i < 256; ++i) s += red[t * 256 + i];
    s *= (1.f / 512.f);
    if (t >= 6 && t < 21) {
      const int p = t - 6;
      const bool diag = (p == 0 || p == 2 || p == 5 || p == 9 || p == 14);
      if (!diag) s *= 2.f;
    }
    if (t >= 21 && t < 26) s *= 2.f;
    wsf[t] = s;
  }
}

// ---------------- main kernel building blocks ----------------
// GEMM: A packed(hi|lo) u32 in LDS, W frags from global.
// Terms (in this order, matching R3 exactly when ALO=WLO=true):
//   acc += Ahi*Whi  [+ Alo*Whi if ALO]  [+ Ahi*Wlo if WLO]
template<int KSTEPS, int CTS, int RGS, int LKS, bool ALO, bool WLO>
__device__ __forceinline__ void gemm_rg(const u32* sm, int a_base, int a_stride,
                                        const uint4* __restrict__ wh,
                                        const uint4* __restrict__ wl,
                                        f32x4 (&acc)[RGS][CTS]) {
  const int lane = threadIdx.x & 63;
  const int l15 = lane & 15, g = lane >> 4;
  for (int ks = 0; ks < KSTEPS; ++ks) {
    bf16x8 ah[RGS], al[RGS];
#pragma unroll
    for (int rg = 0; rg < RGS; ++rg) {
      const uint4* ap = (const uint4*)(sm + a_base + (rg * 16 + l15) * a_stride + ks * 32 + 8 * g);
      uint4 dA = ap[0], dB = ap[1];
      uint4 h4;
      h4.x = __builtin_amdgcn_perm(dA.y, dA.x, SEL_HI);
      h4.y = __builtin_amdgcn_perm(dA.w, dA.z, SEL_HI);
      h4.z = __builtin_amdgcn_perm(dB.y, dB.x, SEL_HI);
      h4.w = __builtin_amdgcn_perm(dB.w, dB.z, SEL_HI);
      ah[rg] = __builtin_bit_cast(bf16x8, h4);
      if constexpr (ALO) {
        uint4 l4;
        l4.x = __builtin_amdgcn_perm(dA.y, dA.x, SEL_LO);
        l4.y = __builtin_amdgcn_perm(dA.w, dA.z, SEL_LO);
        l4.z = __builtin_amdgcn_perm(dB.y, dB.x, SEL_LO);
        l4.w = __builtin_amdgcn_perm(dB.w, dB.z, SEL_LO);
        al[rg] = __builtin_bit_cast(bf16x8, l4);
      }
    }
#pragma unroll
    for (int c = 0; c < CTS; ++c) {
      uint4 wH = wh[(c * LKS + ks) * 64];
      bf16x8 bh = __builtin_bit_cast(bf16x8, wH);
      bf16x8 bl;
      if constexpr (WLO) {
        uint4 wL = wl[(c * LKS + ks) * 64];
        bl = __builtin_bit_cast(bf16x8, wL);
      }
#pragma unroll
      for (int rg = 0; rg < RGS; ++rg) {
        acc[rg][c] = mfma16(ah[rg], bh, acc[rg][c]);
        if constexpr (ALO) acc[rg][c] = mfma16(al[rg], bh, acc[rg][c]);
        if constexpr (WLO) acc[rg][c] = mfma16(ah[rg], bl, acc[rg][c]);
      }
    }
  }
}

template<int RGS, int CTS>
__device__ __forceinline__ void add_bias(f32x4 (&acc)[RGS][CTS],
                                         const float* __restrict__ bias, int col0) {
  const int l15 = threadIdx.x & 15;
#pragma unroll
  for (int c = 0; c < CTS; ++c) {
    const float bv = bias[col0 + c * 16 + l15];
#pragma unroll
    for (int rg = 0; rg < RGS; ++rg)
#pragma unroll
      for (int i = 0; i < 4; ++i) acc[rg][c][i] += bv;
  }
}

// per-wave LN stats partials -> A_WP[w][row][2]  (acc row = rg*16 + 4g + i)
template<int RGS, int CTS>
__device__ __forceinline__ void stats_partial(const f32x4 (&acc)[RGS][CTS], float* smf, int w) {
  const int lane = threadIdx.x & 63;
  const int l15 = lane & 15, g = lane >> 4;
  float s1[RGS][4], s2[RGS][4];
#pragma unroll
  for (int rg = 0; rg < RGS; ++rg)
#pragma unroll
    for (int i = 0; i < 4; ++i) {
      float a = 0.f, b = 0.f;
#pragma unroll
      for (int c = 0; c < CTS; ++c) { const float v = acc[rg][c][i]; a += v; b += v * v; }
      s1[rg][i] = a; s2[rg][i] = b;
    }
#pragma unroll
  for (int m = 1; m <= 8; m <<= 1)
#pragma unroll
    for (int rg = 0; rg < RGS; ++rg)
#pragma unroll
      for (int i = 0; i < 4; ++i) {
        s1[rg][i] += __shfl_xor(s1[rg][i], m);
        s2[rg][i] += __shfl_xor(s2[rg][i], m);
      }
  if (l15 == 0) {
#pragma unroll
    for (int rg = 0; rg < RGS; ++rg)
#pragma unroll
      for (int i = 0; i < 4; ++i) {
        const int row = rg * 16 + 4 * g + i;
        smf[A_WP + (w * 64 + row) * 2]     = s1[rg][i];
        smf[A_WP + (w * 64 + row) * 2 + 1] = s2[rg][i];
      }
  }
}

// combine all 8 waves (shared layers) -> A_RS[0]
template<int N>
__device__ __forceinline__ void combine_shared(float* smf, int t) {
  if (t < 64) {
    float a = 0.f, b = 0.f;
#pragma unroll
    for (int w = 0; w < 8; ++w) {
      a += smf[A_WP + (w * 64 + t) * 2];
      b += smf[A_WP + (w * 64 + t) * 2 + 1];
    }
    const float mean = a * (1.f / N);
    const float var = b * (1.f / N) - mean * mean;
    smf[A_RS + t * 2]     = mean;
    smf[A_RS + t * 2 + 1] = rsqrtf(fmaxf(var, 0.f) + 1e-5f);
  }
}

// combine wave pairs (expert layers, N=128) -> A_RS[e]
__device__ __forceinline__ void combine_expert(float* smf, int t) {
  if (t < 256) {
    const int e = t >> 6, r = t & 63;
    const float a = smf[A_WP + ((2 * e) * 64 + r) * 2]     + smf[A_WP + ((2 * e + 1) * 64 + r) * 2];
    const float b = smf[A_WP + ((2 * e) * 64 + r) * 2 + 1] + smf[A_WP + ((2 * e + 1) * 64 + r) * 2 + 1];
    const float mean = a * (1.f / 128.f);
    const float var = b * (1.f / 128.f) - mean * mean;
    smf[A_RS + e * 128 + r * 2]     = mean;
    smf[A_RS + e * 128 + r * 2 + 1] = rsqrtf(fmaxf(var, 0.f) + 1e-5f);
  }
}

// normalize acc, scale/shift, ReLU, pack, store.
// HIONLY=false: RNE pair (class path, bit-exact R3 recipe). HIONLY=true: RNE hi only (reg path).
template<int RGS, int CTS, bool HIONLY>
__device__ __forceinline__ void norm_pack_store(const f32x4 (&acc)[RGS][CTS], u32* sm,
    int st_ofs, const float* __restrict__ gamma, const float* __restrict__ beta,
    int col0, int dst, int dstr, int dcol0) {
  float* smf = (float*)sm;
  const int lane = threadIdx.x & 63;
  const int l15 = lane & 15, g = lane >> 4;
  float gv[CTS], bv[CTS];
#pragma unroll
  for (int c = 0; c < CTS; ++c) {
    gv[c] = gamma[col0 + c * 16 + l15];
    bv[c] = beta[col0 + c * 16 + l15];
  }
#pragma unroll
  for (int rg = 0; rg < RGS; ++rg)
#pragma unroll
    for (int i = 0; i < 4; ++i) {
      const int row = rg * 16 + 4 * g + i;
      const float mean = smf[st_ofs + row * 2];
      const float inv  = smf[st_ofs + row * 2 + 1];
#pragma unroll
      for (int c = 0; c < CTS; ++c) {
        float y = (acc[rg][c][i] - mean) * inv * gv[c] + bv[c];
        y = fmaxf(y, 0.f);
        sm[dst + row * dstr + dcol0 + c * 16 + l15] = HIONLY ? pack_hi_rne(y) : pack_split(y);
      }
    }
}

__global__ void __launch_bounds__(NTH, 1) moe_v11(
    const float* __restrict__ x,
    const float* __restrict__ bb1, const float* __restrict__ bg1, const float* __restrict__ bbt1,
    const float* __restrict__ bb2, const float* __restrict__ bg2, const float* __restrict__ bbt2,
    const float* __restrict__ cb1, const float* __restrict__ cg1, const float* __restrict__ cbt1,
    const float* __restrict__ cb2, const float* __restrict__ cg2, const float* __restrict__ cbt2,
    const float* __restrict__ chW, const float* __restrict__ chb,
    const float* __restrict__ rb1, const float* __restrict__ rg1, const float* __restrict__ rbt1,
    const float* __restrict__ rb2, const float* __restrict__ rg2, const float* __restrict__ rbt2,
    const float* __restrict__ rhb,
    float* __restrict__ out, const uint4* __restrict__ wp, const float* __restrict__ cs) {
  __shared__ __align__(16) u32 sm[SMEM_DW];
  float* smf = (float*)sm;
  const int t = threadIdx.x;
  const int w = t >> 6;
  const int row0 = blockIdx.x * R_TILE;

  // ---- stage x packed [64][36] (K zero-padded to 32) ----
  {
    const int r = t >> 3, k0 = (t & 7) * 4;
#pragma unroll
    for (int i = 0; i < 4; ++i) {
      const int k = k0 + i;
      const float v = (k < 5) ? x[(size_t)(row0 + r) * 5 + k] : 0.f;
      sm[A_X + r * 36 + k] = pack_split(v);
    }
  }
  // ---- closed-form LN(h) stats per row -> A_RS[0] ----
  if (t < 64) {
    float xv[5];
#pragma unroll
    for (int k = 0; k < 5; ++k) xv[k] = x[(size_t)(row0 + t) * 5 + k];
    float mean = cs[5];
#pragma unroll
    for (int k = 0; k < 5; ++k) mean += xv[k] * cs[k];
    float e2 = cs[26];
    int p = 0;
#pragma unroll
    for (int k = 0; k < 5; ++k) {
      e2 += xv[k] * cs[21 + k];
#pragma unroll
      for (int k2 = 0; k2 <= k; ++k2) e2 += cs[6 + p++] * xv[k] * xv[k2];
    }
    const float var = e2 - mean * mean;
    smf[A_RS + t * 2]     = mean;
    smf[A_RS + t * 2 + 1] = rsqrtf(fmaxf(var, 0.f) + 1e-5f);
  }
  __syncthreads();

  // ---- phase 1: fused L1 -> LN -> pack -> partial L2, h in 128-col chunks ----
  f32x4 accS[4][2];
#pragma unroll
  for (int rg = 0; rg < 4; ++rg)
#pragma unroll
    for (int c = 0; c < 2; ++c) accS[rg][c] = (f32x4){0.f, 0.f, 0.f, 0.f};
  for (int kc = 0; kc < 4; ++kc) {
    f32x4 acc1[4][1];
#pragma unroll
    for (int rg = 0; rg < 4; ++rg) acc1[rg][0] = (f32x4){0.f, 0.f, 0.f, 0.f};
    gemm_rg<1, 1, 4, 1, true, true>(sm, A_X, 36,
        wp + L0H + (kc * 8 + w) * 64 + (t & 63),
        wp + L0H + L0N + (kc * 8 + w) * 64 + (t & 63), acc1);
    add_bias<4, 1>(acc1, bb1, kc * 128 + w * 16);
    norm_pack_store<4, 1, false>(acc1, sm, A_RS, bg1, bbt1, kc * 128 + w * 16, A_CHUNK, 132, w * 16);
    __syncthreads();
    gemm_rg<4, 2, 4, 16, true, true>(sm, A_CHUNK, 132,
        wp + L1H + (w * 32 + kc * 4) * 64 + (t & 63),
        wp + L1H + L1N + (w * 32 + kc * 4) * 64 + (t & 63), accS);
    __syncthreads();
  }

  // ---- s: bias + in-reg LN + pack -> A_S ----
  add_bias<4, 2>(accS, bb2, w * 32);
  stats_partial<4, 2>(accS, smf, w);
  __syncthreads();
  combine_shared<256>(smf, t);
  __syncthreads();
  norm_pack_store<4, 2, false>(accS, sm, A_RS, bg2, bbt2, w * 32, A_S, 260, w * 32);
  __syncthreads();

  // ---- class expert L1: K=256 -> c1 ----
  {
    f32x4 accC[4][1];
#pragma unroll
    for (int rg = 0; rg < 4; ++rg) accC[rg][0] = (f32x4){0.f, 0.f, 0.f, 0.f};
    gemm_rg<8, 1, 4, 8, true, true>(sm, A_S, 260,
        wp + L2H + (w * 8) * 64 + (t & 63),
        wp + L2H + L2N + (w * 8) * 64 + (t & 63), accC);
    add_bias<4, 1>(accC, cb1, w * 16);
    stats_partial<4, 1>(accC, smf, w);
    __syncthreads();
    combine_shared<128>(smf, t);
    __syncthreads();
    norm_pack_store<4, 1, false>(accC, sm, A_RS, cg1, cbt1, w * 16, A_C1, 132, w * 16);
    __syncthreads();
  }

  // ---- class expert L2: K=128 -> c2 (into chunk buf) ----
  {
    f32x4 accD[4][1];
#pragma unroll
    for (int rg = 0; rg < 4; ++rg) accD[rg][0] = (f32x4){0.f, 0.f, 0.f, 0.f};
    gemm_rg<4, 1, 4, 4, true, true>(sm, A_C1, 132,
        wp + L3H + (w * 4) * 64 + (t & 63),
        wp + L3H + L3N + (w * 4) * 64 + (t & 63), accD);
    add_bias<4, 1>(accD, cb2, w * 16);
    stats_partial<4, 1>(accD, smf, w);
    __syncthreads();
    combine_shared<128>(smf, t);
    __syncthreads();
    norm_pack_store<4, 1, false>(accD, sm, A_RS, cg2, cbt2, w * 16, A_CHUNK, 132, w * 16);
    __syncthreads();
  }

  // ---- class head + logits out (R3's exact recipe -> argmax bit-identical) ----
  {
    const int r = t >> 3, o = (t >> 1) & 3, q = t & 1;
    const uint4* cp = (const uint4*)(sm + A_CHUNK + r * 132 + q * 64);
    float s = 0.f;
#pragma unroll
    for (int i = 0; i < 16; ++i) {
      uint4 d = cp[i];
      const int kb = q * 64 + 4 * i;
      s += unpack_hl(d.x) * chW[(kb + 0) * 4 + o];
      s += unpack_hl(d.y) * chW[(kb + 1) * 4 + o];
      s += unpack_hl(d.z) * chW[(kb + 2) * 4 + o];
      s += unpack_hl(d.w) * chW[(kb + 3) * 4 + o];
    }
    s += __shfl_xor(s, 1);
    if (q == 0) {
      const float v = s + chb[o];
      smf[A_LG + r * 4 + o] = v;
      out[(size_t)(row0 + r) * 4 + o] = v;
    }
  }
  __syncthreads();
  if (t < 64) {  // argmax (first max, matches jnp.argmax)
    float best = smf[A_LG + t * 4];
    int bi = 0;
#pragma unroll
    for (int n = 1; n < 4; ++n) {
      const float v = smf[A_LG + t * 4 + n];
      if (v > best) { best = v; bi = n; }
    }
    sm[A_IDX + t] = (u32)bi;
  }

  // ---- reg experts L1 (concat N=512): K=256 from s-hi, weight pair (2-term) ----
  {
    f32x4 accE[4][4];
#pragma unroll
    for (int rg = 0; rg < 4; ++rg)
#pragma unroll
      for (int c = 0; c < 4; ++c) accE[rg][c] = (f32x4){0.f, 0.f, 0.f, 0.f};
    gemm_rg<8, 4, 4, 8, false, true>(sm, A_S, 260,
        wp + L4H + (w * 32) * 64 + (t & 63),
        wp + L4H + L4N + (w * 32) * 64 + (t & 63), accE);
    add_bias<4, 4>(accE, rb1, w * 64);      // rb1 flat [E*128] == concat col
    stats_partial<4, 4>(accE, smf, w);
    __syncthreads();                        // also: all waves done reading s / head done
    combine_expert(smf, t);
    __syncthreads();
    norm_pack_store<4, 4, true>(accE, sm, A_RS + (w >> 1) * 128, rg1, rbt1, w * 64,
                                A_E, 532, (w >> 1) * 132 + (w & 1) * 64);
    __syncthreads();
  }

  // ---- reg experts L2 (concat): K=128 from e1-hi, weight pair (2-term) ----
  {
    f32x4 accF[4][4];
#pragma unroll
    for (int rg = 0; rg < 4; ++rg)
#pragma unroll
      for (int c = 0; c < 4; ++c) accF[rg][c] = (f32x4){0.f, 0.f, 0.f, 0.f};
    gemm_rg<4, 4, 4, 4, false, true>(sm, A_E + (w >> 1) * 132, 532,
        wp + L5H + (w * 16) * 64 + (t & 63),
        wp + L5H + L5N + (w * 16) * 64 + (t & 63), accF);
    add_bias<4, 4>(accF, rb2, w * 64);
    stats_partial<4, 4>(accF, smf, w);
    __syncthreads();                        // all waves done reading e1
    combine_expert(smf, t);
    __syncthreads();
    norm_pack_store<4, 4, true>(accF, sm, A_RS + (w >> 1) * 128, rg2, rbt2, w * 64,
                                A_E, 532, (w >> 1) * 132 + (w & 1) * 64);
    __syncthreads();
  }

  // ---- reg heads via MFMA: per-expert K=128, N=16, e2-hi x weight pair (2-term) ----
  {
#pragma unroll 1
    for (int it = 0; it < 2; ++it) {
      const int task = w + 8 * it;        // 0..15
      const int e = task & 3, rgp = task >> 2;
      f32x4 aH[1][1];
      aH[0][0] = (f32x4){0.f, 0.f, 0.f, 0.f};
      gemm_rg<4, 1, 1, 4, false, true>(sm, A_E + rgp * 16 * 532 + e * 132, 532,
          wp + L7H + (e * 4) * 64 + (t & 63),
          wp + L7H + L7N + (e * 4) * 64 + (t & 63), aH);
      const int l15 = t & 15, g = (t & 63) >> 4;
      if (l15 < 3) {
#pragma unroll
        for (int i = 0; i < 4; ++i)
          smf[A_RH + e * 256 + (rgp * 16 + 4 * g + i) * 4 + l15] =
              aH[0][0][i] + rhb[e * 3 + l15];
      }
    }
  }
  __syncthreads();

  // ---- gather chosen expert + softmax ----
  if (t < 64) {
    const int e = (int)sm[A_IDX + t];
    const float v0 = smf[A_RH + e * 256 + t * 4 + 0];
    const float v1 = smf[A_RH + e * 256 + t * 4 + 1];
    const float v2 = smf[A_RH + e * 256 + t * 4 + 2];
    const float mx = fmaxf(v0, fmaxf(v1, v2));
    const float e0 = expf(v0 - mx), e1 = expf(v1 - mx), e2 = expf(v2 - mx);
    const float inv = 1.f / (e0 + e1 + e2);
    float* po = out + (size_t)B_ROWS * 4 + (size_t)(row0 + t) * 3;
    po[0] = e0 * inv; po[1] = e1 * inv; po[2] = e2 * inv;
  }
}

// =================== fallback: round-1 fp32 kernel (used if ws too small) ===================
#define TILE 16
#define S_H 516
#define S_S 260
#define S_N 132
#define F_OFF_H 0
#define F_OFF_C1 0
#define F_OFF_C2 2112
#define F_OFF_E2 4224
#define F_OFF_S 8256
#define F_OFF_E1 8256
#define F_OFF_X 12416
#define F_OFF_HEAD 12544
#define F_OFF_RH 12608
#define F_OFF_INT 12672
#define F_SMEM 12704

template<int K, int N, int RB, int CB, int INS, int OUTS, bool BAR>
__device__ __forceinline__ void dense(const float* __restrict__ W, const float* __restrict__ bias,
                                      const float* IN, float* OUT, int tid) {
  constexpr int CBLK = N / CB;
  const int cb = tid % CBLK, rg = tid / CBLK;
  const int c0 = cb * CB, r0 = rg * RB;
  float acc[RB][CB];
#pragma unroll
  for (int i = 0; i < RB; ++i)
#pragma unroll
    for (int j = 0; j < CB; ++j) acc[i][j] = 0.f;
  for (int k = 0; k < K; k += 4) {
    float4 a[RB];
#pragma unroll
    for (int i = 0; i < RB; ++i) a[i] = *(const float4*)(IN + (r0 + i) * INS + k);
#pragma unroll
    for (int kk = 0; kk < 4; ++kk) {
      float wv2[CB];
      if constexpr (CB == 2) { float2 wv = *(const float2*)(W + (k + kk) * N + c0); wv2[0] = wv.x; wv2[1] = wv.y; }
      else wv2[0] = W[(k + kk) * N + c0];
#pragma unroll
      for (int i = 0; i < RB; ++i) {
        const float av = ((const float*)&a[i])[kk];
#pragma unroll
        for (int j = 0; j < CB; ++j) acc[i][j] += av * wv2[j];
      }
    }
  }
  if (BAR) __syncthreads();
#pragma unroll
  for (int i = 0; i < RB; ++i)
#pragma unroll
    for (int j = 0; j < CB; ++j) OUT[(r0 + i) * OUTS + c0 + j] = acc[i][j] + bias[c0 + j];
}

template<int K, int N, int RB, int CB, int INS, int OUTS, bool GATHER, bool BAR>
__device__ __forceinline__ void dense_ex(const float* __restrict__ Wb, const float* __restrict__ Bb,
                                         const int* sOrd, const int* sExp,
                                         const float* IN, float* OUT, int tid) {
  constexpr int CBLK = N / CB;
  const int cb = tid % CBLK, rg = tid / CBLK;
  const int c0 = cb * CB, r0 = rg * RB;
  int e[RB], ir[RB];
#pragma unroll
  for (int i = 0; i < RB; ++i) { e[i] = sExp[r0 + i]; ir[i] = GATHER ? sOrd[r0 + i] : (r0 + i); }
  float acc[RB][CB];
#pragma unroll
  for (int i = 0; i < RB; ++i)
#pragma unroll
    for (int j = 0; j < CB; ++j) acc[i][j] = 0.f;
  const float* Wp[RB];
#pragma unroll
  for (int i = 0; i < RB; ++i) Wp[i] = Wb + (size_t)e[i] * K * N;
  for (int k = 0; k < K; k += 4) {
    float4 a[RB];
#pragma unroll
    for (int i = 0; i < RB; ++i) a[i] = *(const float4*)(IN + ir[i] * INS + k);
#pragma unroll
    for (int kk = 0; kk < 4; ++kk) {
#pragma unroll
      for (int i = 0; i < RB; ++i) {
        float wv2[CB];
        if constexpr (CB == 2) { float2 wv = *(const float2*)(Wp[i] + (k + kk) * N + c0); wv2[0] = wv.x; wv2[1] = wv.y; }
        else wv2[0] = Wp[i][(k + kk) * N + c0];
        const float av = ((const float*)&a[i])[kk];
#pragma unroll
        for (int j = 0; j < CB; ++j) acc[i][j] += av * wv2[j];
      }
    }
  }
  if (BAR) __syncthreads();
#pragma unroll
  for (int i = 0; i < RB; ++i)
#pragma unroll
    for (int j = 0; j < CB; ++j) OUT[(r0 + i) * OUTS + c0 + j] = acc[i][j] + Bb[e[i] * N + c0 + j];
}

template<int N, int S, bool RELU>
__device__ __forceinline__ void ln_rows(float* buf, const float* __restrict__ g,
                                        const float* __restrict__ b, int tid) {
  const int r = tid >> 4, j = tid & 15;
  float* rp = buf + r * S;
  float s = 0.f;
  for (int c = j; c < N; c += 16) s += rp[c];
#pragma unroll
  for (int m = 8; m; m >>= 1) s += __shfl_xor(s, m);
  const float mean = s * (1.f / N);
  float v = 0.f;
  for (int c = j; c < N; c += 16) { const float d = rp[c] - mean; v += d * d; }
#pragma unroll
  for (int m = 8; m; m >>= 1) v += __shfl_xor(v, m);
  const float inv = 1.f / sqrtf(v * (1.f / N) + 1e-5f);
  for (int c = j; c < N; c += 16) {
    const float y = (rp[c] - mean) * inv * g[c] + b[c];
    rp[c] = RELU ? fmaxf(y, 0.f) : y;
  }
}

template<int N, int S>
__device__ __forceinline__ void ln_rows_ex(float* buf, const float* __restrict__ Gb,
                                           const float* __restrict__ Bb, const int* sExp, int tid) {
  const int r = tid >> 4, j = tid & 15;
  const int e = sExp[r];
  const float* g = Gb + e * N;
  const float* b = Bb + e * N;
  float* rp = buf + r * S;
  float s = 0.f;
  for (int c = j; c < N; c += 16) s += rp[c];
#pragma unroll
  for (int m = 8; m; m >>= 1) s += __shfl_xor(s, m);
  const float mean = s * (1.f / N);
  float v = 0.f;
  for (int c = j; c < N; c += 16) { const float d = rp[c] - mean; v += d * d; }
#pragma unroll
  for (int m = 8; m; m >>= 1) v += __shfl_xor(v, m);
  const float inv = 1.f / sqrtf(v * (1.f / N) + 1e-5f);
  for (int c = j; c < N; c += 16) {
    const float y = (rp[c] - mean) * inv * g[c] + b[c];
    rp[c] = fmaxf(y, 0.f);
  }
}

__global__ void __launch_bounds__(256)
moe_fused(const float* __restrict__ x,
          const float* __restrict__ bW1, const float* __restrict__ bb1,
          const float* __restrict__ bg1, const float* __restrict__ bbt1,
          const float* __restrict__ bW2, const float* __restrict__ bb2,
          const float* __restrict__ bg2, const float* __restrict__ bbt2,
          const float* __restrict__ cW1, const float* __restrict__ cb1,
          const float* __restrict__ cg1, const float* __restrict__ cbt1,
          const float* __restrict__ cW2, const float* __restrict__ cb2,
          const float* __restrict__ cg2, const float* __restrict__ cbt2,
          const float* __restrict__ chW, const float* __restrict__ chb,
          const float* __restrict__ rW1, const float* __restrict__ rb1,
          const float* __restrict__ rg1, const float* __restrict__ rbt1,
          const float* __restrict__ rW2, const float* __restrict__ rb2,
          const float* __restrict__ rg2, const float* __restrict__ rbt2,
          const float* __restrict__ rhW, const float* __restrict__ rhb,
          float* __restrict__ out) {
  __shared__ __align__(16) float smf[F_SMEM];
  const int tid = threadIdx.x;
  const int row0 = blockIdx.x * TILE;
  float* sH = smf + F_OFF_H;
  float* sS = smf + F_OFF_S;
  float* sC1 = smf + F_OFF_C1;
  float* sC2 = smf + F_OFF_C2;
  float* sE2 = smf + F_OFF_E2;
  float* sE1 = smf + F_OFF_E1;
  float* sX = smf + F_OFF_X;
  float* sHd = smf + F_OFF_HEAD;
  float* sRH = smf + F_OFF_RH;
  int* sOrd = (int*)(smf + F_OFF_INT);
  int* sExp = sOrd + TILE;

  if (tid < TILE * 5) {
    const int r = tid / 5, k = tid % 5;
    sX[r * 8 + k] = x[(size_t)(row0 + r) * 5 + k];
  }
  __syncthreads();
  for (int o = tid; o < TILE * 512; o += 256) {
    const int r = o >> 9, c = o & 511;
    float a = 0.f;
#pragma unroll
    for (int k = 0; k < 5; ++k) a += sX[r * 8 + k] * bW1[k * 512 + c];
    sH[r * S_H + c] = a + bb1[c];
  }
  __syncthreads();
  ln_rows<512, S_H, true>(sH, bg1, bbt1, tid);
  __syncthreads();
  dense<512, 256, 8, 2, S_H, S_S, false>(bW2, bb2, sH, sS, tid);
  __syncthreads();
  ln_rows<256, S_S, true>(sS, bg2, bbt2, tid);
  __syncthreads();
  dense<256, 128, 8, 1, S_S, S_N, false>(cW1, cb1, sS, sC1, tid);
  __syncthreads();
  ln_rows<128, S_N, true>(sC1, cg1, cbt1, tid);
  __syncthreads();
  dense<128, 128, 8, 1, S_N, S_N, false>(cW2, cb2, sC1, sC2, tid);
  __syncthreads();
  ln_rows<128, S_N, true>(sC2, cg2, cbt2, tid);
  __syncthreads();
  if (tid < TILE * 4) {
    const int r = tid >> 2, n = tid & 3;
    float a = 0.f;
    for (int k = 0; k < 128; ++k) a += sC2[r * S_N + k] * chW[k * 4 + n];
    a += chb[n];
    sHd[r * 4 + n] = a;
    out[(size_t)(row0 + r) * 4 + n] = a;
  }
  __syncthreads();
  if (tid == 0) {
    int idx[TILE];
    for (int r = 0; r < TILE; ++r) {
      float best = sHd[r * 4]; int bi = 0;
      for (int n = 1; n < 4; ++n) {
        const float vv = sHd[r * 4 + n];
        if (vv > best) { best = vv; bi = n; }
      }
      idx[r] = bi;
    }
    int p = 0;
    for (int e = 0; e < 4; ++e)
      for (int r = 0; r < TILE; ++r)
        if (idx[r] == e) { sOrd[p] = r; sExp[p] = e; ++p; }
  }
  __syncthreads();
  dense_ex<256, 128, 4, 2, S_S, S_N, true, true>(rW1, rb1, sOrd, sExp, sS, sE1, tid);
  __syncthreads();
  ln_rows_ex<128, S_N>(sE1, rg1, rbt1, sExp, tid);
  __syncthreads();
  dense_ex<128, 128, 4, 2, S_N, S_N, false, false>(rW2, rb2, sOrd, sExp, sE1, sE2, tid);
  __syncthreads();
  ln_rows_ex<128, S_N>(sE2, rg2, rbt2, sExp, tid);
  __syncthreads();
  if (tid < TILE * 3) {
    const int rr = tid / 3, n = tid % 3;
    const int e = sExp[rr];
    float a = 0.f;
    for (int k = 0; k < 128; ++k) a += sE2[rr * S_N + k] * rhW[(size_t)(e * 128 + k) * 3 + n];
    a += rhb[e * 3 + n];
    sRH[rr * 4 + n] = a;
  }
  __syncthreads();
  if (tid < TILE) {
    const int rr = tid;
    const float v0 = sRH[rr * 4 + 0];
    const float v1 = sRH[rr * 4 + 1];
    const float v2 = sRH[rr * 4 + 2];
    const float mx = fmaxf(v0, fmaxf(v1, v2));
    const float e0 = expf(v0 - mx), e1 = expf(v1 - mx), e2 = expf(v2 - mx);
    const float inv = 1.f / (e0 + e1 + e2);
    const size_t orow = (size_t)row0 + sOrd[rr];
    float* po = out + (size_t)B_ROWS * 4 + orow * 3;
    po[0] = e0 * inv; po[1] = e1 * inv; po[2] = e2 * inv;
  }
}

extern "C" void kernel_launch(void* const* d_in, const int* in_sizes, int n_in,
                              void* d_out, int out_size, void* d_ws, size_t ws_size,
                              hipStream_t stream) {
  (void)in_sizes; (void)n_in; (void)out_size;
  const float* p[29];
  for (int i = 0; i < 29; ++i) p[i] = (const float*)d_in[i];
  if (ws_size >= WS_NEEDED) {
    float* wsf = (float*)((char*)d_ws + (size_t)WS_FRAGS * 16);
    pack_weights<<<196, 256, 0, stream>>>(p[1], p[5], p[9], p[13], p[19], p[23],
                                          p[27], (uint4*)d_ws);
    pack_stats<<<1, 256, 0, stream>>>(p[1], p[2], wsf);
    moe_v11<<<B_ROWS / R_TILE, NTH, 0, stream>>>(
        p[0],
        p[2], p[3], p[4],
        p[6], p[7], p[8],
        p[10], p[11], p[12],
        p[14], p[15], p[16],
        p[17], p[18],
        p[20], p[21], p[22],
        p[24], p[25], p[26],
        p[28],
        (float*)d_out, (const uint4*)d_ws, wsf);
  } else {
    moe_fused<<<B_ROWS / TILE, 256, 0, stream>>>(
        p[0], p[1], p[2], p[3], p[4], p[5], p[6], p[7], p[8],
        p[9], p[10], p[11], p[12], p[13], p[14], p[15], p[16],
        p[17], p[18], p[19], p[20], p[21], p[22], p[23], p[24],
        p[25], p[26], p[27], p[28],
        (float*)d_out);
  }
}